// Round 1
// baseline (1057.314 us; speedup 1.0000x reference)
//
#include <hip/hip_runtime.h>
#include <math.h>

#define N_NODES 50000
#define N_EDGES 800000

// ---------------------------------------------------------------------------
// GEMM1: Y1p = X @ Wp1 (no bias; bias folds into node-level init)
//        ACC1 = X @ Ws1 + bs1 + bp1   (scatter1 accumulates on top)
// block=256, 16 rows/block, thread t: col = t&127, matrix = (t>=128)
// ---------------------------------------------------------------------------
__global__ __launch_bounds__(256) void k_gemm1(
    const float* __restrict__ X,
    const float* __restrict__ Wp, const float* __restrict__ bp,
    const float* __restrict__ Ws, const float* __restrict__ bs,
    float* __restrict__ Y1p, float* __restrict__ ACC1)
{
    __shared__ float Xs[16][128];
    const int t = threadIdx.x;
    const int base = blockIdx.x * (16 * 128);

    const float4* Xv = reinterpret_cast<const float4*>(X + base);
    float4* Xsv = reinterpret_cast<float4*>(&Xs[0][0]);
    Xsv[t] = Xv[t];
    Xsv[t + 256] = Xv[t + 256];
    __syncthreads();

    const int c = t & 127;
    const bool self_path = (t >= 128);
    const float* __restrict__ W = self_path ? Ws : Wp;

    float acc[16];
#pragma unroll
    for (int r = 0; r < 16; ++r) acc[r] = 0.f;

#pragma unroll 4
    for (int k = 0; k < 128; ++k) {
        const float w = W[k * 128 + c];
#pragma unroll
        for (int r = 0; r < 16; ++r) acc[r] = fmaf(Xs[r][k], w, acc[r]);
    }

    float* __restrict__ Out = self_path ? ACC1 : Y1p;
    const float bias = self_path ? (bs[c] + bp[c]) : 0.f;
#pragma unroll
    for (int r = 0; r < 16; ++r) Out[base + r * 128 + c] = acc[r] + bias;
}

// ---------------------------------------------------------------------------
// scatter1: ACC1[row] += vals[e] * Y1p[col]   (128 features, float2/lane)
// one wave (64 lanes) per edge
// ---------------------------------------------------------------------------
__global__ __launch_bounds__(256) void k_scatter1(
    const int* __restrict__ er, const int* __restrict__ ec,
    const float* __restrict__ ev,
    const float* __restrict__ Y1p, float* __restrict__ ACC1)
{
    const unsigned tid = blockIdx.x * 256u + threadIdx.x;
    const unsigned e = tid >> 6;
    if (e >= N_EDGES) return;
    const unsigned d2 = tid & 63u;

    const int r = er[e];
    const int c = ec[e];
    const float v = ev[e];

    const float2 x = reinterpret_cast<const float2*>(Y1p)[c * 64 + d2];
    float* dst = ACC1 + r * 128 + d2 * 2;
    atomicAdd(dst,     v * x.x);
    atomicAdd(dst + 1, v * x.y);
}

// ---------------------------------------------------------------------------
// GEMM2: H1 = relu(ACC1) applied on LDS stage.
//        Y2p = H1 @ Wp2 ; ACC2 = H1 @ Ws2 + bs2 + bp2
// block=256, 16 rows/block; thread: col=t&63, matrix=(t&64), rowhalf=(t>>7)*8
// ---------------------------------------------------------------------------
__global__ __launch_bounds__(256) void k_gemm2(
    const float* __restrict__ A1,
    const float* __restrict__ Wp, const float* __restrict__ bp,
    const float* __restrict__ Ws, const float* __restrict__ bs,
    float* __restrict__ Y2p, float* __restrict__ ACC2)
{
    __shared__ float Hs[16][128];
    const int t = threadIdx.x;
    const int base = blockIdx.x * (16 * 128);

    const float4* Av = reinterpret_cast<const float4*>(A1 + base);
    float4* Hsv = reinterpret_cast<float4*>(&Hs[0][0]);
    float4 v0 = Av[t];
    float4 v1 = Av[t + 256];
    v0.x = fmaxf(v0.x, 0.f); v0.y = fmaxf(v0.y, 0.f);
    v0.z = fmaxf(v0.z, 0.f); v0.w = fmaxf(v0.w, 0.f);
    v1.x = fmaxf(v1.x, 0.f); v1.y = fmaxf(v1.y, 0.f);
    v1.z = fmaxf(v1.z, 0.f); v1.w = fmaxf(v1.w, 0.f);
    Hsv[t] = v0;
    Hsv[t + 256] = v1;
    __syncthreads();

    const int c = t & 63;
    const bool self_path = (t & 64) != 0;
    const int rb = (t >> 7) * 8;
    const float* __restrict__ W = self_path ? Ws : Wp;

    float acc[8];
#pragma unroll
    for (int r = 0; r < 8; ++r) acc[r] = 0.f;

#pragma unroll 4
    for (int k = 0; k < 128; ++k) {
        const float w = W[k * 64 + c];
#pragma unroll
        for (int r = 0; r < 8; ++r) acc[r] = fmaf(Hs[rb + r][k], w, acc[r]);
    }

    const int obase = blockIdx.x * (16 * 64);
    float* __restrict__ Out = self_path ? ACC2 : Y2p;
    const float bias = self_path ? (bs[c] + bp[c]) : 0.f;
#pragma unroll
    for (int r = 0; r < 8; ++r) Out[obase + (rb + r) * 64 + c] = acc[r] + bias;
}

// ---------------------------------------------------------------------------
// scatter2: ACC2[row] += vals[e] * Y2p[col]   (64 features, 1 float/lane)
// ---------------------------------------------------------------------------
__global__ __launch_bounds__(256) void k_scatter2(
    const int* __restrict__ er, const int* __restrict__ ec,
    const float* __restrict__ ev,
    const float* __restrict__ Y2p, float* __restrict__ ACC2)
{
    const unsigned tid = blockIdx.x * 256u + threadIdx.x;
    const unsigned e = tid >> 6;
    if (e >= N_EDGES) return;
    const unsigned d = tid & 63u;

    const int r = er[e];
    const int c = ec[e];
    const float v = ev[e];

    atomicAdd(ACC2 + r * 64 + d, v * Y2p[c * 64 + d]);
}

// ---------------------------------------------------------------------------
// edgedot: out[e] = sigmoid( dot( relu(ACC2[row]), relu(ACC2[col]) ) )
// one wave per edge, lane = feature, shfl_xor reduce over 64 lanes
// ---------------------------------------------------------------------------
__global__ __launch_bounds__(256) void k_edgedot(
    const int* __restrict__ er, const int* __restrict__ ec,
    const float* __restrict__ ACC2, float* __restrict__ out)
{
    const unsigned tid = blockIdx.x * 256u + threadIdx.x;
    const unsigned e = tid >> 6;
    if (e >= N_EDGES) return;
    const unsigned d = tid & 63u;

    const int r = er[e];
    const int c = ec[e];

    const float a = fmaxf(ACC2[r * 64 + d], 0.f);
    const float b = fmaxf(ACC2[c * 64 + d], 0.f);
    float p = a * b;

#pragma unroll
    for (int off = 32; off; off >>= 1) p += __shfl_xor(p, off, 64);

    if (d == 0) out[e] = 1.f / (1.f + expf(-p));
}

// ---------------------------------------------------------------------------
extern "C" void kernel_launch(void* const* d_in, const int* in_sizes, int n_in,
                              void* d_out, int out_size, void* d_ws, size_t ws_size,
                              hipStream_t stream)
{
    const float* X   = (const float*)d_in[0];
    const int*   er  = (const int*)d_in[1];
    const int*   ec  = (const int*)d_in[2];
    const float* ev  = (const float*)d_in[3];
    const float* Wp1 = (const float*)d_in[4];
    const float* bp1 = (const float*)d_in[5];
    const float* Ws1 = (const float*)d_in[6];
    const float* bs1 = (const float*)d_in[7];
    const float* Wp2 = (const float*)d_in[8];
    const float* bp2 = (const float*)d_in[9];
    const float* Ws2 = (const float*)d_in[10];
    const float* bs2 = (const float*)d_in[11];
    float* out = (float*)d_out;

    // workspace layout (floats):
    //   [0          , 6.4M)  Y1p   -- dead after scatter1; reused by Y2p/ACC2
    //   [6.4M       , 12.8M) ACC1
    float* Y1p  = (float*)d_ws;
    float* ACC1 = Y1p + (size_t)N_NODES * 128;
    float* Y2p  = (float*)d_ws;                       // reuse Y1p region
    float* ACC2 = (float*)d_ws + (size_t)N_NODES * 64;

    const dim3 blk(256);
    const int edge_blocks = (N_EDGES * 64 + 255) / 256;   // 200000

    k_gemm1  <<<N_NODES / 16, blk, 0, stream>>>(X, Wp1, bp1, Ws1, bs1, Y1p, ACC1);
    k_scatter1<<<edge_blocks,  blk, 0, stream>>>(er, ec, ev, Y1p, ACC1);
    k_gemm2  <<<N_NODES / 16, blk, 0, stream>>>(ACC1, Wp2, bp2, Ws2, bs2, Y2p, ACC2);
    k_scatter2<<<edge_blocks,  blk, 0, stream>>>(er, ec, ev, Y2p, ACC2);
    k_edgedot <<<edge_blocks,  blk, 0, stream>>>(er, ec, ACC2, out);
}

// Round 2
// 595.384 us; speedup vs baseline: 1.7759x; 1.7759x over previous
//
#include <hip/hip_runtime.h>
#include <math.h>

#define N_NODES 50000
#define N_EDGES 800000

// ---------------------------------------------------------------------------
// CSR build: k_zero -> k_hist -> k_scan (1 block) -> k_reorder
// rowptr has N_NODES+1 ints. After scan, rowptr[i] = start(i).
// k_reorder's atomicAdd(&rowptr[r],1) hands out slots; afterwards
// rowptr[i] == start(i+1), so agg reads start = (i? rowptr[i-1] : 0).
// ---------------------------------------------------------------------------
__global__ __launch_bounds__(256) void k_zero(int* __restrict__ rowptr)
{
    const int i = blockIdx.x * 256 + threadIdx.x;
    if (i <= N_NODES) rowptr[i] = 0;
}

__global__ __launch_bounds__(256) void k_hist(
    const int* __restrict__ er, int* __restrict__ rowptr)
{
    const int e = blockIdx.x * 256 + threadIdx.x;
    if (e < N_EDGES) atomicAdd(&rowptr[er[e] + 1], 1);
}

__global__ __launch_bounds__(1024) void k_scan(int* __restrict__ rowptr)
{
    // single block, 1024 threads; inclusive scan of rowptr[1..N_NODES]
    const int T = 1024;
    const int CH = (N_NODES + T - 1) / T;   // 49
    __shared__ int partial[T];
    const int t = threadIdx.x;
    const int begin = 1 + t * CH;
    int end = 1 + (t + 1) * CH;
    if (end > N_NODES + 1) end = N_NODES + 1;

    int s = 0;
    for (int i = begin; i < end; ++i) { s += rowptr[i]; rowptr[i] = s; }
    partial[t] = s;
    __syncthreads();
    if (t == 0) {
        int run = 0;
        for (int i = 0; i < T; ++i) { int v = partial[i]; partial[i] = run; run += v; }
    }
    __syncthreads();
    const int add = partial[t];
    for (int i = begin; i < end; ++i) rowptr[i] += add;
    if (t == 0) rowptr[0] = 0;
}

__global__ __launch_bounds__(256) void k_reorder(
    const int* __restrict__ er, const int* __restrict__ ec,
    const float* __restrict__ ev, int* __restrict__ rowptr,
    int* __restrict__ ecol_s, float* __restrict__ eval_s)
{
    const int e = blockIdx.x * 256 + threadIdx.x;
    if (e >= N_EDGES) return;
    const int r = er[e];
    const int slot = atomicAdd(&rowptr[r], 1);
    ecol_s[slot] = ec[e];
    eval_s[slot] = ev[e];
}

// ---------------------------------------------------------------------------
// GEMM1: Y1p = X @ Wp1 ; ACC1 = X @ Ws1 + (bs1 + bp1)
// ---------------------------------------------------------------------------
__global__ __launch_bounds__(256) void k_gemm1(
    const float* __restrict__ X,
    const float* __restrict__ Wp, const float* __restrict__ bp,
    const float* __restrict__ Ws, const float* __restrict__ bs,
    float* __restrict__ Y1p, float* __restrict__ ACC1)
{
    __shared__ float Xs[16][128];
    const int t = threadIdx.x;
    const int base = blockIdx.x * (16 * 128);

    const float4* Xv = reinterpret_cast<const float4*>(X + base);
    float4* Xsv = reinterpret_cast<float4*>(&Xs[0][0]);
    Xsv[t] = Xv[t];
    Xsv[t + 256] = Xv[t + 256];
    __syncthreads();

    const int c = t & 127;
    const bool self_path = (t >= 128);
    const float* __restrict__ W = self_path ? Ws : Wp;

    float acc[16];
#pragma unroll
    for (int r = 0; r < 16; ++r) acc[r] = 0.f;

#pragma unroll 4
    for (int k = 0; k < 128; ++k) {
        const float w = W[k * 128 + c];
#pragma unroll
        for (int r = 0; r < 16; ++r) acc[r] = fmaf(Xs[r][k], w, acc[r]);
    }

    float* __restrict__ Out = self_path ? ACC1 : Y1p;
    const float bias = self_path ? (bs[c] + bp[c]) : 0.f;
#pragma unroll
    for (int r = 0; r < 16; ++r) Out[base + r * 128 + c] = acc[r] + bias;
}

// ---------------------------------------------------------------------------
// agg1: ACC1[i] += sum_{j in row i} val_j * Y1p[col_j]   (128 feats, float2)
// one wave per node; no atomics.
// ---------------------------------------------------------------------------
__global__ __launch_bounds__(256) void k_agg1(
    const int* __restrict__ rowptr, const int* __restrict__ ecol_s,
    const float* __restrict__ eval_s,
    const float* __restrict__ Y1p, float* __restrict__ ACC1)
{
    const unsigned tid = blockIdx.x * 256u + threadIdx.x;
    const unsigned i = tid >> 6;
    if (i >= N_NODES) return;
    const unsigned lane = tid & 63u;

    const int e0 = (i == 0) ? 0 : rowptr[i - 1];
    const int e1 = rowptr[i];

    float2 acc = {0.f, 0.f};
    if (e0 < e1) {
        int c = ecol_s[e0];
        float v = eval_s[e0];
        for (int j = e0; j < e1; ++j) {
            int cn = 0; float vn = 0.f;
            if (j + 1 < e1) { cn = ecol_s[j + 1]; vn = eval_s[j + 1]; }
            const float2 x = reinterpret_cast<const float2*>(Y1p)[c * 64 + lane];
            acc.x = fmaf(v, x.x, acc.x);
            acc.y = fmaf(v, x.y, acc.y);
            c = cn; v = vn;
        }
    }
    float2* dst = reinterpret_cast<float2*>(ACC1) + i * 64 + lane;
    float2 cur = *dst;
    cur.x += acc.x; cur.y += acc.y;
    *dst = cur;
}

// ---------------------------------------------------------------------------
// GEMM2: H1 = relu(ACC1); Y2p = H1 @ Wp2 ; ACC2 = H1 @ Ws2 + (bs2 + bp2)
// ---------------------------------------------------------------------------
__global__ __launch_bounds__(256) void k_gemm2(
    const float* __restrict__ A1,
    const float* __restrict__ Wp, const float* __restrict__ bp,
    const float* __restrict__ Ws, const float* __restrict__ bs,
    float* __restrict__ Y2p, float* __restrict__ ACC2)
{
    __shared__ float Hs[16][128];
    const int t = threadIdx.x;
    const int base = blockIdx.x * (16 * 128);

    const float4* Av = reinterpret_cast<const float4*>(A1 + base);
    float4* Hsv = reinterpret_cast<float4*>(&Hs[0][0]);
    float4 v0 = Av[t];
    float4 v1 = Av[t + 256];
    v0.x = fmaxf(v0.x, 0.f); v0.y = fmaxf(v0.y, 0.f);
    v0.z = fmaxf(v0.z, 0.f); v0.w = fmaxf(v0.w, 0.f);
    v1.x = fmaxf(v1.x, 0.f); v1.y = fmaxf(v1.y, 0.f);
    v1.z = fmaxf(v1.z, 0.f); v1.w = fmaxf(v1.w, 0.f);
    Hsv[t] = v0;
    Hsv[t + 256] = v1;
    __syncthreads();

    const int c = t & 63;
    const bool self_path = (t & 64) != 0;
    const int rb = (t >> 7) * 8;
    const float* __restrict__ W = self_path ? Ws : Wp;

    float acc[8];
#pragma unroll
    for (int r = 0; r < 8; ++r) acc[r] = 0.f;

#pragma unroll 4
    for (int k = 0; k < 128; ++k) {
        const float w = W[k * 64 + c];
#pragma unroll
        for (int r = 0; r < 8; ++r) acc[r] = fmaf(Hs[rb + r][k], w, acc[r]);
    }

    const int obase = blockIdx.x * (16 * 64);
    float* __restrict__ Out = self_path ? ACC2 : Y2p;
    const float bias = self_path ? (bs[c] + bp[c]) : 0.f;
#pragma unroll
    for (int r = 0; r < 8; ++r) Out[obase + (rb + r) * 64 + c] = acc[r] + bias;
}

// ---------------------------------------------------------------------------
// agg2: ACC2[i] += sum val_j * Y2p[col_j]   (64 feats, 1 float/lane)
// ---------------------------------------------------------------------------
__global__ __launch_bounds__(256) void k_agg2(
    const int* __restrict__ rowptr, const int* __restrict__ ecol_s,
    const float* __restrict__ eval_s,
    const float* __restrict__ Y2p, float* __restrict__ ACC2)
{
    const unsigned tid = blockIdx.x * 256u + threadIdx.x;
    const unsigned i = tid >> 6;
    if (i >= N_NODES) return;
    const unsigned lane = tid & 63u;

    const int e0 = (i == 0) ? 0 : rowptr[i - 1];
    const int e1 = rowptr[i];

    float acc = 0.f;
    if (e0 < e1) {
        int c = ecol_s[e0];
        float v = eval_s[e0];
        for (int j = e0; j < e1; ++j) {
            int cn = 0; float vn = 0.f;
            if (j + 1 < e1) { cn = ecol_s[j + 1]; vn = eval_s[j + 1]; }
            acc = fmaf(v, Y2p[c * 64 + lane], acc);
            c = cn; v = vn;
        }
    }
    ACC2[i * 64 + lane] += acc;
}

// ---------------------------------------------------------------------------
// edgedot: out[e] = sigmoid( dot( relu(ACC2[row]), relu(ACC2[col]) ) )
// ---------------------------------------------------------------------------
__global__ __launch_bounds__(256) void k_edgedot(
    const int* __restrict__ er, const int* __restrict__ ec,
    const float* __restrict__ ACC2, float* __restrict__ out)
{
    const unsigned tid = blockIdx.x * 256u + threadIdx.x;
    const unsigned e = tid >> 6;
    if (e >= N_EDGES) return;
    const unsigned d = tid & 63u;

    const int r = er[e];
    const int c = ec[e];

    const float a = fmaxf(ACC2[r * 64 + d], 0.f);
    const float b = fmaxf(ACC2[c * 64 + d], 0.f);
    float p = a * b;

#pragma unroll
    for (int off = 32; off; off >>= 1) p += __shfl_xor(p, off, 64);

    if (d == 0) out[e] = 1.f / (1.f + expf(-p));
}

// ---------------------------------------------------------------------------
extern "C" void kernel_launch(void* const* d_in, const int* in_sizes, int n_in,
                              void* d_out, int out_size, void* d_ws, size_t ws_size,
                              hipStream_t stream)
{
    const float* X   = (const float*)d_in[0];
    const int*   er  = (const int*)d_in[1];
    const int*   ec  = (const int*)d_in[2];
    const float* ev  = (const float*)d_in[3];
    const float* Wp1 = (const float*)d_in[4];
    const float* bp1 = (const float*)d_in[5];
    const float* Ws1 = (const float*)d_in[6];
    const float* bs1 = (const float*)d_in[7];
    const float* Wp2 = (const float*)d_in[8];
    const float* bp2 = (const float*)d_in[9];
    const float* Ws2 = (const float*)d_in[10];
    const float* bs2 = (const float*)d_in[11];
    float* out = (float*)d_out;

    // workspace layout (floats):
    //   [0      , 6.4M )  Y1p    (later reused: Y2p [0,3.2M), ACC2 [3.2M,6.4M))
    //   [6.4M   , 12.8M)  ACC1
    //   [12.8M  , ...  )  rowptr[50001] | ecol_s[800k] | eval_s[800k]
    float* Y1p   = (float*)d_ws;
    float* ACC1  = Y1p + (size_t)N_NODES * 128;
    float* Y2p   = (float*)d_ws;
    float* ACC2  = (float*)d_ws + (size_t)N_NODES * 64;
    int*   rowptr = (int*)(ACC1 + (size_t)N_NODES * 128);
    int*   ecol_s = rowptr + (N_NODES + 1);
    float* eval_s = (float*)(ecol_s + N_EDGES);

    const dim3 blk(256);
    const int node_waves  = (N_NODES * 64 + 255) / 256;   // 12500
    const int edge_waves  = (N_EDGES * 64 + 255) / 256;   // 200000
    const int edge_thr    = (N_EDGES + 255) / 256;        // 3125
    const int node_thr    = (N_NODES + 256) / 256;        // covers N_NODES+1

    // CSR build
    k_zero   <<<node_thr, blk, 0, stream>>>(rowptr);
    k_hist   <<<edge_thr, blk, 0, stream>>>(er, rowptr);
    k_scan   <<<1, 1024, 0, stream>>>(rowptr);
    k_reorder<<<edge_thr, blk, 0, stream>>>(er, ec, ev, rowptr, ecol_s, eval_s);

    // layer 1
    k_gemm1<<<N_NODES / 16, blk, 0, stream>>>(X, Wp1, bp1, Ws1, bs1, Y1p, ACC1);
    k_agg1 <<<node_waves,   blk, 0, stream>>>(rowptr, ecol_s, eval_s, Y1p, ACC1);

    // layer 2
    k_gemm2<<<N_NODES / 16, blk, 0, stream>>>(ACC1, Wp2, bp2, Ws2, bs2, Y2p, ACC2);
    k_agg2 <<<node_waves,   blk, 0, stream>>>(rowptr, ecol_s, eval_s, Y2p, ACC2);

    // edge scores
    k_edgedot<<<edge_waves, blk, 0, stream>>>(er, ec, ACC2, out);
}

// Round 3
// 523.468 us; speedup vs baseline: 2.0198x; 1.1374x over previous
//
#include <hip/hip_runtime.h>
#include <hip/hip_bf16.h>
#include <math.h>

#define N_NODES 50000
#define N_EDGES 800000

typedef unsigned short u16;
typedef unsigned int   u32;

static __device__ __forceinline__ float b2f(u16 u) {
    union { u32 i; float f; } x; x.i = ((u32)u) << 16; return x.f;
}
static __device__ __forceinline__ u16 f2b(float f) {
    union { float f; u32 i; } x; x.f = f;
    u32 r = x.i + 0x7fffu + ((x.i >> 16) & 1u);   // round-to-nearest-even
    return (u16)(r >> 16);
}

// ---------------------------------------------------------------------------
// CSR build: k_zero -> k_hist -> k_scan (1 block) -> k_reorder
// After reorder, rowptr[i] == start(i+1); start(i) = (i ? rowptr[i-1] : 0).
// ---------------------------------------------------------------------------
__global__ __launch_bounds__(256) void k_zero(int* __restrict__ rowptr)
{
    const int i = blockIdx.x * 256 + threadIdx.x;
    if (i <= N_NODES) rowptr[i] = 0;
}

__global__ __launch_bounds__(256) void k_hist(
    const int* __restrict__ er, int* __restrict__ rowptr)
{
    const int e = blockIdx.x * 256 + threadIdx.x;
    if (e < N_EDGES) atomicAdd(&rowptr[er[e] + 1], 1);
}

__global__ __launch_bounds__(1024) void k_scan(int* __restrict__ rowptr)
{
    const int T = 1024;
    const int CH = (N_NODES + T - 1) / T;
    __shared__ int partial[T];
    const int t = threadIdx.x;
    const int begin = 1 + t * CH;
    int end = 1 + (t + 1) * CH;
    if (end > N_NODES + 1) end = N_NODES + 1;

    int s = 0;
    for (int i = begin; i < end; ++i) { s += rowptr[i]; rowptr[i] = s; }
    partial[t] = s;
    __syncthreads();
    if (t == 0) {
        int run = 0;
        for (int i = 0; i < T; ++i) { int v = partial[i]; partial[i] = run; run += v; }
    }
    __syncthreads();
    const int add = partial[t];
    for (int i = begin; i < end; ++i) rowptr[i] += add;
    if (t == 0) rowptr[0] = 0;
}

__global__ __launch_bounds__(256) void k_reorder(
    const int* __restrict__ er, const int* __restrict__ ec,
    const float* __restrict__ ev, int* __restrict__ rowptr,
    int* __restrict__ ecol_s, float* __restrict__ eval_s)
{
    const int e = blockIdx.x * 256 + threadIdx.x;
    if (e >= N_EDGES) return;
    const int r = er[e];
    const int slot = atomicAdd(&rowptr[r], 1);
    ecol_s[slot] = ec[e];
    eval_s[slot] = ev[e];
}

// ---------------------------------------------------------------------------
// GEMM1: Y1pb (bf16) = X @ Wp1 ; ACC1 (f32) = X @ Ws1 + (bs1 + bp1)
// ---------------------------------------------------------------------------
__global__ __launch_bounds__(256) void k_gemm1(
    const float* __restrict__ X,
    const float* __restrict__ Wp, const float* __restrict__ bp,
    const float* __restrict__ Ws, const float* __restrict__ bs,
    u16* __restrict__ Y1pb, float* __restrict__ ACC1)
{
    __shared__ float Xs[16][128];
    const int t = threadIdx.x;
    const int base = blockIdx.x * (16 * 128);

    const float4* Xv = reinterpret_cast<const float4*>(X + base);
    float4* Xsv = reinterpret_cast<float4*>(&Xs[0][0]);
    Xsv[t] = Xv[t];
    Xsv[t + 256] = Xv[t + 256];
    __syncthreads();

    const int c = t & 127;
    const bool self_path = (t >= 128);
    const float* __restrict__ W = self_path ? Ws : Wp;

    float acc[16];
#pragma unroll
    for (int r = 0; r < 16; ++r) acc[r] = 0.f;

#pragma unroll 4
    for (int k = 0; k < 128; ++k) {
        const float w = W[k * 128 + c];
#pragma unroll
        for (int r = 0; r < 16; ++r) acc[r] = fmaf(Xs[r][k], w, acc[r]);
    }

    if (self_path) {
        const float bias = bs[c] + bp[c];
#pragma unroll
        for (int r = 0; r < 16; ++r) ACC1[base + r * 128 + c] = acc[r] + bias;
    } else {
#pragma unroll
        for (int r = 0; r < 16; ++r) Y1pb[base + r * 128 + c] = f2b(acc[r]);
    }
}

// ---------------------------------------------------------------------------
// agg1: H1b[i] = relu( ACC1[i] + sum val_j * Y1pb[col_j] )    (bf16 out)
// one wave per node; lane handles 2 features (bf16x2 gather).
// ---------------------------------------------------------------------------
__global__ __launch_bounds__(256) void k_agg1(
    const int* __restrict__ rowptr, const int* __restrict__ ecol_s,
    const float* __restrict__ eval_s,
    const u16* __restrict__ Y1pb, const float* __restrict__ ACC1,
    u16* __restrict__ H1b)
{
    const unsigned tid = blockIdx.x * 256u + threadIdx.x;
    const unsigned i = tid >> 6;
    if (i >= N_NODES) return;
    const unsigned lane = tid & 63u;

    const int e0 = (i == 0) ? 0 : rowptr[i - 1];
    const int e1 = rowptr[i];

    const u32* __restrict__ Yv = reinterpret_cast<const u32*>(Y1pb);

    float ax = 0.f, ay = 0.f;
    if (e0 < e1) {
        int c = ecol_s[e0];
        float v = eval_s[e0];
        for (int j = e0; j < e1; ++j) {
            int cn = 0; float vn = 0.f;
            if (j + 1 < e1) { cn = ecol_s[j + 1]; vn = eval_s[j + 1]; }
            const u32 w = Yv[c * 64 + lane];
            ax = fmaf(v, b2f((u16)(w & 0xffffu)), ax);
            ay = fmaf(v, b2f((u16)(w >> 16)), ay);
            c = cn; v = vn;
        }
    }
    const float2 s = reinterpret_cast<const float2*>(ACC1)[i * 64 + lane];
    const float h0 = fmaxf(s.x + ax, 0.f);
    const float h1 = fmaxf(s.y + ay, 0.f);
    reinterpret_cast<u32*>(H1b)[i * 64 + lane] = (u32)f2b(h0) | ((u32)f2b(h1) << 16);
}

// ---------------------------------------------------------------------------
// GEMM2: reads H1b (bf16, already relu'd); Y2pb (bf16) = H1 @ Wp2 ;
//        ACC2 (f32) = H1 @ Ws2 + (bs2 + bp2)
// ---------------------------------------------------------------------------
__global__ __launch_bounds__(256) void k_gemm2(
    const u16* __restrict__ H1b,
    const float* __restrict__ Wp, const float* __restrict__ bp,
    const float* __restrict__ Ws, const float* __restrict__ bs,
    u16* __restrict__ Y2pb, float* __restrict__ ACC2)
{
    __shared__ float Hs[16][128];
    const int t = threadIdx.x;
    const int base = blockIdx.x * (16 * 128);

    // stage: 2048 bf16 = 256 threads x 8 bf16 (one uint4 each)
    {
        const uint4 w = reinterpret_cast<const uint4*>(H1b + base)[t];
        float* dst = &Hs[0][0] + t * 8;
        dst[0] = b2f((u16)(w.x & 0xffffu)); dst[1] = b2f((u16)(w.x >> 16));
        dst[2] = b2f((u16)(w.y & 0xffffu)); dst[3] = b2f((u16)(w.y >> 16));
        dst[4] = b2f((u16)(w.z & 0xffffu)); dst[5] = b2f((u16)(w.z >> 16));
        dst[6] = b2f((u16)(w.w & 0xffffu)); dst[7] = b2f((u16)(w.w >> 16));
    }
    __syncthreads();

    const int c = t & 63;
    const bool self_path = (t & 64) != 0;
    const int rb = (t >> 7) * 8;
    const float* __restrict__ W = self_path ? Ws : Wp;

    float acc[8];
#pragma unroll
    for (int r = 0; r < 8; ++r) acc[r] = 0.f;

#pragma unroll 4
    for (int k = 0; k < 128; ++k) {
        const float w = W[k * 64 + c];
#pragma unroll
        for (int r = 0; r < 8; ++r) acc[r] = fmaf(Hs[rb + r][k], w, acc[r]);
    }

    const int obase = blockIdx.x * (16 * 64);
    if (self_path) {
        const float bias = bs[c] + bp[c];
#pragma unroll
        for (int r = 0; r < 8; ++r) ACC2[obase + (rb + r) * 64 + c] = acc[r] + bias;
    } else {
#pragma unroll
        for (int r = 0; r < 8; ++r) Y2pb[obase + (rb + r) * 64 + c] = f2b(acc[r]);
    }
}

// ---------------------------------------------------------------------------
// agg2: H2b[i] = relu( ACC2[i] + sum val_j * Y2pb[col_j] )   (bf16 out)
// ---------------------------------------------------------------------------
__global__ __launch_bounds__(256) void k_agg2(
    const int* __restrict__ rowptr, const int* __restrict__ ecol_s,
    const float* __restrict__ eval_s,
    const u16* __restrict__ Y2pb, const float* __restrict__ ACC2,
    u16* __restrict__ H2b)
{
    const unsigned tid = blockIdx.x * 256u + threadIdx.x;
    const unsigned i = tid >> 6;
    if (i >= N_NODES) return;
    const unsigned lane = tid & 63u;

    const int e0 = (i == 0) ? 0 : rowptr[i - 1];
    const int e1 = rowptr[i];

    float acc = 0.f;
    if (e0 < e1) {
        int c = ecol_s[e0];
        float v = eval_s[e0];
        for (int j = e0; j < e1; ++j) {
            int cn = 0; float vn = 0.f;
            if (j + 1 < e1) { cn = ecol_s[j + 1]; vn = eval_s[j + 1]; }
            acc = fmaf(v, b2f(Y2pb[c * 64 + lane]), acc);
            c = cn; v = vn;
        }
    }
    const float h = fmaxf(ACC2[i * 64 + lane] + acc, 0.f);
    H2b[i * 64 + lane] = f2b(h);
}

// ---------------------------------------------------------------------------
// edgedot: out[e] = sigmoid( dot(H2[row], H2[col]) )  (H2b already relu'd)
// 2 edges per wave: 32 lanes/edge, bf16x2 per lane.
// ---------------------------------------------------------------------------
__global__ __launch_bounds__(256) void k_edgedot(
    const int* __restrict__ er, const int* __restrict__ ec,
    const u16* __restrict__ H2b, float* __restrict__ out)
{
    const unsigned tid = blockIdx.x * 256u + threadIdx.x;
    const unsigned e = tid >> 5;
    if (e >= N_EDGES) return;
    const unsigned hl = tid & 31u;

    const int r = er[e];
    const int c = ec[e];

    const u32* __restrict__ Hv = reinterpret_cast<const u32*>(H2b);
    const u32 wa = Hv[r * 32 + hl];
    const u32 wb = Hv[c * 32 + hl];

    float p = b2f((u16)(wa & 0xffffu)) * b2f((u16)(wb & 0xffffu))
            + b2f((u16)(wa >> 16))     * b2f((u16)(wb >> 16));

#pragma unroll
    for (int off = 16; off; off >>= 1) p += __shfl_xor(p, off, 64);

    if (hl == 0) out[e] = 1.f / (1.f + expf(-p));
}

// ---------------------------------------------------------------------------
extern "C" void kernel_launch(void* const* d_in, const int* in_sizes, int n_in,
                              void* d_out, int out_size, void* d_ws, size_t ws_size,
                              hipStream_t stream)
{
    const float* X   = (const float*)d_in[0];
    const int*   er  = (const int*)d_in[1];
    const int*   ec  = (const int*)d_in[2];
    const float* ev  = (const float*)d_in[3];
    const float* Wp1 = (const float*)d_in[4];
    const float* bp1 = (const float*)d_in[5];
    const float* Ws1 = (const float*)d_in[6];
    const float* bs1 = (const float*)d_in[7];
    const float* Wp2 = (const float*)d_in[8];
    const float* bp2 = (const float*)d_in[9];
    const float* Ws2 = (const float*)d_in[10];
    const float* bs2 = (const float*)d_in[11];
    float* out = (float*)d_out;

    // workspace layout (float units from base):
    //   phase 1: ACC1 f32 [0, 6.4M) | Y1pb bf16 [6.4M, 9.6M) | H1b bf16 [9.6M, 12.8M)
    //   phase 2 (reuses [0,6.4M)): Y2pb bf16 [0,1.6M) | ACC2 f32 [1.6M,4.8M) | H2b bf16 [4.8M,6.4M)
    //   CSR at [12.8M, ...): rowptr[50001] | ecol_s[800k] | eval_s[800k]
    float* ws    = (float*)d_ws;
    float* ACC1  = ws;
    u16*   Y1pb  = (u16*)(ws + (size_t)N_NODES * 128);
    u16*   H1b   = (u16*)(ws + (size_t)N_NODES * 128 + (size_t)N_NODES * 64);
    u16*   Y2pb  = (u16*)ws;
    float* ACC2  = ws + (size_t)N_NODES * 32;
    u16*   H2b   = (u16*)(ws + (size_t)N_NODES * 32 + (size_t)N_NODES * 64);
    int*   rowptr = (int*)(ws + (size_t)N_NODES * 256);
    int*   ecol_s = rowptr + (N_NODES + 4);
    float* eval_s = (float*)(ecol_s + N_EDGES);

    const dim3 blk(256);
    const int node_waves = (N_NODES * 64 + 255) / 256;    // 12500
    const int edge_hw    = (N_EDGES * 32 + 255) / 256;    // 100000
    const int edge_thr   = (N_EDGES + 255) / 256;         // 3125
    const int node_thr   = (N_NODES + 256) / 256;

    // CSR build
    k_zero   <<<node_thr, blk, 0, stream>>>(rowptr);
    k_hist   <<<edge_thr, blk, 0, stream>>>(er, rowptr);
    k_scan   <<<1, 1024, 0, stream>>>(rowptr);
    k_reorder<<<edge_thr, blk, 0, stream>>>(er, ec, ev, rowptr, ecol_s, eval_s);

    // layer 1
    k_gemm1<<<N_NODES / 16, blk, 0, stream>>>(X, Wp1, bp1, Ws1, bs1, Y1pb, ACC1);
    k_agg1 <<<node_waves,   blk, 0, stream>>>(rowptr, ecol_s, eval_s, Y1pb, ACC1, H1b);

    // layer 2
    k_gemm2<<<N_NODES / 16, blk, 0, stream>>>(H1b, Wp2, bp2, Ws2, bs2, Y2pb, ACC2);
    k_agg2 <<<node_waves,   blk, 0, stream>>>(rowptr, ecol_s, eval_s, Y2pb, ACC2, H2b);

    // edge scores
    k_edgedot<<<edge_hw, blk, 0, stream>>>(er, ec, H2b, out);
}

// Round 4
// 324.197 us; speedup vs baseline: 3.2613x; 1.6147x over previous
//
#include <hip/hip_runtime.h>
#include <hip/hip_bf16.h>
#include <math.h>

#define N_NODES 50000
#define N_EDGES 800000

typedef unsigned short u16;
typedef unsigned int   u32;

static __device__ __forceinline__ float b2f(u16 u) {
    union { u32 i; float f; } x; x.i = ((u32)u) << 16; return x.f;
}
static __device__ __forceinline__ u16 f2b(float f) {
    union { float f; u32 i; } x; x.f = f;
    u32 r = x.i + 0x7fffu + ((x.i >> 16) & 1u);   // round-to-nearest-even
    return (u16)(r >> 16);
}

// ---------------------------------------------------------------------------
// CSR build: zero -> hist -> scan1 (49 blk) -> scan3 (offsets) -> reorder
// cnt[50000] histogram; scan writes rowptr[1..50000] (rowptr[0]=0).
// reorder's atomicAdd(&rowptr[r],1) hands out slots; afterwards
// rowptr[i] == start(i+1); start(i) = (i ? rowptr[i-1] : 0).
// ---------------------------------------------------------------------------
__global__ __launch_bounds__(256) void k_zero(int* __restrict__ cnt)
{
    const int i = blockIdx.x * 256 + threadIdx.x;
    if (i < N_NODES) cnt[i] = 0;
}

__global__ __launch_bounds__(256) void k_hist(
    const int* __restrict__ er, int* __restrict__ cnt)
{
    const int e = blockIdx.x * 256 + threadIdx.x;
    if (e < N_EDGES) atomicAdd(&cnt[er[e]], 1);
}

// 49 blocks x 256 thr, 4 ints/thread (int4). Inclusive scan within block,
// block totals to bsum[b]. Writes rowptr[1+4g .. 1+4g+3] (16B-aligned).
__global__ __launch_bounds__(256) void k_scan1(
    const int* __restrict__ cnt, int* __restrict__ rowptr, int* __restrict__ bsum)
{
    __shared__ int wsum[4];
    const int t = threadIdx.x;
    const int g4 = blockIdx.x * 256 + t;
    int4 v = make_int4(0, 0, 0, 0);
    if (g4 < 12500) v = reinterpret_cast<const int4*>(cnt)[g4];
    const int s0 = v.x, s1 = s0 + v.y, s2 = s1 + v.z, s3 = s2 + v.w;

    const int lane = t & 63, wv = t >> 6;
    int incl = s3;
#pragma unroll
    for (int off = 1; off < 64; off <<= 1) {
        int u = __shfl_up(incl, off, 64);
        if (lane >= off) incl += u;
    }
    if (lane == 63) wsum[wv] = incl;
    __syncthreads();
    int woff = 0;
    if (wv > 0) woff += wsum[0];
    if (wv > 1) woff += wsum[1];
    if (wv > 2) woff += wsum[2];
    const int excl = woff + incl - s3;

    if (g4 < 12500) {
        int4 o;
        o.x = excl + s0; o.y = excl + s1; o.z = excl + s2; o.w = excl + s3;
        reinterpret_cast<int4*>(rowptr + 1)[g4] = o;
    }
    if (t == 255) bsum[blockIdx.x] = woff + incl;
}

// 49 blocks: block b adds sum(bsum[0..b-1]) to its 1024 rowptr entries.
__global__ __launch_bounds__(256) void k_scan3(
    int* __restrict__ rowptr, const int* __restrict__ bsum)
{
    __shared__ int s_add;
    const int b = blockIdx.x;
    const int t = threadIdx.x;
    if (t < 64) {
        int v = (t < b) ? bsum[t] : 0;
#pragma unroll
        for (int off = 32; off; off >>= 1) v += __shfl_xor(v, off, 64);
        if (t == 0) s_add = v;
    }
    __syncthreads();
    if (b == 0) {
        if (t == 0) rowptr[0] = 0;
        return;
    }
    const int add = s_add;
    const int g4 = b * 256 + t;
    if (g4 < 12500) {
        int4* o4 = reinterpret_cast<int4*>(rowptr + 1);
        int4 v = o4[g4];
        v.x += add; v.y += add; v.z += add; v.w += add;
        o4[g4] = v;
    }
}

__global__ __launch_bounds__(256) void k_reorder(
    const int* __restrict__ er, const int* __restrict__ ec,
    const float* __restrict__ ev, int* __restrict__ rowptr,
    int2* __restrict__ ecv)
{
    const int e = blockIdx.x * 256 + threadIdx.x;
    if (e >= N_EDGES) return;
    const int r = er[e];
    const int slot = atomicAdd(&rowptr[r], 1);
    ecv[slot] = make_int2(ec[e], __float_as_int(ev[e]));
}

// ---------------------------------------------------------------------------
// GEMM1: Y1pb (bf16) = X @ Wp1 ; ACC1 (f32) = X @ Ws1 + (bs1 + bp1)
// ---------------------------------------------------------------------------
__global__ __launch_bounds__(256) void k_gemm1(
    const float* __restrict__ X,
    const float* __restrict__ Wp, const float* __restrict__ bp,
    const float* __restrict__ Ws, const float* __restrict__ bs,
    u16* __restrict__ Y1pb, float* __restrict__ ACC1)
{
    __shared__ float Xs[16][128];
    const int t = threadIdx.x;
    const int base = blockIdx.x * (16 * 128);

    const float4* Xv = reinterpret_cast<const float4*>(X + base);
    float4* Xsv = reinterpret_cast<float4*>(&Xs[0][0]);
    Xsv[t] = Xv[t];
    Xsv[t + 256] = Xv[t + 256];
    __syncthreads();

    const int c = t & 127;
    const bool self_path = (t >= 128);
    const float* __restrict__ W = self_path ? Ws : Wp;

    float acc[16];
#pragma unroll
    for (int r = 0; r < 16; ++r) acc[r] = 0.f;

#pragma unroll 4
    for (int k = 0; k < 128; ++k) {
        const float w = W[k * 128 + c];
#pragma unroll
        for (int r = 0; r < 16; ++r) acc[r] = fmaf(Xs[r][k], w, acc[r]);
    }

    if (self_path) {
        const float bias = bs[c] + bp[c];
#pragma unroll
        for (int r = 0; r < 16; ++r) ACC1[base + r * 128 + c] = acc[r] + bias;
    } else {
#pragma unroll
        for (int r = 0; r < 16; ++r) Y1pb[base + r * 128 + c] = f2b(acc[r]);
    }
}

// ---------------------------------------------------------------------------
// agg1: H1b[i] = relu( ACC1[i] + sum val_j * Y1pb[col_j] )    (bf16 out)
// one wave per node, lane = 2 feats (u32); gather loop unrolled x4 for MLP.
// ---------------------------------------------------------------------------
__global__ __launch_bounds__(256) void k_agg1(
    const int* __restrict__ rowptr, const int2* __restrict__ ecv,
    const u16* __restrict__ Y1pb, const float* __restrict__ ACC1,
    u16* __restrict__ H1b)
{
    const unsigned tid = blockIdx.x * 256u + threadIdx.x;
    const unsigned i = tid >> 6;
    if (i >= N_NODES) return;
    const unsigned lane = tid & 63u;

    const int e0 = (i == 0) ? 0 : rowptr[i - 1];
    const int e1 = rowptr[i];

    const u32* __restrict__ Yv = reinterpret_cast<const u32*>(Y1pb);

    float ax0 = 0.f, ay0 = 0.f, ax1 = 0.f, ay1 = 0.f;
    float ax2 = 0.f, ay2 = 0.f, ax3 = 0.f, ay3 = 0.f;
    int j = e0;
    for (; j + 3 < e1; j += 4) {
        const int2 p0 = ecv[j], p1 = ecv[j + 1], p2 = ecv[j + 2], p3 = ecv[j + 3];
        const u32 w0 = Yv[p0.x * 64 + lane];
        const u32 w1 = Yv[p1.x * 64 + lane];
        const u32 w2 = Yv[p2.x * 64 + lane];
        const u32 w3 = Yv[p3.x * 64 + lane];
        const float v0 = __int_as_float(p0.y), v1 = __int_as_float(p1.y);
        const float v2 = __int_as_float(p2.y), v3 = __int_as_float(p3.y);
        ax0 = fmaf(v0, b2f((u16)(w0 & 0xffffu)), ax0); ay0 = fmaf(v0, b2f((u16)(w0 >> 16)), ay0);
        ax1 = fmaf(v1, b2f((u16)(w1 & 0xffffu)), ax1); ay1 = fmaf(v1, b2f((u16)(w1 >> 16)), ay1);
        ax2 = fmaf(v2, b2f((u16)(w2 & 0xffffu)), ax2); ay2 = fmaf(v2, b2f((u16)(w2 >> 16)), ay2);
        ax3 = fmaf(v3, b2f((u16)(w3 & 0xffffu)), ax3); ay3 = fmaf(v3, b2f((u16)(w3 >> 16)), ay3);
    }
    for (; j < e1; ++j) {
        const int2 p = ecv[j];
        const u32 w = Yv[p.x * 64 + lane];
        const float v = __int_as_float(p.y);
        ax0 = fmaf(v, b2f((u16)(w & 0xffffu)), ax0);
        ay0 = fmaf(v, b2f((u16)(w >> 16)), ay0);
    }
    const float ax = (ax0 + ax1) + (ax2 + ax3);
    const float ay = (ay0 + ay1) + (ay2 + ay3);

    const float2 s = reinterpret_cast<const float2*>(ACC1)[i * 64 + lane];
    const float h0 = fmaxf(s.x + ax, 0.f);
    const float h1 = fmaxf(s.y + ay, 0.f);
    reinterpret_cast<u32*>(H1b)[i * 64 + lane] = (u32)f2b(h0) | ((u32)f2b(h1) << 16);
}

// ---------------------------------------------------------------------------
// GEMM2: reads H1b (bf16, relu'd); Y2pb (bf16) = H1 @ Wp2 ;
//        ACC2 (f32) = H1 @ Ws2 + (bs2 + bp2)
// ---------------------------------------------------------------------------
__global__ __launch_bounds__(256) void k_gemm2(
    const u16* __restrict__ H1b,
    const float* __restrict__ Wp, const float* __restrict__ bp,
    const float* __restrict__ Ws, const float* __restrict__ bs,
    u16* __restrict__ Y2pb, float* __restrict__ ACC2)
{
    __shared__ float Hs[16][128];
    const int t = threadIdx.x;
    const int base = blockIdx.x * (16 * 128);

    {
        const uint4 w = reinterpret_cast<const uint4*>(H1b + base)[t];
        float* dst = &Hs[0][0] + t * 8;
        dst[0] = b2f((u16)(w.x & 0xffffu)); dst[1] = b2f((u16)(w.x >> 16));
        dst[2] = b2f((u16)(w.y & 0xffffu)); dst[3] = b2f((u16)(w.y >> 16));
        dst[4] = b2f((u16)(w.z & 0xffffu)); dst[5] = b2f((u16)(w.z >> 16));
        dst[6] = b2f((u16)(w.w & 0xffffu)); dst[7] = b2f((u16)(w.w >> 16));
    }
    __syncthreads();

    const int c = t & 63;
    const bool self_path = (t & 64) != 0;
    const int rb = (t >> 7) * 8;
    const float* __restrict__ W = self_path ? Ws : Wp;

    float acc[8];
#pragma unroll
    for (int r = 0; r < 8; ++r) acc[r] = 0.f;

#pragma unroll 4
    for (int k = 0; k < 128; ++k) {
        const float w = W[k * 64 + c];
#pragma unroll
        for (int r = 0; r < 8; ++r) acc[r] = fmaf(Hs[rb + r][k], w, acc[r]);
    }

    const int obase = blockIdx.x * (16 * 64);
    if (self_path) {
        const float bias = bs[c] + bp[c];
#pragma unroll
        for (int r = 0; r < 8; ++r) ACC2[obase + (rb + r) * 64 + c] = acc[r] + bias;
    } else {
#pragma unroll
        for (int r = 0; r < 8; ++r) Y2pb[obase + (rb + r) * 64 + c] = f2b(acc[r]);
    }
}

// ---------------------------------------------------------------------------
// agg2: H2b[i] = relu( ACC2[i] + sum val_j * Y2pb[col_j] )   (bf16 out)
// 2 nodes per wave: 32 lanes/node, u32 (2 feats)/lane; unrolled x4.
// ---------------------------------------------------------------------------
__global__ __launch_bounds__(256) void k_agg2(
    const int* __restrict__ rowptr, const int2* __restrict__ ecv,
    const u16* __restrict__ Y2pb, const float* __restrict__ ACC2,
    u16* __restrict__ H2b)
{
    const unsigned tid = blockIdx.x * 256u + threadIdx.x;
    const unsigned lane = tid & 63u;
    const unsigned i = (tid >> 6) * 2 + (lane >> 5);
    if (i >= N_NODES) return;
    const unsigned hl = lane & 31u;

    const int e0 = (i == 0) ? 0 : rowptr[i - 1];
    const int e1 = rowptr[i];

    const u32* __restrict__ Yv = reinterpret_cast<const u32*>(Y2pb);

    float ax0 = 0.f, ay0 = 0.f, ax1 = 0.f, ay1 = 0.f;
    float ax2 = 0.f, ay2 = 0.f, ax3 = 0.f, ay3 = 0.f;
    int j = e0;
    for (; j + 3 < e1; j += 4) {
        const int2 p0 = ecv[j], p1 = ecv[j + 1], p2 = ecv[j + 2], p3 = ecv[j + 3];
        const u32 w0 = Yv[p0.x * 32 + hl];
        const u32 w1 = Yv[p1.x * 32 + hl];
        const u32 w2 = Yv[p2.x * 32 + hl];
        const u32 w3 = Yv[p3.x * 32 + hl];
        const float v0 = __int_as_float(p0.y), v1 = __int_as_float(p1.y);
        const float v2 = __int_as_float(p2.y), v3 = __int_as_float(p3.y);
        ax0 = fmaf(v0, b2f((u16)(w0 & 0xffffu)), ax0); ay0 = fmaf(v0, b2f((u16)(w0 >> 16)), ay0);
        ax1 = fmaf(v1, b2f((u16)(w1 & 0xffffu)), ax1); ay1 = fmaf(v1, b2f((u16)(w1 >> 16)), ay1);
        ax2 = fmaf(v2, b2f((u16)(w2 & 0xffffu)), ax2); ay2 = fmaf(v2, b2f((u16)(w2 >> 16)), ay2);
        ax3 = fmaf(v3, b2f((u16)(w3 & 0xffffu)), ax3); ay3 = fmaf(v3, b2f((u16)(w3 >> 16)), ay3);
    }
    for (; j < e1; ++j) {
        const int2 p = ecv[j];
        const u32 w = Yv[p.x * 32 + hl];
        const float v = __int_as_float(p.y);
        ax0 = fmaf(v, b2f((u16)(w & 0xffffu)), ax0);
        ay0 = fmaf(v, b2f((u16)(w >> 16)), ay0);
    }
    const float ax = (ax0 + ax1) + (ax2 + ax3);
    const float ay = (ay0 + ay1) + (ay2 + ay3);

    const float2 s = reinterpret_cast<const float2*>(ACC2)[i * 32 + hl];
    const float h0 = fmaxf(s.x + ax, 0.f);
    const float h1 = fmaxf(s.y + ay, 0.f);
    reinterpret_cast<u32*>(H2b)[i * 32 + hl] = (u32)f2b(h0) | ((u32)f2b(h1) << 16);
}

// ---------------------------------------------------------------------------
// edgedot: out[e] = sigmoid( dot(H2[row], H2[col]) )  (H2b already relu'd)
// 2 edges per wave: 32 lanes/edge, bf16x2 per lane.
// ---------------------------------------------------------------------------
__global__ __launch_bounds__(256) void k_edgedot(
    const int* __restrict__ er, const int* __restrict__ ec,
    const u16* __restrict__ H2b, float* __restrict__ out)
{
    const unsigned tid = blockIdx.x * 256u + threadIdx.x;
    const unsigned e = tid >> 5;
    if (e >= N_EDGES) return;
    const unsigned hl = tid & 31u;

    const int r = er[e];
    const int c = ec[e];

    const u32* __restrict__ Hv = reinterpret_cast<const u32*>(H2b);
    const u32 wa = Hv[r * 32 + hl];
    const u32 wb = Hv[c * 32 + hl];

    float p = b2f((u16)(wa & 0xffffu)) * b2f((u16)(wb & 0xffffu))
            + b2f((u16)(wa >> 16))     * b2f((u16)(wb >> 16));

#pragma unroll
    for (int off = 16; off; off >>= 1) p += __shfl_xor(p, off, 64);

    if (hl == 0) out[e] = 1.f / (1.f + expf(-p));
}

// ---------------------------------------------------------------------------
extern "C" void kernel_launch(void* const* d_in, const int* in_sizes, int n_in,
                              void* d_out, int out_size, void* d_ws, size_t ws_size,
                              hipStream_t stream)
{
    const float* X   = (const float*)d_in[0];
    const int*   er  = (const int*)d_in[1];
    const int*   ec  = (const int*)d_in[2];
    const float* ev  = (const float*)d_in[3];
    const float* Wp1 = (const float*)d_in[4];
    const float* bp1 = (const float*)d_in[5];
    const float* Ws1 = (const float*)d_in[6];
    const float* bs1 = (const float*)d_in[7];
    const float* Wp2 = (const float*)d_in[8];
    const float* bp2 = (const float*)d_in[9];
    const float* Ws2 = (const float*)d_in[10];
    const float* bs2 = (const float*)d_in[11];
    float* out = (float*)d_out;

    // workspace layout (float units from base):
    //   phase 1: ACC1 f32 [0, 6.4M) | Y1pb bf16 [6.4M, 9.6M) | H1b bf16 [9.6M, 12.8M)
    //   phase 2 (reuses [0,6.4M)): Y2pb bf16 [0,1.6M) | ACC2 f32 [1.6M,4.8M) | H2b bf16 [4.8M,6.4M)
    //   CSR at [12.8M,...): rp_base[50008] | bsum[64] | ecv int2[800k]
    //   cnt[50000] aliases ecv's head (dead before reorder writes ecv).
    float* ws    = (float*)d_ws;
    float* ACC1  = ws;
    u16*   Y1pb  = (u16*)(ws + (size_t)N_NODES * 128);
    u16*   H1b   = (u16*)(ws + (size_t)N_NODES * 128 + (size_t)N_NODES * 64);
    u16*   Y2pb  = (u16*)ws;
    float* ACC2  = ws + (size_t)N_NODES * 32;
    u16*   H2b   = (u16*)(ws + (size_t)N_NODES * 32 + (size_t)N_NODES * 64);

    int*  rp_base = (int*)(ws + (size_t)N_NODES * 256);
    int*  rowptr  = rp_base + 3;        // rowptr+1 is 16B-aligned
    int*  bsum    = rp_base + 50008;    // 16B-aligned
    int2* ecv     = (int2*)(bsum + 64); // 16B-aligned
    int*  cnt     = (int*)ecv;          // alias (dead before reorder)

    const dim3 blk(256);
    const int node_waves  = (N_NODES * 64 + 255) / 256;        // 12500
    const int node2_waves = ((N_NODES / 2) * 64 + 255) / 256;  // 6250
    const int edge_hw     = (N_EDGES * 32 + 255) / 256;        // 100000
    const int edge_thr    = (N_EDGES + 255) / 256;             // 3125
    const int node_thr    = (N_NODES + 255) / 256;             // 196
    const int scan_blocks = 49;                                // ceil(12500/256)

    // CSR build
    k_zero   <<<node_thr,    blk, 0, stream>>>(cnt);
    k_hist   <<<edge_thr,    blk, 0, stream>>>(er, cnt);
    k_scan1  <<<scan_blocks, blk, 0, stream>>>(cnt, rowptr, bsum);
    k_scan3  <<<scan_blocks, blk, 0, stream>>>(rowptr, bsum);
    k_reorder<<<edge_thr,    blk, 0, stream>>>(er, ec, ev, rowptr, ecv);

    // layer 1
    k_gemm1<<<N_NODES / 16, blk, 0, stream>>>(X, Wp1, bp1, Ws1, bs1, Y1pb, ACC1);
    k_agg1 <<<node_waves,   blk, 0, stream>>>(rowptr, ecv, Y1pb, ACC1, H1b);

    // layer 2
    k_gemm2<<<N_NODES / 16, blk, 0, stream>>>(H1b, Wp2, bp2, Ws2, bs2, Y2pb, ACC2);
    k_agg2 <<<node2_waves,  blk, 0, stream>>>(rowptr, ecv, Y2pb, ACC2, H2b);

    // edge scores
    k_edgedot<<<edge_hw, blk, 0, stream>>>(er, ec, H2b, out);
}

// Round 5
// 253.684 us; speedup vs baseline: 4.1678x; 1.2780x over previous
//
#include <hip/hip_runtime.h>
#include <hip/hip_bf16.h>
#include <math.h>

#define N_NODES 50000
#define N_EDGES 800000

typedef unsigned short u16;
typedef unsigned int   u32;
typedef short short8 __attribute__((ext_vector_type(8)));
typedef float f32x4  __attribute__((ext_vector_type(4)));

static __device__ __forceinline__ float b2f(u16 u) {
    union { u32 i; float f; } x; x.i = ((u32)u) << 16; return x.f;
}
static __device__ __forceinline__ u16 f2b(float f) {
    union { float f; u32 i; } x; x.f = f;
    u32 r = x.i + 0x7fffu + ((x.i >> 16) & 1u);   // round-to-nearest-even
    return (u16)(r >> 16);
}

// ---------------------------------------------------------------------------
// CSR build: zero -> hist -> scan1 (49 blk) -> scan3 -> reorder
// ---------------------------------------------------------------------------
__global__ __launch_bounds__(256) void k_zero(int* __restrict__ cnt)
{
    const int i = blockIdx.x * 256 + threadIdx.x;
    if (i < N_NODES) cnt[i] = 0;
}

__global__ __launch_bounds__(256) void k_hist(
    const int* __restrict__ er, int* __restrict__ cnt)
{
    const int e = blockIdx.x * 256 + threadIdx.x;
    if (e < N_EDGES) atomicAdd(&cnt[er[e]], 1);
}

__global__ __launch_bounds__(256) void k_scan1(
    const int* __restrict__ cnt, int* __restrict__ rowptr, int* __restrict__ bsum)
{
    __shared__ int wsum[4];
    const int t = threadIdx.x;
    const int g4 = blockIdx.x * 256 + t;
    int4 v = make_int4(0, 0, 0, 0);
    if (g4 < 12500) v = reinterpret_cast<const int4*>(cnt)[g4];
    const int s0 = v.x, s1 = s0 + v.y, s2 = s1 + v.z, s3 = s2 + v.w;

    const int lane = t & 63, wv = t >> 6;
    int incl = s3;
#pragma unroll
    for (int off = 1; off < 64; off <<= 1) {
        int u = __shfl_up(incl, off, 64);
        if (lane >= off) incl += u;
    }
    if (lane == 63) wsum[wv] = incl;
    __syncthreads();
    int woff = 0;
    if (wv > 0) woff += wsum[0];
    if (wv > 1) woff += wsum[1];
    if (wv > 2) woff += wsum[2];
    const int excl = woff + incl - s3;

    if (g4 < 12500) {
        int4 o;
        o.x = excl + s0; o.y = excl + s1; o.z = excl + s2; o.w = excl + s3;
        reinterpret_cast<int4*>(rowptr + 1)[g4] = o;
    }
    if (t == 255) bsum[blockIdx.x] = woff + incl;
}

__global__ __launch_bounds__(256) void k_scan3(
    int* __restrict__ rowptr, const int* __restrict__ bsum)
{
    __shared__ int s_add;
    const int b = blockIdx.x;
    const int t = threadIdx.x;
    if (t < 64) {
        int v = (t < b) ? bsum[t] : 0;
#pragma unroll
        for (int off = 32; off; off >>= 1) v += __shfl_xor(v, off, 64);
        if (t == 0) s_add = v;
    }
    __syncthreads();
    if (b == 0) {
        if (t == 0) rowptr[0] = 0;
        return;
    }
    const int add = s_add;
    const int g4 = b * 256 + t;
    if (g4 < 12500) {
        int4* o4 = reinterpret_cast<int4*>(rowptr + 1);
        int4 v = o4[g4];
        v.x += add; v.y += add; v.z += add; v.w += add;
        o4[g4] = v;
    }
}

__global__ __launch_bounds__(256) void k_reorder(
    const int* __restrict__ er, const int* __restrict__ ec,
    const float* __restrict__ ev, int* __restrict__ rowptr,
    int2* __restrict__ ecv)
{
    const int e = blockIdx.x * 256 + threadIdx.x;
    if (e >= N_EDGES) return;
    const int r = er[e];
    const int slot = atomicAdd(&rowptr[r], 1);
    ecv[slot] = make_int2(ec[e], __float_as_int(ev[e]));
}

// ---------------------------------------------------------------------------
// prepw: WT[n][k] = bf16(W[k][n]) for all 4 weight matrices.
// ---------------------------------------------------------------------------
__global__ __launch_bounds__(128) void k_prepw(
    const float* __restrict__ Wp1, const float* __restrict__ Ws1,
    const float* __restrict__ Wp2, const float* __restrict__ Ws2,
    u16* __restrict__ WT1p, u16* __restrict__ WT1s,
    u16* __restrict__ WT2p, u16* __restrict__ WT2s)
{
    const int b = blockIdx.x, k = threadIdx.x;
    const float* src; u16* dst; int N, n;
    if (b < 128)      { src = Wp1; N = 128; n = b;       dst = WT1p + n * 128; }
    else if (b < 256) { src = Ws1; N = 128; n = b - 128; dst = WT1s + n * 128; }
    else if (b < 320) { src = Wp2; N = 64;  n = b - 256; dst = WT2p + n * 128; }
    else              { src = Ws2; N = 64;  n = b - 320; dst = WT2s + n * 128; }
    dst[k] = f2b(src[k * N + n]);
}

// ---------------------------------------------------------------------------
// GEMM1 (MFMA): Y1pb (bf16) = X @ Wp1 ; ACC1 (f32) = X @ Ws1 + (bs1+bp1)
// block = 256 thr = 4 waves; tile 80 rows x 256 cols (625 blocks exact).
// wave w: matrix = w>>1 (0 pass / 1 self), cols (w&1)*64 .. +63 (4 n-tiles).
// LDS: X tile as bf16 [80][128], XOR-swizzled (elem ^= (row&7)<<3).
// ---------------------------------------------------------------------------
__global__ __launch_bounds__(256) void k_gemm1(
    const float* __restrict__ X,
    const u16* __restrict__ WT1p, const u16* __restrict__ WT1s,
    const float* __restrict__ bp, const float* __restrict__ bs,
    u16* __restrict__ Y1pb, float* __restrict__ ACC1)
{
    __shared__ u16 Xs[80 * 128];
    const int t = threadIdx.x;

    // stage: 2560 float4 reads -> bf16 -> swizzled LDS
    const float4* Xv = reinterpret_cast<const float4*>(X) + (size_t)blockIdx.x * 2560;
#pragma unroll
    for (int i = 0; i < 10; ++i) {
        const int f4 = t + 256 * i;
        const float4 v = Xv[f4];
        const int row = f4 >> 5, col4 = f4 & 31;
        const u32 lo = (u32)f2b(v.x) | ((u32)f2b(v.y) << 16);
        const u32 hi = (u32)f2b(v.z) | ((u32)f2b(v.w) << 16);
        const int e = row * 128 + ((col4 * 4) ^ ((row & 7) << 3));
        *reinterpret_cast<uint2*>(&Xs[e]) = make_uint2(lo, hi);
    }
    __syncthreads();

    const int lane = t & 63;
    const int w = t >> 6;
    const int mat = w >> 1;
    const int cbase = (w & 1) * 64;
    const u16* __restrict__ WT = mat ? WT1s : WT1p;
    const int lr = lane & 15;
    const int lk = (lane >> 4) * 8;

    f32x4 acc[5][4];
#pragma unroll
    for (int m = 0; m < 5; ++m)
#pragma unroll
        for (int n = 0; n < 4; ++n) acc[m][n] = (f32x4){0.f, 0.f, 0.f, 0.f};

#pragma unroll
    for (int kk = 0; kk < 4; ++kk) {
        short8 b[4];
#pragma unroll
        for (int n = 0; n < 4; ++n) {
            const int col = cbase + n * 16 + lr;
            b[n] = *reinterpret_cast<const short8*>(WT + col * 128 + kk * 32 + lk);
        }
#pragma unroll
        for (int m = 0; m < 5; ++m) {
            const int row = m * 16 + lr;
            const int e = row * 128 + ((kk * 32 + lk) ^ ((row & 7) << 3));
            const short8 a = *reinterpret_cast<const short8*>(&Xs[e]);
#pragma unroll
            for (int n = 0; n < 4; ++n)
                acc[m][n] = __builtin_amdgcn_mfma_f32_16x16x32_bf16(a, b[n], acc[m][n], 0, 0, 0);
        }
    }

    const int row0 = blockIdx.x * 80;
    const int rq = (lane >> 4) * 4;
    if (mat == 0) {
#pragma unroll
        for (int m = 0; m < 5; ++m)
#pragma unroll
            for (int n = 0; n < 4; ++n) {
                const int col = cbase + n * 16 + lr;
#pragma unroll
                for (int q = 0; q < 4; ++q)
                    Y1pb[(size_t)(row0 + m * 16 + rq + q) * 128 + col] = f2b(acc[m][n][q]);
            }
    } else {
        float bias[4];
#pragma unroll
        for (int n = 0; n < 4; ++n) {
            const int col = cbase + n * 16 + lr;
            bias[n] = bs[col] + bp[col];
        }
#pragma unroll
        for (int m = 0; m < 5; ++m)
#pragma unroll
            for (int n = 0; n < 4; ++n) {
                const int col = cbase + n * 16 + lr;
#pragma unroll
                for (int q = 0; q < 4; ++q)
                    ACC1[(size_t)(row0 + m * 16 + rq + q) * 128 + col] = acc[m][n][q] + bias[n];
            }
    }
}

// ---------------------------------------------------------------------------
// agg1: H1b[i] = relu( ACC1[i] + sum val_j * Y1pb[col_j] )    (bf16 out)
// ---------------------------------------------------------------------------
__global__ __launch_bounds__(256) void k_agg1(
    const int* __restrict__ rowptr, const int2* __restrict__ ecv,
    const u16* __restrict__ Y1pb, const float* __restrict__ ACC1,
    u16* __restrict__ H1b)
{
    const unsigned tid = blockIdx.x * 256u + threadIdx.x;
    const unsigned i = tid >> 6;
    if (i >= N_NODES) return;
    const unsigned lane = tid & 63u;

    const int e0 = (i == 0) ? 0 : rowptr[i - 1];
    const int e1 = rowptr[i];

    const u32* __restrict__ Yv = reinterpret_cast<const u32*>(Y1pb);

    float ax0 = 0.f, ay0 = 0.f, ax1 = 0.f, ay1 = 0.f;
    float ax2 = 0.f, ay2 = 0.f, ax3 = 0.f, ay3 = 0.f;
    int j = e0;
    for (; j + 3 < e1; j += 4) {
        const int2 p0 = ecv[j], p1 = ecv[j + 1], p2 = ecv[j + 2], p3 = ecv[j + 3];
        const u32 w0 = Yv[p0.x * 64 + lane];
        const u32 w1 = Yv[p1.x * 64 + lane];
        const u32 w2 = Yv[p2.x * 64 + lane];
        const u32 w3 = Yv[p3.x * 64 + lane];
        const float v0 = __int_as_float(p0.y), v1 = __int_as_float(p1.y);
        const float v2 = __int_as_float(p2.y), v3 = __int_as_float(p3.y);
        ax0 = fmaf(v0, b2f((u16)(w0 & 0xffffu)), ax0); ay0 = fmaf(v0, b2f((u16)(w0 >> 16)), ay0);
        ax1 = fmaf(v1, b2f((u16)(w1 & 0xffffu)), ax1); ay1 = fmaf(v1, b2f((u16)(w1 >> 16)), ay1);
        ax2 = fmaf(v2, b2f((u16)(w2 & 0xffffu)), ax2); ay2 = fmaf(v2, b2f((u16)(w2 >> 16)), ay2);
        ax3 = fmaf(v3, b2f((u16)(w3 & 0xffffu)), ax3); ay3 = fmaf(v3, b2f((u16)(w3 >> 16)), ay3);
    }
    for (; j < e1; ++j) {
        const int2 p = ecv[j];
        const u32 w = Yv[p.x * 64 + lane];
        const float v = __int_as_float(p.y);
        ax0 = fmaf(v, b2f((u16)(w & 0xffffu)), ax0);
        ay0 = fmaf(v, b2f((u16)(w >> 16)), ay0);
    }
    const float ax = (ax0 + ax1) + (ax2 + ax3);
    const float ay = (ay0 + ay1) + (ay2 + ay3);

    const float2 s = reinterpret_cast<const float2*>(ACC1)[i * 64 + lane];
    const float h0 = fmaxf(s.x + ax, 0.f);
    const float h1 = fmaxf(s.y + ay, 0.f);
    reinterpret_cast<u32*>(H1b)[i * 64 + lane] = (u32)f2b(h0) | ((u32)f2b(h1) << 16);
}

// ---------------------------------------------------------------------------
// GEMM2 (MFMA): Y2pb (bf16) = H1 @ Wp2 ; ACC2 (f32) = H1 @ Ws2 + (bs2+bp2)
// tile 80 rows x 128 cols; wave w: matrix = w>>1, cols (w&1)*32 .. +31.
// ---------------------------------------------------------------------------
__global__ __launch_bounds__(256) void k_gemm2(
    const u16* __restrict__ H1b,
    const u16* __restrict__ WT2p, const u16* __restrict__ WT2s,
    const float* __restrict__ bp, const float* __restrict__ bs,
    u16* __restrict__ Y2pb, float* __restrict__ ACC2)
{
    __shared__ u16 Hs[80 * 128];
    const int t = threadIdx.x;

    // stage: 1280 x 16B chunks of bf16 -> swizzled LDS
    const uint4* Hv = reinterpret_cast<const uint4*>(H1b) + (size_t)blockIdx.x * 1280;
#pragma unroll
    for (int i = 0; i < 5; ++i) {
        const int ch = t + 256 * i;
        const uint4 v = Hv[ch];
        const int row = ch >> 4, c16 = ch & 15;
        const int e = row * 128 + ((c16 * 8) ^ ((row & 7) << 3));
        *reinterpret_cast<uint4*>(&Hs[e]) = v;
    }
    __syncthreads();

    const int lane = t & 63;
    const int w = t >> 6;
    const int mat = w >> 1;
    const int cbase = (w & 1) * 32;
    const u16* __restrict__ WT = mat ? WT2s : WT2p;
    const int lr = lane & 15;
    const int lk = (lane >> 4) * 8;

    f32x4 acc[5][2];
#pragma unroll
    for (int m = 0; m < 5; ++m)
#pragma unroll
        for (int n = 0; n < 2; ++n) acc[m][n] = (f32x4){0.f, 0.f, 0.f, 0.f};

#pragma unroll
    for (int kk = 0; kk < 4; ++kk) {
        short8 b[2];
#pragma unroll
        for (int n = 0; n < 2; ++n) {
            const int col = cbase + n * 16 + lr;
            b[n] = *reinterpret_cast<const short8*>(WT + col * 128 + kk * 32 + lk);
        }
#pragma unroll
        for (int m = 0; m < 5; ++m) {
            const int row = m * 16 + lr;
            const int e = row * 128 + ((kk * 32 + lk) ^ ((row & 7) << 3));
            const short8 a = *reinterpret_cast<const short8*>(&Hs[e]);
#pragma unroll
            for (int n = 0; n < 2; ++n)
                acc[m][n] = __builtin_amdgcn_mfma_f32_16x16x32_bf16(a, b[n], acc[m][n], 0, 0, 0);
        }
    }

    const int row0 = blockIdx.x * 80;
    const int rq = (lane >> 4) * 4;
    if (mat == 0) {
#pragma unroll
        for (int m = 0; m < 5; ++m)
#pragma unroll
            for (int n = 0; n < 2; ++n) {
                const int col = cbase + n * 16 + lr;
#pragma unroll
                for (int q = 0; q < 4; ++q)
                    Y2pb[(size_t)(row0 + m * 16 + rq + q) * 64 + col] = f2b(acc[m][n][q]);
            }
    } else {
        float bias[2];
#pragma unroll
        for (int n = 0; n < 2; ++n) {
            const int col = cbase + n * 16 + lr;
            bias[n] = bs[col] + bp[col];
        }
#pragma unroll
        for (int m = 0; m < 5; ++m)
#pragma unroll
            for (int n = 0; n < 2; ++n) {
                const int col = cbase + n * 16 + lr;
#pragma unroll
                for (int q = 0; q < 4; ++q)
                    ACC2[(size_t)(row0 + m * 16 + rq + q) * 64 + col] = acc[m][n][q] + bias[n];
            }
    }
}

// ---------------------------------------------------------------------------
// agg2: H2b[i] = relu( ACC2[i] + sum val_j * Y2pb[col_j] )   (bf16 out)
// 2 nodes per wave: 32 lanes/node, u32 (2 feats)/lane; unrolled x4.
// ---------------------------------------------------------------------------
__global__ __launch_bounds__(256) void k_agg2(
    const int* __restrict__ rowptr, const int2* __restrict__ ecv,
    const u16* __restrict__ Y2pb, const float* __restrict__ ACC2,
    u16* __restrict__ H2b)
{
    const unsigned tid = blockIdx.x * 256u + threadIdx.x;
    const unsigned lane = tid & 63u;
    const unsigned i = (tid >> 6) * 2 + (lane >> 5);
    if (i >= N_NODES) return;
    const unsigned hl = lane & 31u;

    const int e0 = (i == 0) ? 0 : rowptr[i - 1];
    const int e1 = rowptr[i];

    const u32* __restrict__ Yv = reinterpret_cast<const u32*>(Y2pb);

    float ax0 = 0.f, ay0 = 0.f, ax1 = 0.f, ay1 = 0.f;
    float ax2 = 0.f, ay2 = 0.f, ax3 = 0.f, ay3 = 0.f;
    int j = e0;
    for (; j + 3 < e1; j += 4) {
        const int2 p0 = ecv[j], p1 = ecv[j + 1], p2 = ecv[j + 2], p3 = ecv[j + 3];
        const u32 w0 = Yv[p0.x * 32 + hl];
        const u32 w1 = Yv[p1.x * 32 + hl];
        const u32 w2 = Yv[p2.x * 32 + hl];
        const u32 w3 = Yv[p3.x * 32 + hl];
        const float v0 = __int_as_float(p0.y), v1 = __int_as_float(p1.y);
        const float v2 = __int_as_float(p2.y), v3 = __int_as_float(p3.y);
        ax0 = fmaf(v0, b2f((u16)(w0 & 0xffffu)), ax0); ay0 = fmaf(v0, b2f((u16)(w0 >> 16)), ay0);
        ax1 = fmaf(v1, b2f((u16)(w1 & 0xffffu)), ax1); ay1 = fmaf(v1, b2f((u16)(w1 >> 16)), ay1);
        ax2 = fmaf(v2, b2f((u16)(w2 & 0xffffu)), ax2); ay2 = fmaf(v2, b2f((u16)(w2 >> 16)), ay2);
        ax3 = fmaf(v3, b2f((u16)(w3 & 0xffffu)), ax3); ay3 = fmaf(v3, b2f((u16)(w3 >> 16)), ay3);
    }
    for (; j < e1; ++j) {
        const int2 p = ecv[j];
        const u32 w = Yv[p.x * 32 + hl];
        const float v = __int_as_float(p.y);
        ax0 = fmaf(v, b2f((u16)(w & 0xffffu)), ax0);
        ay0 = fmaf(v, b2f((u16)(w >> 16)), ay0);
    }
    const float ax = (ax0 + ax1) + (ax2 + ax3);
    const float ay = (ay0 + ay1) + (ay2 + ay3);

    const float2 s = reinterpret_cast<const float2*>(ACC2)[i * 32 + hl];
    const float h0 = fmaxf(s.x + ax, 0.f);
    const float h1 = fmaxf(s.y + ay, 0.f);
    reinterpret_cast<u32*>(H2b)[i * 32 + hl] = (u32)f2b(h0) | ((u32)f2b(h1) << 16);
}

// ---------------------------------------------------------------------------
// edgedot: out[e] = sigmoid( dot(H2[row], H2[col]) )
// ---------------------------------------------------------------------------
__global__ __launch_bounds__(256) void k_edgedot(
    const int* __restrict__ er, const int* __restrict__ ec,
    const u16* __restrict__ H2b, float* __restrict__ out)
{
    const unsigned tid = blockIdx.x * 256u + threadIdx.x;
    const unsigned e = tid >> 5;
    if (e >= N_EDGES) return;
    const unsigned hl = tid & 31u;

    const int r = er[e];
    const int c = ec[e];

    const u32* __restrict__ Hv = reinterpret_cast<const u32*>(H2b);
    const u32 wa = Hv[r * 32 + hl];
    const u32 wb = Hv[c * 32 + hl];

    float p = b2f((u16)(wa & 0xffffu)) * b2f((u16)(wb & 0xffffu))
            + b2f((u16)(wa >> 16))     * b2f((u16)(wb >> 16));

#pragma unroll
    for (int off = 16; off; off >>= 1) p += __shfl_xor(p, off, 64);

    if (hl == 0) out[e] = 1.f / (1.f + expf(-p));
}

// ---------------------------------------------------------------------------
extern "C" void kernel_launch(void* const* d_in, const int* in_sizes, int n_in,
                              void* d_out, int out_size, void* d_ws, size_t ws_size,
                              hipStream_t stream)
{
    const float* X   = (const float*)d_in[0];
    const int*   er  = (const int*)d_in[1];
    const int*   ec  = (const int*)d_in[2];
    const float* ev  = (const float*)d_in[3];
    const float* Wp1 = (const float*)d_in[4];
    const float* bp1 = (const float*)d_in[5];
    const float* Ws1 = (const float*)d_in[6];
    const float* bs1 = (const float*)d_in[7];
    const float* Wp2 = (const float*)d_in[8];
    const float* bp2 = (const float*)d_in[9];
    const float* Ws2 = (const float*)d_in[10];
    const float* bs2 = (const float*)d_in[11];
    float* out = (float*)d_out;

    // workspace layout (float units from base):
    //   phase 1: ACC1 f32 [0, 6.4M) | Y1pb bf16 [6.4M, 9.6M) | H1b bf16 [9.6M, 12.8M)
    //   phase 2 (reuses [0,6.4M)): Y2pb bf16 [0,1.6M) | ACC2 f32 [1.6M,4.8M) | H2b bf16 [4.8M,6.4M)
    //   CSR at [12.8M,...): rp_base[50008] | bsum[64] | ecv int2[800k] | WT bufs (96KB)
    //   cnt[50000] aliases ecv's head (dead before reorder writes ecv).
    float* ws    = (float*)d_ws;
    float* ACC1  = ws;
    u16*   Y1pb  = (u16*)(ws + (size_t)N_NODES * 128);
    u16*   H1b   = (u16*)(ws + (size_t)N_NODES * 128 + (size_t)N_NODES * 64);
    u16*   Y2pb  = (u16*)ws;
    float* ACC2  = ws + (size_t)N_NODES * 32;
    u16*   H2b   = (u16*)(ws + (size_t)N_NODES * 32 + (size_t)N_NODES * 64);

    int*  rp_base = (int*)(ws + (size_t)N_NODES * 256);
    int*  rowptr  = rp_base + 3;        // rowptr+1 is 16B-aligned
    int*  bsum    = rp_base + 50008;    // 16B-aligned
    int2* ecv     = (int2*)(bsum + 64); // 16B-aligned
    int*  cnt     = (int*)ecv;          // alias (dead before reorder)
    u16*  WT1p    = (u16*)(ecv + N_EDGES);  // 16B-aligned
    u16*  WT1s    = WT1p + 128 * 128;
    u16*  WT2p    = WT1s + 128 * 128;
    u16*  WT2s    = WT2p + 64 * 128;

    const dim3 blk(256);
    const int node_waves  = (N_NODES * 64 + 255) / 256;        // 12500
    const int node2_waves = ((N_NODES / 2) * 64 + 255) / 256;  // 6250
    const int edge_hw     = (N_EDGES * 32 + 255) / 256;        // 100000
    const int edge_thr    = (N_EDGES + 255) / 256;             // 3125
    const int node_thr    = (N_NODES + 255) / 256;             // 196
    const int scan_blocks = 49;
    const int gemm_blocks = N_NODES / 80;                      // 625 exact

    // weight prep + CSR build
    k_prepw  <<<384, 128, 0, stream>>>(Wp1, Ws1, Wp2, Ws2, WT1p, WT1s, WT2p, WT2s);
    k_zero   <<<node_thr,    blk, 0, stream>>>(cnt);
    k_hist   <<<edge_thr,    blk, 0, stream>>>(er, cnt);
    k_scan1  <<<scan_blocks, blk, 0, stream>>>(cnt, rowptr, bsum);
    k_scan3  <<<scan_blocks, blk, 0, stream>>>(rowptr, bsum);
    k_reorder<<<edge_thr,    blk, 0, stream>>>(er, ec, ev, rowptr, ecv);

    // layer 1
    k_gemm1<<<gemm_blocks, blk, 0, stream>>>(X, WT1p, WT1s, bp1, bs1, Y1pb, ACC1);
    k_agg1 <<<node_waves,  blk, 0, stream>>>(rowptr, ecv, Y1pb, ACC1, H1b);

    // layer 2
    k_gemm2<<<gemm_blocks, blk, 0, stream>>>(H1b, WT2p, WT2s, bp2, bs2, Y2pb, ACC2);
    k_agg2 <<<node2_waves, blk, 0, stream>>>(rowptr, ecv, Y2pb, ACC2, H2b);

    // edge scores
    k_edgedot<<<edge_hw, blk, 0, stream>>>(er, ec, H2b, out);
}

// Round 6
// 223.361 us; speedup vs baseline: 4.7337x; 1.1358x over previous
//
#include <hip/hip_runtime.h>
#include <hip/hip_bf16.h>
#include <math.h>

#define N_NODES 50000
#define N_EDGES 800000

typedef unsigned short u16;
typedef unsigned int   u32;
typedef short short8 __attribute__((ext_vector_type(8)));
typedef float f32x4  __attribute__((ext_vector_type(4)));

static __device__ __forceinline__ float b2f(u16 u) {
    union { u32 i; float f; } x; x.i = ((u32)u) << 16; return x.f;
}
static __device__ __forceinline__ u16 f2b(float f) {
    union { float f; u32 i; } x; x.f = f;
    u32 r = x.i + 0x7fffu + ((x.i >> 16) & 1u);   // round-to-nearest-even
    return (u16)(r >> 16);
}

// ---------------------------------------------------------------------------
// CSR build: zero -> hist -> scan1 (49 blk) -> scan3 -> reorder
// ---------------------------------------------------------------------------
__global__ __launch_bounds__(256) void k_zero(int* __restrict__ cnt)
{
    const int i = blockIdx.x * 256 + threadIdx.x;
    if (i < N_NODES) cnt[i] = 0;
}

__global__ __launch_bounds__(256) void k_hist(
    const int* __restrict__ er, int* __restrict__ cnt)
{
    const int e = blockIdx.x * 256 + threadIdx.x;
    if (e < N_EDGES) atomicAdd(&cnt[er[e]], 1);
}

__global__ __launch_bounds__(256) void k_scan1(
    const int* __restrict__ cnt, int* __restrict__ rowptr, int* __restrict__ bsum)
{
    __shared__ int wsum[4];
    const int t = threadIdx.x;
    const int g4 = blockIdx.x * 256 + t;
    int4 v = make_int4(0, 0, 0, 0);
    if (g4 < 12500) v = reinterpret_cast<const int4*>(cnt)[g4];
    const int s0 = v.x, s1 = s0 + v.y, s2 = s1 + v.z, s3 = s2 + v.w;

    const int lane = t & 63, wv = t >> 6;
    int incl = s3;
#pragma unroll
    for (int off = 1; off < 64; off <<= 1) {
        int u = __shfl_up(incl, off, 64);
        if (lane >= off) incl += u;
    }
    if (lane == 63) wsum[wv] = incl;
    __syncthreads();
    int woff = 0;
    if (wv > 0) woff += wsum[0];
    if (wv > 1) woff += wsum[1];
    if (wv > 2) woff += wsum[2];
    const int excl = woff + incl - s3;

    if (g4 < 12500) {
        int4 o;
        o.x = excl + s0; o.y = excl + s1; o.z = excl + s2; o.w = excl + s3;
        reinterpret_cast<int4*>(rowptr + 1)[g4] = o;
    }
    if (t == 255) bsum[blockIdx.x] = woff + incl;
}

__global__ __launch_bounds__(256) void k_scan3(
    int* __restrict__ rowptr, const int* __restrict__ bsum)
{
    __shared__ int s_add;
    const int b = blockIdx.x;
    const int t = threadIdx.x;
    if (t < 64) {
        int v = (t < b) ? bsum[t] : 0;
#pragma unroll
        for (int off = 32; off; off >>= 1) v += __shfl_xor(v, off, 64);
        if (t == 0) s_add = v;
    }
    __syncthreads();
    if (b == 0) {
        if (t == 0) rowptr[0] = 0;
        return;
    }
    const int add = s_add;
    const int g4 = b * 256 + t;
    if (g4 < 12500) {
        int4* o4 = reinterpret_cast<int4*>(rowptr + 1);
        int4 v = o4[g4];
        v.x += add; v.y += add; v.z += add; v.w += add;
        o4[g4] = v;
    }
}

__global__ __launch_bounds__(256) void k_reorder(
    const int* __restrict__ er, const int* __restrict__ ec,
    const float* __restrict__ ev, int* __restrict__ rowptr,
    int2* __restrict__ ecv)
{
    const int e = blockIdx.x * 256 + threadIdx.x;
    if (e >= N_EDGES) return;
    const int r = er[e];
    const int slot = atomicAdd(&rowptr[r], 1);
    ecv[slot] = make_int2(ec[e], __float_as_int(ev[e]));
}

// ---------------------------------------------------------------------------
// prepw: WT[n][k] = bf16(W[k][n]) for all 4 weight matrices.
// ---------------------------------------------------------------------------
__global__ __launch_bounds__(128) void k_prepw(
    const float* __restrict__ Wp1, const float* __restrict__ Ws1,
    const float* __restrict__ Wp2, const float* __restrict__ Ws2,
    u16* __restrict__ WT1p, u16* __restrict__ WT1s,
    u16* __restrict__ WT2p, u16* __restrict__ WT2s)
{
    const int b = blockIdx.x, k = threadIdx.x;
    const float* src; u16* dst; int N, n;
    if (b < 128)      { src = Wp1; N = 128; n = b;       dst = WT1p + n * 128; }
    else if (b < 256) { src = Ws1; N = 128; n = b - 128; dst = WT1s + n * 128; }
    else if (b < 320) { src = Wp2; N = 64;  n = b - 256; dst = WT2p + n * 128; }
    else              { src = Ws2; N = 64;  n = b - 320; dst = WT2s + n * 128; }
    dst[k] = f2b(src[k * N + n]);
}

// ---------------------------------------------------------------------------
// GEMM1 (MFMA): Y1pb (bf16) = X @ Wp1 ; ACC1 (f32) = X @ Ws1 + (bs1+bp1)
// ---------------------------------------------------------------------------
__global__ __launch_bounds__(256) void k_gemm1(
    const float* __restrict__ X,
    const u16* __restrict__ WT1p, const u16* __restrict__ WT1s,
    const float* __restrict__ bp, const float* __restrict__ bs,
    u16* __restrict__ Y1pb, float* __restrict__ ACC1)
{
    __shared__ u16 Xs[80 * 128];
    const int t = threadIdx.x;

    const float4* Xv = reinterpret_cast<const float4*>(X) + (size_t)blockIdx.x * 2560;
#pragma unroll
    for (int i = 0; i < 10; ++i) {
        const int f4 = t + 256 * i;
        const float4 v = Xv[f4];
        const int row = f4 >> 5, col4 = f4 & 31;
        const u32 lo = (u32)f2b(v.x) | ((u32)f2b(v.y) << 16);
        const u32 hi = (u32)f2b(v.z) | ((u32)f2b(v.w) << 16);
        const int e = row * 128 + ((col4 * 4) ^ ((row & 7) << 3));
        *reinterpret_cast<uint2*>(&Xs[e]) = make_uint2(lo, hi);
    }
    __syncthreads();

    const int lane = t & 63;
    const int w = t >> 6;
    const int mat = w >> 1;
    const int cbase = (w & 1) * 64;
    const u16* __restrict__ WT = mat ? WT1s : WT1p;
    const int lr = lane & 15;
    const int lk = (lane >> 4) * 8;

    f32x4 acc[5][4];
#pragma unroll
    for (int m = 0; m < 5; ++m)
#pragma unroll
        for (int n = 0; n < 4; ++n) acc[m][n] = (f32x4){0.f, 0.f, 0.f, 0.f};

#pragma unroll
    for (int kk = 0; kk < 4; ++kk) {
        short8 b[4];
#pragma unroll
        for (int n = 0; n < 4; ++n) {
            const int col = cbase + n * 16 + lr;
            b[n] = *reinterpret_cast<const short8*>(WT + col * 128 + kk * 32 + lk);
        }
#pragma unroll
        for (int m = 0; m < 5; ++m) {
            const int row = m * 16 + lr;
            const int e = row * 128 + ((kk * 32 + lk) ^ ((row & 7) << 3));
            const short8 a = *reinterpret_cast<const short8*>(&Xs[e]);
#pragma unroll
            for (int n = 0; n < 4; ++n)
                acc[m][n] = __builtin_amdgcn_mfma_f32_16x16x32_bf16(a, b[n], acc[m][n], 0, 0, 0);
        }
    }

    const int row0 = blockIdx.x * 80;
    const int rq = (lane >> 4) * 4;
    if (mat == 0) {
#pragma unroll
        for (int m = 0; m < 5; ++m)
#pragma unroll
            for (int n = 0; n < 4; ++n) {
                const int col = cbase + n * 16 + lr;
#pragma unroll
                for (int q = 0; q < 4; ++q)
                    Y1pb[(size_t)(row0 + m * 16 + rq + q) * 128 + col] = f2b(acc[m][n][q]);
            }
    } else {
        float bias[4];
#pragma unroll
        for (int n = 0; n < 4; ++n) {
            const int col = cbase + n * 16 + lr;
            bias[n] = bs[col] + bp[col];
        }
#pragma unroll
        for (int m = 0; m < 5; ++m)
#pragma unroll
            for (int n = 0; n < 4; ++n) {
                const int col = cbase + n * 16 + lr;
#pragma unroll
                for (int q = 0; q < 4; ++q)
                    ACC1[(size_t)(row0 + m * 16 + rq + q) * 128 + col] = acc[m][n][q] + bias[n];
            }
    }
}

// ---------------------------------------------------------------------------
// agg1: H1b[i] = relu( ACC1[i] + sum val_j * Y1pb[col_j] )    (bf16 out)
// ---------------------------------------------------------------------------
__global__ __launch_bounds__(256) void k_agg1(
    const int* __restrict__ rowptr, const int2* __restrict__ ecv,
    const u16* __restrict__ Y1pb, const float* __restrict__ ACC1,
    u16* __restrict__ H1b)
{
    const unsigned tid = blockIdx.x * 256u + threadIdx.x;
    const unsigned i = tid >> 6;
    if (i >= N_NODES) return;
    const unsigned lane = tid & 63u;

    const int e0 = (i == 0) ? 0 : rowptr[i - 1];
    const int e1 = rowptr[i];

    const u32* __restrict__ Yv = reinterpret_cast<const u32*>(Y1pb);

    float ax0 = 0.f, ay0 = 0.f, ax1 = 0.f, ay1 = 0.f;
    float ax2 = 0.f, ay2 = 0.f, ax3 = 0.f, ay3 = 0.f;
    int j = e0;
    for (; j + 3 < e1; j += 4) {
        const int2 p0 = ecv[j], p1 = ecv[j + 1], p2 = ecv[j + 2], p3 = ecv[j + 3];
        const u32 w0 = Yv[p0.x * 64 + lane];
        const u32 w1 = Yv[p1.x * 64 + lane];
        const u32 w2 = Yv[p2.x * 64 + lane];
        const u32 w3 = Yv[p3.x * 64 + lane];
        const float v0 = __int_as_float(p0.y), v1 = __int_as_float(p1.y);
        const float v2 = __int_as_float(p2.y), v3 = __int_as_float(p3.y);
        ax0 = fmaf(v0, b2f((u16)(w0 & 0xffffu)), ax0); ay0 = fmaf(v0, b2f((u16)(w0 >> 16)), ay0);
        ax1 = fmaf(v1, b2f((u16)(w1 & 0xffffu)), ax1); ay1 = fmaf(v1, b2f((u16)(w1 >> 16)), ay1);
        ax2 = fmaf(v2, b2f((u16)(w2 & 0xffffu)), ax2); ay2 = fmaf(v2, b2f((u16)(w2 >> 16)), ay2);
        ax3 = fmaf(v3, b2f((u16)(w3 & 0xffffu)), ax3); ay3 = fmaf(v3, b2f((u16)(w3 >> 16)), ay3);
    }
    for (; j < e1; ++j) {
        const int2 p = ecv[j];
        const u32 w = Yv[p.x * 64 + lane];
        const float v = __int_as_float(p.y);
        ax0 = fmaf(v, b2f((u16)(w & 0xffffu)), ax0);
        ay0 = fmaf(v, b2f((u16)(w >> 16)), ay0);
    }
    const float ax = (ax0 + ax1) + (ax2 + ax3);
    const float ay = (ay0 + ay1) + (ay2 + ay3);

    const float2 s = reinterpret_cast<const float2*>(ACC1)[i * 64 + lane];
    const float h0 = fmaxf(s.x + ax, 0.f);
    const float h1 = fmaxf(s.y + ay, 0.f);
    reinterpret_cast<u32*>(H1b)[i * 64 + lane] = (u32)f2b(h0) | ((u32)f2b(h1) << 16);
}

// ---------------------------------------------------------------------------
// GEMM2 (MFMA): Y2pb (bf16) = H1 @ Wp2 ; ACC2 (f32) = H1 @ Ws2 + (bs2+bp2)
// ---------------------------------------------------------------------------
__global__ __launch_bounds__(256) void k_gemm2(
    const u16* __restrict__ H1b,
    const u16* __restrict__ WT2p, const u16* __restrict__ WT2s,
    const float* __restrict__ bp, const float* __restrict__ bs,
    u16* __restrict__ Y2pb, float* __restrict__ ACC2)
{
    __shared__ u16 Hs[80 * 128];
    const int t = threadIdx.x;

    const uint4* Hv = reinterpret_cast<const uint4*>(H1b) + (size_t)blockIdx.x * 1280;
#pragma unroll
    for (int i = 0; i < 5; ++i) {
        const int ch = t + 256 * i;
        const uint4 v = Hv[ch];
        const int row = ch >> 4, c16 = ch & 15;
        const int e = row * 128 + ((c16 * 8) ^ ((row & 7) << 3));
        *reinterpret_cast<uint4*>(&Hs[e]) = v;
    }
    __syncthreads();

    const int lane = t & 63;
    const int w = t >> 6;
    const int mat = w >> 1;
    const int cbase = (w & 1) * 32;
    const u16* __restrict__ WT = mat ? WT2s : WT2p;
    const int lr = lane & 15;
    const int lk = (lane >> 4) * 8;

    f32x4 acc[5][2];
#pragma unroll
    for (int m = 0; m < 5; ++m)
#pragma unroll
        for (int n = 0; n < 2; ++n) acc[m][n] = (f32x4){0.f, 0.f, 0.f, 0.f};

#pragma unroll
    for (int kk = 0; kk < 4; ++kk) {
        short8 b[2];
#pragma unroll
        for (int n = 0; n < 2; ++n) {
            const int col = cbase + n * 16 + lr;
            b[n] = *reinterpret_cast<const short8*>(WT + col * 128 + kk * 32 + lk);
        }
#pragma unroll
        for (int m = 0; m < 5; ++m) {
            const int row = m * 16 + lr;
            const int e = row * 128 + ((kk * 32 + lk) ^ ((row & 7) << 3));
            const short8 a = *reinterpret_cast<const short8*>(&Hs[e]);
#pragma unroll
            for (int n = 0; n < 2; ++n)
                acc[m][n] = __builtin_amdgcn_mfma_f32_16x16x32_bf16(a, b[n], acc[m][n], 0, 0, 0);
        }
    }

    const int row0 = blockIdx.x * 80;
    const int rq = (lane >> 4) * 4;
    if (mat == 0) {
#pragma unroll
        for (int m = 0; m < 5; ++m)
#pragma unroll
            for (int n = 0; n < 2; ++n) {
                const int col = cbase + n * 16 + lr;
#pragma unroll
                for (int q = 0; q < 4; ++q)
                    Y2pb[(size_t)(row0 + m * 16 + rq + q) * 64 + col] = f2b(acc[m][n][q]);
            }
    } else {
        float bias[2];
#pragma unroll
        for (int n = 0; n < 2; ++n) {
            const int col = cbase + n * 16 + lr;
            bias[n] = bs[col] + bp[col];
        }
#pragma unroll
        for (int m = 0; m < 5; ++m)
#pragma unroll
            for (int n = 0; n < 2; ++n) {
                const int col = cbase + n * 16 + lr;
#pragma unroll
                for (int q = 0; q < 4; ++q)
                    ACC2[(size_t)(row0 + m * 16 + rq + q) * 64 + col] = acc[m][n][q] + bias[n];
            }
    }
}

// ---------------------------------------------------------------------------
// agg2: H2b[i] = relu( ACC2[i] + sum val_j * Y2pb[col_j] )   (bf16 out)
// ---------------------------------------------------------------------------
__global__ __launch_bounds__(256) void k_agg2(
    const int* __restrict__ rowptr, const int2* __restrict__ ecv,
    const u16* __restrict__ Y2pb, const float* __restrict__ ACC2,
    u16* __restrict__ H2b)
{
    const unsigned tid = blockIdx.x * 256u + threadIdx.x;
    const unsigned lane = tid & 63u;
    const unsigned i = (tid >> 6) * 2 + (lane >> 5);
    if (i >= N_NODES) return;
    const unsigned hl = lane & 31u;

    const int e0 = (i == 0) ? 0 : rowptr[i - 1];
    const int e1 = rowptr[i];

    const u32* __restrict__ Yv = reinterpret_cast<const u32*>(Y2pb);

    float ax0 = 0.f, ay0 = 0.f, ax1 = 0.f, ay1 = 0.f;
    float ax2 = 0.f, ay2 = 0.f, ax3 = 0.f, ay3 = 0.f;
    int j = e0;
    for (; j + 3 < e1; j += 4) {
        const int2 p0 = ecv[j], p1 = ecv[j + 1], p2 = ecv[j + 2], p3 = ecv[j + 3];
        const u32 w0 = Yv[p0.x * 32 + hl];
        const u32 w1 = Yv[p1.x * 32 + hl];
        const u32 w2 = Yv[p2.x * 32 + hl];
        const u32 w3 = Yv[p3.x * 32 + hl];
        const float v0 = __int_as_float(p0.y), v1 = __int_as_float(p1.y);
        const float v2 = __int_as_float(p2.y), v3 = __int_as_float(p3.y);
        ax0 = fmaf(v0, b2f((u16)(w0 & 0xffffu)), ax0); ay0 = fmaf(v0, b2f((u16)(w0 >> 16)), ay0);
        ax1 = fmaf(v1, b2f((u16)(w1 & 0xffffu)), ax1); ay1 = fmaf(v1, b2f((u16)(w1 >> 16)), ay1);
        ax2 = fmaf(v2, b2f((u16)(w2 & 0xffffu)), ax2); ay2 = fmaf(v2, b2f((u16)(w2 >> 16)), ay2);
        ax3 = fmaf(v3, b2f((u16)(w3 & 0xffffu)), ax3); ay3 = fmaf(v3, b2f((u16)(w3 >> 16)), ay3);
    }
    for (; j < e1; ++j) {
        const int2 p = ecv[j];
        const u32 w = Yv[p.x * 32 + hl];
        const float v = __int_as_float(p.y);
        ax0 = fmaf(v, b2f((u16)(w & 0xffffu)), ax0);
        ay0 = fmaf(v, b2f((u16)(w >> 16)), ay0);
    }
    const float ax = (ax0 + ax1) + (ax2 + ax3);
    const float ay = (ay0 + ay1) + (ay2 + ay3);

    const float2 s = reinterpret_cast<const float2*>(ACC2)[i * 32 + hl];
    const float h0 = fmaxf(s.x + ax, 0.f);
    const float h1 = fmaxf(s.y + ay, 0.f);
    reinterpret_cast<u32*>(H2b)[i * 32 + hl] = (u32)f2b(h0) | ((u32)f2b(h1) << 16);
}

// ---------------------------------------------------------------------------
// edgedot: out[e] = sigmoid( dot(H2[row], H2[col]) )
// one THREAD per edge: 8x uint4 dual loads, 64-FMA register dot, no shuffles.
// ---------------------------------------------------------------------------
__global__ __launch_bounds__(256) void k_edgedot(
    const int* __restrict__ er, const int* __restrict__ ec,
    const u16* __restrict__ H2b, float* __restrict__ out)
{
    const int e = blockIdx.x * 256 + threadIdx.x;
    if (e >= N_EDGES) return;

    const int r = er[e];
    const int c = ec[e];

    const uint4* __restrict__ A = reinterpret_cast<const uint4*>(H2b + (size_t)r * 64);
    const uint4* __restrict__ B = reinterpret_cast<const uint4*>(H2b + (size_t)c * 64);

    float s0 = 0.f, s1 = 0.f, s2 = 0.f, s3 = 0.f;
#pragma unroll
    for (int k = 0; k < 8; ++k) {
        const uint4 a = A[k];
        const uint4 b = B[k];
        s0 = fmaf(b2f((u16)(a.x & 0xffffu)), b2f((u16)(b.x & 0xffffu)), s0);
        s1 = fmaf(b2f((u16)(a.x >> 16)),     b2f((u16)(b.x >> 16)),     s1);
        s2 = fmaf(b2f((u16)(a.y & 0xffffu)), b2f((u16)(b.y & 0xffffu)), s2);
        s3 = fmaf(b2f((u16)(a.y >> 16)),     b2f((u16)(b.y >> 16)),     s3);
        s0 = fmaf(b2f((u16)(a.z & 0xffffu)), b2f((u16)(b.z & 0xffffu)), s0);
        s1 = fmaf(b2f((u16)(a.z >> 16)),     b2f((u16)(b.z >> 16)),     s1);
        s2 = fmaf(b2f((u16)(a.w & 0xffffu)), b2f((u16)(b.w & 0xffffu)), s2);
        s3 = fmaf(b2f((u16)(a.w >> 16)),     b2f((u16)(b.w >> 16)),     s3);
    }
    const float p = (s0 + s1) + (s2 + s3);
    out[e] = 1.f / (1.f + expf(-p));
}

// ---------------------------------------------------------------------------
extern "C" void kernel_launch(void* const* d_in, const int* in_sizes, int n_in,
                              void* d_out, int out_size, void* d_ws, size_t ws_size,
                              hipStream_t stream)
{
    const float* X   = (const float*)d_in[0];
    const int*   er  = (const int*)d_in[1];
    const int*   ec  = (const int*)d_in[2];
    const float* ev  = (const float*)d_in[3];
    const float* Wp1 = (const float*)d_in[4];
    const float* bp1 = (const float*)d_in[5];
    const float* Ws1 = (const float*)d_in[6];
    const float* bs1 = (const float*)d_in[7];
    const float* Wp2 = (const float*)d_in[8];
    const float* bp2 = (const float*)d_in[9];
    const float* Ws2 = (const float*)d_in[10];
    const float* bs2 = (const float*)d_in[11];
    float* out = (float*)d_out;

    // workspace layout (float units from base):
    //   phase 1: ACC1 f32 [0, 6.4M) | Y1pb bf16 [6.4M, 9.6M) | H1b bf16 [9.6M, 12.8M)
    //   phase 2 (reuses [0,6.4M)): Y2pb bf16 [0,1.6M) | ACC2 f32 [1.6M,4.8M) | H2b bf16 [4.8M,6.4M)
    //   CSR at [12.8M,...): rp_base[50008] | bsum[64] | ecv int2[800k] | WT bufs (96KB)
    //   cnt[50000] aliases ecv's head (dead before reorder writes ecv).
    float* ws    = (float*)d_ws;
    float* ACC1  = ws;
    u16*   Y1pb  = (u16*)(ws + (size_t)N_NODES * 128);
    u16*   H1b   = (u16*)(ws + (size_t)N_NODES * 128 + (size_t)N_NODES * 64);
    u16*   Y2pb  = (u16*)ws;
    float* ACC2  = ws + (size_t)N_NODES * 32;
    u16*   H2b   = (u16*)(ws + (size_t)N_NODES * 32 + (size_t)N_NODES * 64);

    int*  rp_base = (int*)(ws + (size_t)N_NODES * 256);
    int*  rowptr  = rp_base + 3;        // rowptr+1 is 16B-aligned
    int*  bsum    = rp_base + 50008;    // 16B-aligned
    int2* ecv     = (int2*)(bsum + 64); // 16B-aligned
    int*  cnt     = (int*)ecv;          // alias (dead before reorder)
    u16*  WT1p    = (u16*)(ecv + N_EDGES);  // 16B-aligned
    u16*  WT1s    = WT1p + 128 * 128;
    u16*  WT2p    = WT1s + 128 * 128;
    u16*  WT2s    = WT2p + 64 * 128;

    const dim3 blk(256);
    const int node_waves  = (N_NODES * 64 + 255) / 256;        // 12500
    const int node2_waves = ((N_NODES / 2) * 64 + 255) / 256;  // 6250
    const int edge_thr    = (N_EDGES + 255) / 256;             // 3125
    const int node_thr    = (N_NODES + 255) / 256;             // 196
    const int scan_blocks = 49;
    const int gemm_blocks = N_NODES / 80;                      // 625 exact

    // weight prep + CSR build
    k_prepw  <<<384, 128, 0, stream>>>(Wp1, Ws1, Wp2, Ws2, WT1p, WT1s, WT2p, WT2s);
    k_zero   <<<node_thr,    blk, 0, stream>>>(cnt);
    k_hist   <<<edge_thr,    blk, 0, stream>>>(er, cnt);
    k_scan1  <<<scan_blocks, blk, 0, stream>>>(cnt, rowptr, bsum);
    k_scan3  <<<scan_blocks, blk, 0, stream>>>(rowptr, bsum);
    k_reorder<<<edge_thr,    blk, 0, stream>>>(er, ec, ev, rowptr, ecv);

    // layer 1
    k_gemm1<<<gemm_blocks, blk, 0, stream>>>(X, WT1p, WT1s, bp1, bs1, Y1pb, ACC1);
    k_agg1 <<<node_waves,  blk, 0, stream>>>(rowptr, ecv, Y1pb, ACC1, H1b);

    // layer 2
    k_gemm2<<<gemm_blocks, blk, 0, stream>>>(H1b, WT2p, WT2s, bp2, bs2, Y2pb, ACC2);
    k_agg2 <<<node2_waves, blk, 0, stream>>>(rowptr, ecv, Y2pb, ACC2, H2b);

    // edge scores
    k_edgedot<<<edge_thr, blk, 0, stream>>>(er, ec, H2b, out);
}

// Round 7
// 219.294 us; speedup vs baseline: 4.8214x; 1.0185x over previous
//
#include <hip/hip_runtime.h>
#include <hip/hip_bf16.h>
#include <math.h>

#define N_NODES 50000
#define N_EDGES 800000

typedef unsigned short u16;
typedef unsigned int   u32;
typedef short short8 __attribute__((ext_vector_type(8)));
typedef float f32x4  __attribute__((ext_vector_type(4)));

static __device__ __forceinline__ float b2f(u16 u) {
    union { u32 i; float f; } x; x.i = ((u32)u) << 16; return x.f;
}
static __device__ __forceinline__ u16 f2b(float f) {
    union { float f; u32 i; } x; x.f = f;
    u32 r = x.i + 0x7fffu + ((x.i >> 16) & 1u);   // round-to-nearest-even
    return (u16)(r >> 16);
}

// ---------------------------------------------------------------------------
// CSR build: memset(cnt) -> histpack -> scan1 (49 blk) -> scan3 -> reorder
// Payload packed to 4B: low16 = col (N_NODES<65536), high16 = bf16(val).
// ---------------------------------------------------------------------------
__global__ __launch_bounds__(256) void k_histpack(
    const int* __restrict__ er, const int* __restrict__ ec,
    const float* __restrict__ ev,
    int* __restrict__ cnt, u32* __restrict__ pkcv)
{
    const int e = blockIdx.x * 256 + threadIdx.x;
    if (e >= N_EDGES) return;
    atomicAdd(&cnt[er[e]], 1);
    pkcv[e] = (u32)ec[e] | ((u32)f2b(ev[e]) << 16);
}

__global__ __launch_bounds__(256) void k_scan1(
    const int* __restrict__ cnt, int* __restrict__ rowptr, int* __restrict__ bsum)
{
    __shared__ int wsum[4];
    const int t = threadIdx.x;
    const int g4 = blockIdx.x * 256 + t;
    int4 v = make_int4(0, 0, 0, 0);
    if (g4 < 12500) v = reinterpret_cast<const int4*>(cnt)[g4];
    const int s0 = v.x, s1 = s0 + v.y, s2 = s1 + v.z, s3 = s2 + v.w;

    const int lane = t & 63, wv = t >> 6;
    int incl = s3;
#pragma unroll
    for (int off = 1; off < 64; off <<= 1) {
        int u = __shfl_up(incl, off, 64);
        if (lane >= off) incl += u;
    }
    if (lane == 63) wsum[wv] = incl;
    __syncthreads();
    int woff = 0;
    if (wv > 0) woff += wsum[0];
    if (wv > 1) woff += wsum[1];
    if (wv > 2) woff += wsum[2];
    const int excl = woff + incl - s3;

    if (g4 < 12500) {
        int4 o;
        o.x = excl + s0; o.y = excl + s1; o.z = excl + s2; o.w = excl + s3;
        reinterpret_cast<int4*>(rowptr + 1)[g4] = o;
    }
    if (t == 255) bsum[blockIdx.x] = woff + incl;
}

__global__ __launch_bounds__(256) void k_scan3(
    int* __restrict__ rowptr, const int* __restrict__ bsum)
{
    __shared__ int s_add;
    const int b = blockIdx.x;
    const int t = threadIdx.x;
    if (t < 64) {
        int v = (t < b) ? bsum[t] : 0;
#pragma unroll
        for (int off = 32; off; off >>= 1) v += __shfl_xor(v, off, 64);
        if (t == 0) s_add = v;
    }
    __syncthreads();
    if (b == 0) {
        if (t == 0) rowptr[0] = 0;
        return;
    }
    const int add = s_add;
    const int g4 = b * 256 + t;
    if (g4 < 12500) {
        int4* o4 = reinterpret_cast<int4*>(rowptr + 1);
        int4 v = o4[g4];
        v.x += add; v.y += add; v.z += add; v.w += add;
        o4[g4] = v;
    }
}

__global__ __launch_bounds__(256) void k_reorder(
    const int* __restrict__ er, const u32* __restrict__ pkcv,
    int* __restrict__ rowptr, u32* __restrict__ ecv32)
{
    const int e = blockIdx.x * 256 + threadIdx.x;
    if (e >= N_EDGES) return;
    const int r = er[e];
    const u32 pk = pkcv[e];
    const int slot = atomicAdd(&rowptr[r], 1);
    ecv32[slot] = pk;
}

// ---------------------------------------------------------------------------
// prepw: WT[n][k] = bf16(W[k][n]) for all 4 weight matrices.
// ---------------------------------------------------------------------------
__global__ __launch_bounds__(128) void k_prepw(
    const float* __restrict__ Wp1, const float* __restrict__ Ws1,
    const float* __restrict__ Wp2, const float* __restrict__ Ws2,
    u16* __restrict__ WT1p, u16* __restrict__ WT1s,
    u16* __restrict__ WT2p, u16* __restrict__ WT2s)
{
    const int b = blockIdx.x, k = threadIdx.x;
    const float* src; u16* dst; int N, n;
    if (b < 128)      { src = Wp1; N = 128; n = b;       dst = WT1p + n * 128; }
    else if (b < 256) { src = Ws1; N = 128; n = b - 128; dst = WT1s + n * 128; }
    else if (b < 320) { src = Wp2; N = 64;  n = b - 256; dst = WT2p + n * 128; }
    else              { src = Ws2; N = 64;  n = b - 320; dst = WT2s + n * 128; }
    dst[k] = f2b(src[k * N + n]);
}

// ---------------------------------------------------------------------------
// GEMM1 (MFMA): Y1pb (bf16) = X @ Wp1 ; ACC1 (f32) = X @ Ws1 + (bs1+bp1)
// ---------------------------------------------------------------------------
__global__ __launch_bounds__(256) void k_gemm1(
    const float* __restrict__ X,
    const u16* __restrict__ WT1p, const u16* __restrict__ WT1s,
    const float* __restrict__ bp, const float* __restrict__ bs,
    u16* __restrict__ Y1pb, float* __restrict__ ACC1)
{
    __shared__ u16 Xs[80 * 128];
    const int t = threadIdx.x;

    const float4* Xv = reinterpret_cast<const float4*>(X) + (size_t)blockIdx.x * 2560;
#pragma unroll
    for (int i = 0; i < 10; ++i) {
        const int f4 = t + 256 * i;
        const float4 v = Xv[f4];
        const int row = f4 >> 5, col4 = f4 & 31;
        const u32 lo = (u32)f2b(v.x) | ((u32)f2b(v.y) << 16);
        const u32 hi = (u32)f2b(v.z) | ((u32)f2b(v.w) << 16);
        const int e = row * 128 + ((col4 * 4) ^ ((row & 7) << 3));
        *reinterpret_cast<uint2*>(&Xs[e]) = make_uint2(lo, hi);
    }
    __syncthreads();

    const int lane = t & 63;
    const int w = t >> 6;
    const int mat = w >> 1;
    const int cbase = (w & 1) * 64;
    const u16* __restrict__ WT = mat ? WT1s : WT1p;
    const int lr = lane & 15;
    const int lk = (lane >> 4) * 8;

    f32x4 acc[5][4];
#pragma unroll
    for (int m = 0; m < 5; ++m)
#pragma unroll
        for (int n = 0; n < 4; ++n) acc[m][n] = (f32x4){0.f, 0.f, 0.f, 0.f};

#pragma unroll
    for (int kk = 0; kk < 4; ++kk) {
        short8 b[4];
#pragma unroll
        for (int n = 0; n < 4; ++n) {
            const int col = cbase + n * 16 + lr;
            b[n] = *reinterpret_cast<const short8*>(WT + col * 128 + kk * 32 + lk);
        }
#pragma unroll
        for (int m = 0; m < 5; ++m) {
            const int row = m * 16 + lr;
            const int e = row * 128 + ((kk * 32 + lk) ^ ((row & 7) << 3));
            const short8 a = *reinterpret_cast<const short8*>(&Xs[e]);
#pragma unroll
            for (int n = 0; n < 4; ++n)
                acc[m][n] = __builtin_amdgcn_mfma_f32_16x16x32_bf16(a, b[n], acc[m][n], 0, 0, 0);
        }
    }

    const int row0 = blockIdx.x * 80;
    const int rq = (lane >> 4) * 4;
    if (mat == 0) {
#pragma unroll
        for (int m = 0; m < 5; ++m)
#pragma unroll
            for (int n = 0; n < 4; ++n) {
                const int col = cbase + n * 16 + lr;
#pragma unroll
                for (int q = 0; q < 4; ++q)
                    Y1pb[(size_t)(row0 + m * 16 + rq + q) * 128 + col] = f2b(acc[m][n][q]);
            }
    } else {
        float bias[4];
#pragma unroll
        for (int n = 0; n < 4; ++n) {
            const int col = cbase + n * 16 + lr;
            bias[n] = bs[col] + bp[col];
        }
#pragma unroll
        for (int m = 0; m < 5; ++m)
#pragma unroll
            for (int n = 0; n < 4; ++n) {
                const int col = cbase + n * 16 + lr;
#pragma unroll
                for (int q = 0; q < 4; ++q)
                    ACC1[(size_t)(row0 + m * 16 + rq + q) * 128 + col] = acc[m][n][q] + bias[n];
            }
    }
}

// ---------------------------------------------------------------------------
// agg1: H1b[i] = relu( ACC1[i] + sum val_j * Y1pb[col_j] )    (bf16 out)
// packed edge: col = pk & 0xFFFF, val = bf16(pk >> 16)
// ---------------------------------------------------------------------------
__global__ __launch_bounds__(256) void k_agg1(
    const int* __restrict__ rowptr, const u32* __restrict__ ecv32,
    const u16* __restrict__ Y1pb, const float* __restrict__ ACC1,
    u16* __restrict__ H1b)
{
    const unsigned tid = blockIdx.x * 256u + threadIdx.x;
    const unsigned i = tid >> 6;
    if (i >= N_NODES) return;
    const unsigned lane = tid & 63u;

    const int e0 = (i == 0) ? 0 : rowptr[i - 1];
    const int e1 = rowptr[i];

    const u32* __restrict__ Yv = reinterpret_cast<const u32*>(Y1pb);

    float ax0 = 0.f, ay0 = 0.f, ax1 = 0.f, ay1 = 0.f;
    float ax2 = 0.f, ay2 = 0.f, ax3 = 0.f, ay3 = 0.f;
    int j = e0;
    for (; j + 3 < e1; j += 4) {
        const u32 p0 = ecv32[j], p1 = ecv32[j + 1], p2 = ecv32[j + 2], p3 = ecv32[j + 3];
        const u32 w0 = Yv[(p0 & 0xffffu) * 64 + lane];
        const u32 w1 = Yv[(p1 & 0xffffu) * 64 + lane];
        const u32 w2 = Yv[(p2 & 0xffffu) * 64 + lane];
        const u32 w3 = Yv[(p3 & 0xffffu) * 64 + lane];
        const float v0 = b2f((u16)(p0 >> 16)), v1 = b2f((u16)(p1 >> 16));
        const float v2 = b2f((u16)(p2 >> 16)), v3 = b2f((u16)(p3 >> 16));
        ax0 = fmaf(v0, b2f((u16)(w0 & 0xffffu)), ax0); ay0 = fmaf(v0, b2f((u16)(w0 >> 16)), ay0);
        ax1 = fmaf(v1, b2f((u16)(w1 & 0xffffu)), ax1); ay1 = fmaf(v1, b2f((u16)(w1 >> 16)), ay1);
        ax2 = fmaf(v2, b2f((u16)(w2 & 0xffffu)), ax2); ay2 = fmaf(v2, b2f((u16)(w2 >> 16)), ay2);
        ax3 = fmaf(v3, b2f((u16)(w3 & 0xffffu)), ax3); ay3 = fmaf(v3, b2f((u16)(w3 >> 16)), ay3);
    }
    for (; j < e1; ++j) {
        const u32 p = ecv32[j];
        const u32 w = Yv[(p & 0xffffu) * 64 + lane];
        const float v = b2f((u16)(p >> 16));
        ax0 = fmaf(v, b2f((u16)(w & 0xffffu)), ax0);
        ay0 = fmaf(v, b2f((u16)(w >> 16)), ay0);
    }
    const float ax = (ax0 + ax1) + (ax2 + ax3);
    const float ay = (ay0 + ay1) + (ay2 + ay3);

    const float2 s = reinterpret_cast<const float2*>(ACC1)[i * 64 + lane];
    const float h0 = fmaxf(s.x + ax, 0.f);
    const float h1 = fmaxf(s.y + ay, 0.f);
    reinterpret_cast<u32*>(H1b)[i * 64 + lane] = (u32)f2b(h0) | ((u32)f2b(h1) << 16);
}

// ---------------------------------------------------------------------------
// GEMM2 (MFMA): Y2pb (bf16) = H1 @ Wp2 ; ACC2 (f32) = H1 @ Ws2 + (bs2+bp2)
// ---------------------------------------------------------------------------
__global__ __launch_bounds__(256) void k_gemm2(
    const u16* __restrict__ H1b,
    const u16* __restrict__ WT2p, const u16* __restrict__ WT2s,
    const float* __restrict__ bp, const float* __restrict__ bs,
    u16* __restrict__ Y2pb, float* __restrict__ ACC2)
{
    __shared__ u16 Hs[80 * 128];
    const int t = threadIdx.x;

    const uint4* Hv = reinterpret_cast<const uint4*>(H1b) + (size_t)blockIdx.x * 1280;
#pragma unroll
    for (int i = 0; i < 5; ++i) {
        const int ch = t + 256 * i;
        const uint4 v = Hv[ch];
        const int row = ch >> 4, c16 = ch & 15;
        const int e = row * 128 + ((c16 * 8) ^ ((row & 7) << 3));
        *reinterpret_cast<uint4*>(&Hs[e]) = v;
    }
    __syncthreads();

    const int lane = t & 63;
    const int w = t >> 6;
    const int mat = w >> 1;
    const int cbase = (w & 1) * 32;
    const u16* __restrict__ WT = mat ? WT2s : WT2p;
    const int lr = lane & 15;
    const int lk = (lane >> 4) * 8;

    f32x4 acc[5][2];
#pragma unroll
    for (int m = 0; m < 5; ++m)
#pragma unroll
        for (int n = 0; n < 2; ++n) acc[m][n] = (f32x4){0.f, 0.f, 0.f, 0.f};

#pragma unroll
    for (int kk = 0; kk < 4; ++kk) {
        short8 b[2];
#pragma unroll
        for (int n = 0; n < 2; ++n) {
            const int col = cbase + n * 16 + lr;
            b[n] = *reinterpret_cast<const short8*>(WT + col * 128 + kk * 32 + lk);
        }
#pragma unroll
        for (int m = 0; m < 5; ++m) {
            const int row = m * 16 + lr;
            const int e = row * 128 + ((kk * 32 + lk) ^ ((row & 7) << 3));
            const short8 a = *reinterpret_cast<const short8*>(&Hs[e]);
#pragma unroll
            for (int n = 0; n < 2; ++n)
                acc[m][n] = __builtin_amdgcn_mfma_f32_16x16x32_bf16(a, b[n], acc[m][n], 0, 0, 0);
        }
    }

    const int row0 = blockIdx.x * 80;
    const int rq = (lane >> 4) * 4;
    if (mat == 0) {
#pragma unroll
        for (int m = 0; m < 5; ++m)
#pragma unroll
            for (int n = 0; n < 2; ++n) {
                const int col = cbase + n * 16 + lr;
#pragma unroll
                for (int q = 0; q < 4; ++q)
                    Y2pb[(size_t)(row0 + m * 16 + rq + q) * 64 + col] = f2b(acc[m][n][q]);
            }
    } else {
        float bias[2];
#pragma unroll
        for (int n = 0; n < 2; ++n) {
            const int col = cbase + n * 16 + lr;
            bias[n] = bs[col] + bp[col];
        }
#pragma unroll
        for (int m = 0; m < 5; ++m)
#pragma unroll
            for (int n = 0; n < 2; ++n) {
                const int col = cbase + n * 16 + lr;
#pragma unroll
                for (int q = 0; q < 4; ++q)
                    ACC2[(size_t)(row0 + m * 16 + rq + q) * 64 + col] = acc[m][n][q] + bias[n];
            }
    }
}

// ---------------------------------------------------------------------------
// agg2: H2b[i] = relu( ACC2[i] + sum val_j * Y2pb[col_j] )   (bf16 out)
// ---------------------------------------------------------------------------
__global__ __launch_bounds__(256) void k_agg2(
    const int* __restrict__ rowptr, const u32* __restrict__ ecv32,
    const u16* __restrict__ Y2pb, const float* __restrict__ ACC2,
    u16* __restrict__ H2b)
{
    const unsigned tid = blockIdx.x * 256u + threadIdx.x;
    const unsigned lane = tid & 63u;
    const unsigned i = (tid >> 6) * 2 + (lane >> 5);
    if (i >= N_NODES) return;
    const unsigned hl = lane & 31u;

    const int e0 = (i == 0) ? 0 : rowptr[i - 1];
    const int e1 = rowptr[i];

    const u32* __restrict__ Yv = reinterpret_cast<const u32*>(Y2pb);

    float ax0 = 0.f, ay0 = 0.f, ax1 = 0.f, ay1 = 0.f;
    float ax2 = 0.f, ay2 = 0.f, ax3 = 0.f, ay3 = 0.f;
    int j = e0;
    for (; j + 3 < e1; j += 4) {
        const u32 p0 = ecv32[j], p1 = ecv32[j + 1], p2 = ecv32[j + 2], p3 = ecv32[j + 3];
        const u32 w0 = Yv[(p0 & 0xffffu) * 32 + hl];
        const u32 w1 = Yv[(p1 & 0xffffu) * 32 + hl];
        const u32 w2 = Yv[(p2 & 0xffffu) * 32 + hl];
        const u32 w3 = Yv[(p3 & 0xffffu) * 32 + hl];
        const float v0 = b2f((u16)(p0 >> 16)), v1 = b2f((u16)(p1 >> 16));
        const float v2 = b2f((u16)(p2 >> 16)), v3 = b2f((u16)(p3 >> 16));
        ax0 = fmaf(v0, b2f((u16)(w0 & 0xffffu)), ax0); ay0 = fmaf(v0, b2f((u16)(w0 >> 16)), ay0);
        ax1 = fmaf(v1, b2f((u16)(w1 & 0xffffu)), ax1); ay1 = fmaf(v1, b2f((u16)(w1 >> 16)), ay1);
        ax2 = fmaf(v2, b2f((u16)(w2 & 0xffffu)), ax2); ay2 = fmaf(v2, b2f((u16)(w2 >> 16)), ay2);
        ax3 = fmaf(v3, b2f((u16)(w3 & 0xffffu)), ax3); ay3 = fmaf(v3, b2f((u16)(w3 >> 16)), ay3);
    }
    for (; j < e1; ++j) {
        const u32 p = ecv32[j];
        const u32 w = Yv[(p & 0xffffu) * 32 + hl];
        const float v = b2f((u16)(p >> 16));
        ax0 = fmaf(v, b2f((u16)(w & 0xffffu)), ax0);
        ay0 = fmaf(v, b2f((u16)(w >> 16)), ay0);
    }
    const float ax = (ax0 + ax1) + (ax2 + ax3);
    const float ay = (ay0 + ay1) + (ay2 + ay3);

    const float2 s = reinterpret_cast<const float2*>(ACC2)[i * 32 + hl];
    const float h0 = fmaxf(s.x + ax, 0.f);
    const float h1 = fmaxf(s.y + ay, 0.f);
    reinterpret_cast<u32*>(H2b)[i * 32 + hl] = (u32)f2b(h0) | ((u32)f2b(h1) << 16);
}

// ---------------------------------------------------------------------------
// edgedot: out[e] = sigmoid( dot(H2[row], H2[col]) )
// one THREAD per edge: 8x uint4 dual loads, 64-FMA register dot, no shuffles.
// ---------------------------------------------------------------------------
__global__ __launch_bounds__(256) void k_edgedot(
    const int* __restrict__ er, const int* __restrict__ ec,
    const u16* __restrict__ H2b, float* __restrict__ out)
{
    const int e = blockIdx.x * 256 + threadIdx.x;
    if (e >= N_EDGES) return;

    const int r = er[e];
    const int c = ec[e];

    const uint4* __restrict__ A = reinterpret_cast<const uint4*>(H2b + (size_t)r * 64);
    const uint4* __restrict__ B = reinterpret_cast<const uint4*>(H2b + (size_t)c * 64);

    float s0 = 0.f, s1 = 0.f, s2 = 0.f, s3 = 0.f;
#pragma unroll
    for (int k = 0; k < 8; ++k) {
        const uint4 a = A[k];
        const uint4 b = B[k];
        s0 = fmaf(b2f((u16)(a.x & 0xffffu)), b2f((u16)(b.x & 0xffffu)), s0);
        s1 = fmaf(b2f((u16)(a.x >> 16)),     b2f((u16)(b.x >> 16)),     s1);
        s2 = fmaf(b2f((u16)(a.y & 0xffffu)), b2f((u16)(b.y & 0xffffu)), s2);
        s3 = fmaf(b2f((u16)(a.y >> 16)),     b2f((u16)(b.y >> 16)),     s3);
        s0 = fmaf(b2f((u16)(a.z & 0xffffu)), b2f((u16)(b.z & 0xffffu)), s0);
        s1 = fmaf(b2f((u16)(a.z >> 16)),     b2f((u16)(b.z >> 16)),     s1);
        s2 = fmaf(b2f((u16)(a.w & 0xffffu)), b2f((u16)(b.w & 0xffffu)), s2);
        s3 = fmaf(b2f((u16)(a.w >> 16)),     b2f((u16)(b.w >> 16)),     s3);
    }
    const float p = (s0 + s1) + (s2 + s3);
    out[e] = 1.f / (1.f + expf(-p));
}

// ---------------------------------------------------------------------------
extern "C" void kernel_launch(void* const* d_in, const int* in_sizes, int n_in,
                              void* d_out, int out_size, void* d_ws, size_t ws_size,
                              hipStream_t stream)
{
    const float* X   = (const float*)d_in[0];
    const int*   er  = (const int*)d_in[1];
    const int*   ec  = (const int*)d_in[2];
    const float* ev  = (const float*)d_in[3];
    const float* Wp1 = (const float*)d_in[4];
    const float* bp1 = (const float*)d_in[5];
    const float* Ws1 = (const float*)d_in[6];
    const float* bs1 = (const float*)d_in[7];
    const float* Wp2 = (const float*)d_in[8];
    const float* bp2 = (const float*)d_in[9];
    const float* Ws2 = (const float*)d_in[10];
    const float* bs2 = (const float*)d_in[11];
    float* out = (float*)d_out;

    // workspace layout (float units from base):
    //   phase 1: ACC1 f32 [0, 6.4M) | Y1pb bf16 [6.4M, 9.6M) | H1b bf16 [9.6M, 12.8M)
    //   phase 2 (reuses [0,6.4M)): Y2pb bf16 [0,1.6M) | ACC2 f32 [1.6M,4.8M) | H2b bf16 [4.8M,6.4M)
    //   CSR at [12.8M,...): rp_base[50008] | bsum[64] | ecv32 u32[800k] | pkcv u32[800k] | WT bufs
    //   cnt[50000] aliases ecv32's head (dead before reorder writes ecv32).
    float* ws    = (float*)d_ws;
    float* ACC1  = ws;
    u16*   Y1pb  = (u16*)(ws + (size_t)N_NODES * 128);
    u16*   H1b   = (u16*)(ws + (size_t)N_NODES * 128 + (size_t)N_NODES * 64);
    u16*   Y2pb  = (u16*)ws;
    float* ACC2  = ws + (size_t)N_NODES * 32;
    u16*   H2b   = (u16*)(ws + (size_t)N_NODES * 32 + (size_t)N_NODES * 64);

    int*  rp_base = (int*)(ws + (size_t)N_NODES * 256);
    int*  rowptr  = rp_base + 3;          // rowptr+1 is 16B-aligned
    int*  bsum    = rp_base + 50008;      // 16B-aligned
    u32*  ecv32   = (u32*)(bsum + 64);    // 16B-aligned
    int*  cnt     = (int*)ecv32;          // alias (dead before reorder)
    u32*  pkcv    = ecv32 + N_EDGES;
    u16*  WT1p    = (u16*)(pkcv + N_EDGES);
    u16*  WT1s    = WT1p + 128 * 128;
    u16*  WT2p    = WT1s + 128 * 128;
    u16*  WT2s    = WT2p + 64 * 128;

    const dim3 blk(256);
    const int node_waves  = (N_NODES * 64 + 255) / 256;        // 12500
    const int node2_waves = ((N_NODES / 2) * 64 + 255) / 256;  // 6250
    const int edge_thr    = (N_EDGES + 255) / 256;             // 3125
    const int scan_blocks = 49;
    const int gemm_blocks = N_NODES / 80;                      // 625 exact

    // weight prep + CSR build
    k_prepw   <<<384, 128, 0, stream>>>(Wp1, Ws1, Wp2, Ws2, WT1p, WT1s, WT2p, WT2s);
    hipMemsetAsync(cnt, 0, (size_t)N_NODES * sizeof(int), stream);
    k_histpack<<<edge_thr,    blk, 0, stream>>>(er, ec, ev, cnt, pkcv);
    k_scan1   <<<scan_blocks, blk, 0, stream>>>(cnt, rowptr, bsum);
    k_scan3   <<<scan_blocks, blk, 0, stream>>>(rowptr, bsum);
    k_reorder <<<edge_thr,    blk, 0, stream>>>(er, pkcv, rowptr, ecv32);

    // layer 1
    k_gemm1<<<gemm_blocks, blk, 0, stream>>>(X, WT1p, WT1s, bp1, bs1, Y1pb, ACC1);
    k_agg1 <<<node_waves,  blk, 0, stream>>>(rowptr, ecv32, Y1pb, ACC1, H1b);

    // layer 2
    k_gemm2<<<gemm_blocks, blk, 0, stream>>>(H1b, WT2p, WT2s, bp2, bs2, Y2pb, ACC2);
    k_agg2 <<<node2_waves, blk, 0, stream>>>(rowptr, ecv32, Y2pb, ACC2, H2b);

    // edge scores
    k_edgedot<<<edge_thr, blk, 0, stream>>>(er, ec, H2b, out);
}

// Round 8
// 199.607 us; speedup vs baseline: 5.2970x; 1.0986x over previous
//
#include <hip/hip_runtime.h>
#include <hip/hip_bf16.h>
#include <math.h>

#define N_NODES 50000
#define N_EDGES 800000
#define NBUCKET 196              // ceil(50000/256)
#define PART_E  4096             // edges per part1 block

typedef unsigned short u16;
typedef unsigned int   u32;
typedef short short8 __attribute__((ext_vector_type(8)));
typedef float f32x4  __attribute__((ext_vector_type(4)));

static __device__ __forceinline__ float b2f(u16 u) {
    union { u32 i; float f; } x; x.i = ((u32)u) << 16; return x.f;
}
static __device__ __forceinline__ u16 f2b(float f) {
    union { float f; u32 i; } x; x.f = f;
    u32 r = x.i + 0x7fffu + ((x.i >> 16) & 1u);   // round-to-nearest-even
    return (u16)(r >> 16);
}

// ---------------------------------------------------------------------------
// CSR build: memset(cnt) -> histpack -> scan1 -> scan3 -> initcur -> part1 -> sort2
// Payload packed to 4B: low16 = col (N_NODES<65536), high16 = bf16(val).
// rowptr is NOT mutated: start(i) = rowptr[i], end(i) = rowptr[i+1].
// ---------------------------------------------------------------------------
__global__ __launch_bounds__(256) void k_histpack(
    const int* __restrict__ er, const int* __restrict__ ec,
    const float* __restrict__ ev,
    int* __restrict__ cnt, u32* __restrict__ pkcv)
{
    const int e = blockIdx.x * 256 + threadIdx.x;
    if (e >= N_EDGES) return;
    atomicAdd(&cnt[er[e]], 1);
    pkcv[e] = (u32)ec[e] | ((u32)f2b(ev[e]) << 16);
}

__global__ __launch_bounds__(256) void k_scan1(
    const int* __restrict__ cnt, int* __restrict__ rowptr, int* __restrict__ bsum)
{
    __shared__ int wsum[4];
    const int t = threadIdx.x;
    const int g4 = blockIdx.x * 256 + t;
    int4 v = make_int4(0, 0, 0, 0);
    if (g4 < 12500) v = reinterpret_cast<const int4*>(cnt)[g4];
    const int s0 = v.x, s1 = s0 + v.y, s2 = s1 + v.z, s3 = s2 + v.w;

    const int lane = t & 63, wv = t >> 6;
    int incl = s3;
#pragma unroll
    for (int off = 1; off < 64; off <<= 1) {
        int u = __shfl_up(incl, off, 64);
        if (lane >= off) incl += u;
    }
    if (lane == 63) wsum[wv] = incl;
    __syncthreads();
    int woff = 0;
    if (wv > 0) woff += wsum[0];
    if (wv > 1) woff += wsum[1];
    if (wv > 2) woff += wsum[2];
    const int excl = woff + incl - s3;

    if (g4 < 12500) {
        int4 o;
        o.x = excl + s0; o.y = excl + s1; o.z = excl + s2; o.w = excl + s3;
        reinterpret_cast<int4*>(rowptr + 1)[g4] = o;
    }
    if (t == 255) bsum[blockIdx.x] = woff + incl;
}

__global__ __launch_bounds__(256) void k_scan3(
    int* __restrict__ rowptr, const int* __restrict__ bsum)
{
    __shared__ int s_add;
    const int b = blockIdx.x;
    const int t = threadIdx.x;
    if (t < 64) {
        int v = (t < b) ? bsum[t] : 0;
#pragma unroll
        for (int off = 32; off; off >>= 1) v += __shfl_xor(v, off, 64);
        if (t == 0) s_add = v;
    }
    __syncthreads();
    if (b == 0) {
        if (t == 0) rowptr[0] = 0;
        return;
    }
    const int add = s_add;
    const int g4 = b * 256 + t;
    if (g4 < 12500) {
        int4* o4 = reinterpret_cast<int4*>(rowptr + 1);
        int4 v = o4[g4];
        v.x += add; v.y += add; v.z += add; v.w += add;
        o4[g4] = v;
    }
}

__global__ __launch_bounds__(256) void k_initcur(
    const int* __restrict__ rowptr, int* __restrict__ cur)
{
    const int t = threadIdx.x;
    if (t < NBUCKET) cur[t] = rowptr[t * 256];
}

// pass 1: partition edges into 196 row-buckets, grouped contiguous writes.
__global__ __launch_bounds__(256) void k_part1(
    const int* __restrict__ er, const u32* __restrict__ pkcv,
    int* __restrict__ cur, uint2* __restrict__ parted)
{
    __shared__ int hist[NBUCKET], base[NBUCKET], cnt[NBUCKET];
    const int t = threadIdx.x;
    if (t < NBUCKET) hist[t] = 0;
    __syncthreads();

    const int e0 = blockIdx.x * PART_E;
    int rows[16]; u32 pks[16];
#pragma unroll
    for (int i = 0; i < 16; ++i) {
        const int e = e0 + t + 256 * i;
        if (e < N_EDGES) {
            rows[i] = er[e];
            pks[i] = pkcv[e];
            atomicAdd(&hist[rows[i] >> 8], 1);
        } else rows[i] = -1;
    }
    __syncthreads();
    if (t < NBUCKET) { base[t] = atomicAdd(&cur[t], hist[t]); cnt[t] = 0; }
    __syncthreads();

#pragma unroll
    for (int i = 0; i < 16; ++i) {
        if (rows[i] >= 0) {
            const int b = rows[i] >> 8;
            const int off = atomicAdd(&cnt[b], 1);
            parted[base[b] + off] = make_uint2(pks[i], (u32)rows[i]);
        }
    }
}

// pass 2: one block per bucket; scatter confined to the bucket's CSR window.
__global__ __launch_bounds__(256) void k_sort2(
    const int* __restrict__ rowptr, const uint2* __restrict__ parted,
    u32* __restrict__ ecv32)
{
    __shared__ int cur[256];
    const int b = blockIdx.x;
    const int t = threadIdx.x;
    const int r0 = b * 256;
    const int rt = r0 + t;
    cur[t] = rowptr[rt < N_NODES ? rt : N_NODES];
    __syncthreads();

    const int lo = rowptr[r0];
    const int r1 = r0 + 256;
    const int hi = rowptr[r1 < N_NODES ? r1 : N_NODES];

    for (int e = lo + t; e < hi; e += 256) {
        const uint2 pe = parted[e];
        const int low = (int)(pe.y & 255u);
        const int slot = atomicAdd(&cur[low], 1);
        ecv32[slot] = pe.x;
    }
}

// ---------------------------------------------------------------------------
// prepw: WT[n][k] = bf16(W[k][n]) for all 4 weight matrices.
// ---------------------------------------------------------------------------
__global__ __launch_bounds__(128) void k_prepw(
    const float* __restrict__ Wp1, const float* __restrict__ Ws1,
    const float* __restrict__ Wp2, const float* __restrict__ Ws2,
    u16* __restrict__ WT1p, u16* __restrict__ WT1s,
    u16* __restrict__ WT2p, u16* __restrict__ WT2s)
{
    const int b = blockIdx.x, k = threadIdx.x;
    const float* src; u16* dst; int N, n;
    if (b < 128)      { src = Wp1; N = 128; n = b;       dst = WT1p + n * 128; }
    else if (b < 256) { src = Ws1; N = 128; n = b - 128; dst = WT1s + n * 128; }
    else if (b < 320) { src = Wp2; N = 64;  n = b - 256; dst = WT2p + n * 128; }
    else              { src = Ws2; N = 64;  n = b - 320; dst = WT2s + n * 128; }
    dst[k] = f2b(src[k * N + n]);
}

// ---------------------------------------------------------------------------
// GEMM1 (MFMA): Y1pb (bf16) = X @ Wp1 ; ACC1 (f32) = X @ Ws1 + (bs1+bp1)
// ---------------------------------------------------------------------------
__global__ __launch_bounds__(256) void k_gemm1(
    const float* __restrict__ X,
    const u16* __restrict__ WT1p, const u16* __restrict__ WT1s,
    const float* __restrict__ bp, const float* __restrict__ bs,
    u16* __restrict__ Y1pb, float* __restrict__ ACC1)
{
    __shared__ u16 Xs[80 * 128];
    const int t = threadIdx.x;

    const float4* Xv = reinterpret_cast<const float4*>(X) + (size_t)blockIdx.x * 2560;
#pragma unroll
    for (int i = 0; i < 10; ++i) {
        const int f4 = t + 256 * i;
        const float4 v = Xv[f4];
        const int row = f4 >> 5, col4 = f4 & 31;
        const u32 lo = (u32)f2b(v.x) | ((u32)f2b(v.y) << 16);
        const u32 hi = (u32)f2b(v.z) | ((u32)f2b(v.w) << 16);
        const int e = row * 128 + ((col4 * 4) ^ ((row & 7) << 3));
        *reinterpret_cast<uint2*>(&Xs[e]) = make_uint2(lo, hi);
    }
    __syncthreads();

    const int lane = t & 63;
    const int w = t >> 6;
    const int mat = w >> 1;
    const int cbase = (w & 1) * 64;
    const u16* __restrict__ WT = mat ? WT1s : WT1p;
    const int lr = lane & 15;
    const int lk = (lane >> 4) * 8;

    f32x4 acc[5][4];
#pragma unroll
    for (int m = 0; m < 5; ++m)
#pragma unroll
        for (int n = 0; n < 4; ++n) acc[m][n] = (f32x4){0.f, 0.f, 0.f, 0.f};

#pragma unroll
    for (int kk = 0; kk < 4; ++kk) {
        short8 b[4];
#pragma unroll
        for (int n = 0; n < 4; ++n) {
            const int col = cbase + n * 16 + lr;
            b[n] = *reinterpret_cast<const short8*>(WT + col * 128 + kk * 32 + lk);
        }
#pragma unroll
        for (int m = 0; m < 5; ++m) {
            const int row = m * 16 + lr;
            const int e = row * 128 + ((kk * 32 + lk) ^ ((row & 7) << 3));
            const short8 a = *reinterpret_cast<const short8*>(&Xs[e]);
#pragma unroll
            for (int n = 0; n < 4; ++n)
                acc[m][n] = __builtin_amdgcn_mfma_f32_16x16x32_bf16(a, b[n], acc[m][n], 0, 0, 0);
        }
    }

    const int row0 = blockIdx.x * 80;
    const int rq = (lane >> 4) * 4;
    if (mat == 0) {
#pragma unroll
        for (int m = 0; m < 5; ++m)
#pragma unroll
            for (int n = 0; n < 4; ++n) {
                const int col = cbase + n * 16 + lr;
#pragma unroll
                for (int q = 0; q < 4; ++q)
                    Y1pb[(size_t)(row0 + m * 16 + rq + q) * 128 + col] = f2b(acc[m][n][q]);
            }
    } else {
        float bias[4];
#pragma unroll
        for (int n = 0; n < 4; ++n) {
            const int col = cbase + n * 16 + lr;
            bias[n] = bs[col] + bp[col];
        }
#pragma unroll
        for (int m = 0; m < 5; ++m)
#pragma unroll
            for (int n = 0; n < 4; ++n) {
                const int col = cbase + n * 16 + lr;
#pragma unroll
                for (int q = 0; q < 4; ++q)
                    ACC1[(size_t)(row0 + m * 16 + rq + q) * 128 + col] = acc[m][n][q] + bias[n];
            }
    }
}

// ---------------------------------------------------------------------------
// agg1: H1b[i] = relu( ACC1[i] + sum val_j * Y1pb[col_j] )    (bf16 out)
// ---------------------------------------------------------------------------
__global__ __launch_bounds__(256) void k_agg1(
    const int* __restrict__ rowptr, const u32* __restrict__ ecv32,
    const u16* __restrict__ Y1pb, const float* __restrict__ ACC1,
    u16* __restrict__ H1b)
{
    const unsigned tid = blockIdx.x * 256u + threadIdx.x;
    const unsigned i = tid >> 6;
    if (i >= N_NODES) return;
    const unsigned lane = tid & 63u;

    const int e0 = rowptr[i];
    const int e1 = rowptr[i + 1];

    const u32* __restrict__ Yv = reinterpret_cast<const u32*>(Y1pb);

    float ax0 = 0.f, ay0 = 0.f, ax1 = 0.f, ay1 = 0.f;
    float ax2 = 0.f, ay2 = 0.f, ax3 = 0.f, ay3 = 0.f;
    int j = e0;
    for (; j + 3 < e1; j += 4) {
        const u32 p0 = ecv32[j], p1 = ecv32[j + 1], p2 = ecv32[j + 2], p3 = ecv32[j + 3];
        const u32 w0 = Yv[(p0 & 0xffffu) * 64 + lane];
        const u32 w1 = Yv[(p1 & 0xffffu) * 64 + lane];
        const u32 w2 = Yv[(p2 & 0xffffu) * 64 + lane];
        const u32 w3 = Yv[(p3 & 0xffffu) * 64 + lane];
        const float v0 = b2f((u16)(p0 >> 16)), v1 = b2f((u16)(p1 >> 16));
        const float v2 = b2f((u16)(p2 >> 16)), v3 = b2f((u16)(p3 >> 16));
        ax0 = fmaf(v0, b2f((u16)(w0 & 0xffffu)), ax0); ay0 = fmaf(v0, b2f((u16)(w0 >> 16)), ay0);
        ax1 = fmaf(v1, b2f((u16)(w1 & 0xffffu)), ax1); ay1 = fmaf(v1, b2f((u16)(w1 >> 16)), ay1);
        ax2 = fmaf(v2, b2f((u16)(w2 & 0xffffu)), ax2); ay2 = fmaf(v2, b2f((u16)(w2 >> 16)), ay2);
        ax3 = fmaf(v3, b2f((u16)(w3 & 0xffffu)), ax3); ay3 = fmaf(v3, b2f((u16)(w3 >> 16)), ay3);
    }
    for (; j < e1; ++j) {
        const u32 p = ecv32[j];
        const u32 w = Yv[(p & 0xffffu) * 64 + lane];
        const float v = b2f((u16)(p >> 16));
        ax0 = fmaf(v, b2f((u16)(w & 0xffffu)), ax0);
        ay0 = fmaf(v, b2f((u16)(w >> 16)), ay0);
    }
    const float ax = (ax0 + ax1) + (ax2 + ax3);
    const float ay = (ay0 + ay1) + (ay2 + ay3);

    const float2 s = reinterpret_cast<const float2*>(ACC1)[i * 64 + lane];
    const float h0 = fmaxf(s.x + ax, 0.f);
    const float h1 = fmaxf(s.y + ay, 0.f);
    reinterpret_cast<u32*>(H1b)[i * 64 + lane] = (u32)f2b(h0) | ((u32)f2b(h1) << 16);
}

// ---------------------------------------------------------------------------
// GEMM2 (MFMA): Y2pb (bf16) = H1 @ Wp2 ; ACC2 (f32) = H1 @ Ws2 + (bs2+bp2)
// ---------------------------------------------------------------------------
__global__ __launch_bounds__(256) void k_gemm2(
    const u16* __restrict__ H1b,
    const u16* __restrict__ WT2p, const u16* __restrict__ WT2s,
    const float* __restrict__ bp, const float* __restrict__ bs,
    u16* __restrict__ Y2pb, float* __restrict__ ACC2)
{
    __shared__ u16 Hs[80 * 128];
    const int t = threadIdx.x;

    const uint4* Hv = reinterpret_cast<const uint4*>(H1b) + (size_t)blockIdx.x * 1280;
#pragma unroll
    for (int i = 0; i < 5; ++i) {
        const int ch = t + 256 * i;
        const uint4 v = Hv[ch];
        const int row = ch >> 4, c16 = ch & 15;
        const int e = row * 128 + ((c16 * 8) ^ ((row & 7) << 3));
        *reinterpret_cast<uint4*>(&Hs[e]) = v;
    }
    __syncthreads();

    const int lane = t & 63;
    const int w = t >> 6;
    const int mat = w >> 1;
    const int cbase = (w & 1) * 32;
    const u16* __restrict__ WT = mat ? WT2s : WT2p;
    const int lr = lane & 15;
    const int lk = (lane >> 4) * 8;

    f32x4 acc[5][2];
#pragma unroll
    for (int m = 0; m < 5; ++m)
#pragma unroll
        for (int n = 0; n < 2; ++n) acc[m][n] = (f32x4){0.f, 0.f, 0.f, 0.f};

#pragma unroll
    for (int kk = 0; kk < 4; ++kk) {
        short8 b[2];
#pragma unroll
        for (int n = 0; n < 2; ++n) {
            const int col = cbase + n * 16 + lr;
            b[n] = *reinterpret_cast<const short8*>(WT + col * 128 + kk * 32 + lk);
        }
#pragma unroll
        for (int m = 0; m < 5; ++m) {
            const int row = m * 16 + lr;
            const int e = row * 128 + ((kk * 32 + lk) ^ ((row & 7) << 3));
            const short8 a = *reinterpret_cast<const short8*>(&Hs[e]);
#pragma unroll
            for (int n = 0; n < 2; ++n)
                acc[m][n] = __builtin_amdgcn_mfma_f32_16x16x32_bf16(a, b[n], acc[m][n], 0, 0, 0);
        }
    }

    const int row0 = blockIdx.x * 80;
    const int rq = (lane >> 4) * 4;
    if (mat == 0) {
#pragma unroll
        for (int m = 0; m < 5; ++m)
#pragma unroll
            for (int n = 0; n < 2; ++n) {
                const int col = cbase + n * 16 + lr;
#pragma unroll
                for (int q = 0; q < 4; ++q)
                    Y2pb[(size_t)(row0 + m * 16 + rq + q) * 64 + col] = f2b(acc[m][n][q]);
            }
    } else {
        float bias[2];
#pragma unroll
        for (int n = 0; n < 2; ++n) {
            const int col = cbase + n * 16 + lr;
            bias[n] = bs[col] + bp[col];
        }
#pragma unroll
        for (int m = 0; m < 5; ++m)
#pragma unroll
            for (int n = 0; n < 2; ++n) {
                const int col = cbase + n * 16 + lr;
#pragma unroll
                for (int q = 0; q < 4; ++q)
                    ACC2[(size_t)(row0 + m * 16 + rq + q) * 64 + col] = acc[m][n][q] + bias[n];
            }
    }
}

// ---------------------------------------------------------------------------
// agg2: H2b[i] = relu( ACC2[i] + sum val_j * Y2pb[col_j] )   (bf16 out)
// ---------------------------------------------------------------------------
__global__ __launch_bounds__(256) void k_agg2(
    const int* __restrict__ rowptr, const u32* __restrict__ ecv32,
    const u16* __restrict__ Y2pb, const float* __restrict__ ACC2,
    u16* __restrict__ H2b)
{
    const unsigned tid = blockIdx.x * 256u + threadIdx.x;
    const unsigned lane = tid & 63u;
    const unsigned i = (tid >> 6) * 2 + (lane >> 5);
    if (i >= N_NODES) return;
    const unsigned hl = lane & 31u;

    const int e0 = rowptr[i];
    const int e1 = rowptr[i + 1];

    const u32* __restrict__ Yv = reinterpret_cast<const u32*>(Y2pb);

    float ax0 = 0.f, ay0 = 0.f, ax1 = 0.f, ay1 = 0.f;
    float ax2 = 0.f, ay2 = 0.f, ax3 = 0.f, ay3 = 0.f;
    int j = e0;
    for (; j + 3 < e1; j += 4) {
        const u32 p0 = ecv32[j], p1 = ecv32[j + 1], p2 = ecv32[j + 2], p3 = ecv32[j + 3];
        const u32 w0 = Yv[(p0 & 0xffffu) * 32 + hl];
        const u32 w1 = Yv[(p1 & 0xffffu) * 32 + hl];
        const u32 w2 = Yv[(p2 & 0xffffu) * 32 + hl];
        const u32 w3 = Yv[(p3 & 0xffffu) * 32 + hl];
        const float v0 = b2f((u16)(p0 >> 16)), v1 = b2f((u16)(p1 >> 16));
        const float v2 = b2f((u16)(p2 >> 16)), v3 = b2f((u16)(p3 >> 16));
        ax0 = fmaf(v0, b2f((u16)(w0 & 0xffffu)), ax0); ay0 = fmaf(v0, b2f((u16)(w0 >> 16)), ay0);
        ax1 = fmaf(v1, b2f((u16)(w1 & 0xffffu)), ax1); ay1 = fmaf(v1, b2f((u16)(w1 >> 16)), ay1);
        ax2 = fmaf(v2, b2f((u16)(w2 & 0xffffu)), ax2); ay2 = fmaf(v2, b2f((u16)(w2 >> 16)), ay2);
        ax3 = fmaf(v3, b2f((u16)(w3 & 0xffffu)), ax3); ay3 = fmaf(v3, b2f((u16)(w3 >> 16)), ay3);
    }
    for (; j < e1; ++j) {
        const u32 p = ecv32[j];
        const u32 w = Yv[(p & 0xffffu) * 32 + hl];
        const float v = b2f((u16)(p >> 16));
        ax0 = fmaf(v, b2f((u16)(w & 0xffffu)), ax0);
        ay0 = fmaf(v, b2f((u16)(w >> 16)), ay0);
    }
    const float ax = (ax0 + ax1) + (ax2 + ax3);
    const float ay = (ay0 + ay1) + (ay2 + ay3);

    const float2 s = reinterpret_cast<const float2*>(ACC2)[i * 32 + hl];
    const float h0 = fmaxf(s.x + ax, 0.f);
    const float h1 = fmaxf(s.y + ay, 0.f);
    reinterpret_cast<u32*>(H2b)[i * 32 + hl] = (u32)f2b(h0) | ((u32)f2b(h1) << 16);
}

// ---------------------------------------------------------------------------
// edgedot: out[e] = sigmoid( dot(H2[row], H2[col]) )
// ---------------------------------------------------------------------------
__global__ __launch_bounds__(256) void k_edgedot(
    const int* __restrict__ er, const int* __restrict__ ec,
    const u16* __restrict__ H2b, float* __restrict__ out)
{
    const int e = blockIdx.x * 256 + threadIdx.x;
    if (e >= N_EDGES) return;

    const int r = er[e];
    const int c = ec[e];

    const uint4* __restrict__ A = reinterpret_cast<const uint4*>(H2b + (size_t)r * 64);
    const uint4* __restrict__ B = reinterpret_cast<const uint4*>(H2b + (size_t)c * 64);

    float s0 = 0.f, s1 = 0.f, s2 = 0.f, s3 = 0.f;
#pragma unroll
    for (int k = 0; k < 8; ++k) {
        const uint4 a = A[k];
        const uint4 b = B[k];
        s0 = fmaf(b2f((u16)(a.x & 0xffffu)), b2f((u16)(b.x & 0xffffu)), s0);
        s1 = fmaf(b2f((u16)(a.x >> 16)),     b2f((u16)(b.x >> 16)),     s1);
        s2 = fmaf(b2f((u16)(a.y & 0xffffu)), b2f((u16)(b.y & 0xffffu)), s2);
        s3 = fmaf(b2f((u16)(a.y >> 16)),     b2f((u16)(b.y >> 16)),     s3);
        s0 = fmaf(b2f((u16)(a.z & 0xffffu)), b2f((u16)(b.z & 0xffffu)), s0);
        s1 = fmaf(b2f((u16)(a.z >> 16)),     b2f((u16)(b.z >> 16)),     s1);
        s2 = fmaf(b2f((u16)(a.w & 0xffffu)), b2f((u16)(b.w & 0xffffu)), s2);
        s3 = fmaf(b2f((u16)(a.w >> 16)),     b2f((u16)(b.w >> 16)),     s3);
    }
    const float p = (s0 + s1) + (s2 + s3);
    out[e] = 1.f / (1.f + expf(-p));
}

// ---------------------------------------------------------------------------
extern "C" void kernel_launch(void* const* d_in, const int* in_sizes, int n_in,
                              void* d_out, int out_size, void* d_ws, size_t ws_size,
                              hipStream_t stream)
{
    const float* X   = (const float*)d_in[0];
    const int*   er  = (const int*)d_in[1];
    const int*   ec  = (const int*)d_in[2];
    const float* ev  = (const float*)d_in[3];
    const float* Wp1 = (const float*)d_in[4];
    const float* bp1 = (const float*)d_in[5];
    const float* Ws1 = (const float*)d_in[6];
    const float* bs1 = (const float*)d_in[7];
    const float* Wp2 = (const float*)d_in[8];
    const float* bp2 = (const float*)d_in[9];
    const float* Ws2 = (const float*)d_in[10];
    const float* bs2 = (const float*)d_in[11];
    float* out = (float*)d_out;

    // workspace layout (float units from base):
    //   phase 0 (CSR build): parted uint2[800k] occupies ws[0,1.6M) floats (dead
    //     before gemm1 writes ACC1/Y2pb there).
    //   phase 1: ACC1 f32 [0, 6.4M) | Y1pb bf16 [6.4M, 9.6M) | H1b bf16 [9.6M, 12.8M)
    //   phase 2 (reuses [0,6.4M)): Y2pb bf16 [0,1.6M) | ACC2 f32 [1.6M,4.8M) | H2b bf16 [4.8M,6.4M)
    //   CSR at [12.8M,...): rp_base[50008] | bsum[64] | cur[256] | ecv32 u32[800k]
    //     | pkcv u32[800k] | WT bufs.  cnt[50000] aliases ecv32 (dead before sort2).
    float* ws    = (float*)d_ws;
    float* ACC1  = ws;
    u16*   Y1pb  = (u16*)(ws + (size_t)N_NODES * 128);
    u16*   H1b   = (u16*)(ws + (size_t)N_NODES * 128 + (size_t)N_NODES * 64);
    u16*   Y2pb  = (u16*)ws;
    float* ACC2  = ws + (size_t)N_NODES * 32;
    u16*   H2b   = (u16*)(ws + (size_t)N_NODES * 32 + (size_t)N_NODES * 64);
    uint2* parted = (uint2*)ws;           // CSR-phase alias of ACC1 region

    int*  rp_base = (int*)(ws + (size_t)N_NODES * 256);
    int*  rowptr  = rp_base + 3;          // rowptr+1 is 16B-aligned
    int*  bsum    = rp_base + 50008;      // 16B-aligned
    int*  cur     = bsum + 64;
    u32*  ecv32   = (u32*)(cur + 256);    // 16B-aligned
    int*  cnt     = (int*)ecv32;          // alias (dead before sort2)
    u32*  pkcv    = ecv32 + N_EDGES;
    u16*  WT1p    = (u16*)(pkcv + N_EDGES);
    u16*  WT1s    = WT1p + 128 * 128;
    u16*  WT2p    = WT1s + 128 * 128;
    u16*  WT2s    = WT2p + 64 * 128;

    const dim3 blk(256);
    const int node_waves  = (N_NODES * 64 + 255) / 256;        // 12500
    const int node2_waves = ((N_NODES / 2) * 64 + 255) / 256;  // 6250
    const int edge_thr    = (N_EDGES + 255) / 256;             // 3125
    const int scan_blocks = 49;
    const int part_blocks = (N_EDGES + PART_E - 1) / PART_E;   // 196
    const int gemm_blocks = N_NODES / 80;                      // 625 exact

    // weight prep + CSR build
    k_prepw   <<<384, 128, 0, stream>>>(Wp1, Ws1, Wp2, Ws2, WT1p, WT1s, WT2p, WT2s);
    hipMemsetAsync(cnt, 0, (size_t)N_NODES * sizeof(int), stream);
    k_histpack<<<edge_thr,    blk, 0, stream>>>(er, ec, ev, cnt, pkcv);
    k_scan1   <<<scan_blocks, blk, 0, stream>>>(cnt, rowptr, bsum);
    k_scan3   <<<scan_blocks, blk, 0, stream>>>(rowptr, bsum);
    k_initcur <<<1,           blk, 0, stream>>>(rowptr, cur);
    k_part1   <<<part_blocks, blk, 0, stream>>>(er, pkcv, cur, parted);
    k_sort2   <<<NBUCKET,     blk, 0, stream>>>(rowptr, parted, ecv32);

    // layer 1
    k_gemm1<<<gemm_blocks, blk, 0, stream>>>(X, WT1p, WT1s, bp1, bs1, Y1pb, ACC1);
    k_agg1 <<<node_waves,  blk, 0, stream>>>(rowptr, ecv32, Y1pb, ACC1, H1b);

    // layer 2
    k_gemm2<<<gemm_blocks, blk, 0, stream>>>(H1b, WT2p, WT2s, bp2, bs2, Y2pb, ACC2);
    k_agg2 <<<node2_waves, blk, 0, stream>>>(rowptr, ecv32, Y2pb, ACC2, H2b);

    // edge scores
    k_edgedot<<<edge_thr, blk, 0, stream>>>(er, ec, H2b, out);
}

// Round 9
// 197.806 us; speedup vs baseline: 5.3452x; 1.0091x over previous
//
#include <hip/hip_runtime.h>
#include <hip/hip_bf16.h>
#include <math.h>

#define N_NODES 50000
#define N_EDGES 800000
#define NBUCKET 196              // ceil(50000/256)
#define PART_E  4096             // edges per part1 block

typedef unsigned short u16;
typedef unsigned int   u32;
typedef short short8 __attribute__((ext_vector_type(8)));
typedef float f32x4  __attribute__((ext_vector_type(4)));

static __device__ __forceinline__ float b2f(u16 u) {
    union { u32 i; float f; } x; x.i = ((u32)u) << 16; return x.f;
}
static __device__ __forceinline__ u16 f2b(float f) {
    union { float f; u32 i; } x; x.f = f;
    u32 r = x.i + 0x7fffu + ((x.i >> 16) & 1u);   // round-to-nearest-even
    return (u16)(r >> 16);
}

// ---------------------------------------------------------------------------
// CSR build: zero -> histpack -> scan1 -> scan3 -> initcur -> part1 -> sort2
// Payload packed to 4B: low16 = col (N_NODES<65536), high16 = bf16(val).
// rowptr is NOT mutated: start(i) = rowptr[i], end(i) = rowptr[i+1].
// ---------------------------------------------------------------------------
__global__ __launch_bounds__(256) void k_zero(int* __restrict__ cnt)
{
    const int i = blockIdx.x * 256 + threadIdx.x;
    if (i < 12500) reinterpret_cast<int4*>(cnt)[i] = make_int4(0, 0, 0, 0);
}

__global__ __launch_bounds__(256) void k_histpack(
    const int* __restrict__ er, const int* __restrict__ ec,
    const float* __restrict__ ev,
    int* __restrict__ cnt, u32* __restrict__ pkcv)
{
    const int e = blockIdx.x * 256 + threadIdx.x;
    if (e >= N_EDGES) return;
    atomicAdd(&cnt[er[e]], 1);
    pkcv[e] = (u32)ec[e] | ((u32)f2b(ev[e]) << 16);
}

__global__ __launch_bounds__(256) void k_scan1(
    const int* __restrict__ cnt, int* __restrict__ rowptr, int* __restrict__ bsum)
{
    __shared__ int wsum[4];
    const int t = threadIdx.x;
    const int g4 = blockIdx.x * 256 + t;
    int4 v = make_int4(0, 0, 0, 0);
    if (g4 < 12500) v = reinterpret_cast<const int4*>(cnt)[g4];
    const int s0 = v.x, s1 = s0 + v.y, s2 = s1 + v.z, s3 = s2 + v.w;

    const int lane = t & 63, wv = t >> 6;
    int incl = s3;
#pragma unroll
    for (int off = 1; off < 64; off <<= 1) {
        int u = __shfl_up(incl, off, 64);
        if (lane >= off) incl += u;
    }
    if (lane == 63) wsum[wv] = incl;
    __syncthreads();
    int woff = 0;
    if (wv > 0) woff += wsum[0];
    if (wv > 1) woff += wsum[1];
    if (wv > 2) woff += wsum[2];
    const int excl = woff + incl - s3;

    if (g4 < 12500) {
        int4 o;
        o.x = excl + s0; o.y = excl + s1; o.z = excl + s2; o.w = excl + s3;
        reinterpret_cast<int4*>(rowptr + 1)[g4] = o;
    }
    if (t == 255) bsum[blockIdx.x] = woff + incl;
}

__global__ __launch_bounds__(256) void k_scan3(
    int* __restrict__ rowptr, const int* __restrict__ bsum)
{
    __shared__ int s_add;
    const int b = blockIdx.x;
    const int t = threadIdx.x;
    if (t < 64) {
        int v = (t < b) ? bsum[t] : 0;
#pragma unroll
        for (int off = 32; off; off >>= 1) v += __shfl_xor(v, off, 64);
        if (t == 0) s_add = v;
    }
    __syncthreads();
    if (b == 0) {
        if (t == 0) rowptr[0] = 0;
        return;
    }
    const int add = s_add;
    const int g4 = b * 256 + t;
    if (g4 < 12500) {
        int4* o4 = reinterpret_cast<int4*>(rowptr + 1);
        int4 v = o4[g4];
        v.x += add; v.y += add; v.z += add; v.w += add;
        o4[g4] = v;
    }
}

__global__ __launch_bounds__(256) void k_initcur(
    const int* __restrict__ rowptr, int* __restrict__ cur)
{
    const int t = threadIdx.x;
    if (t < NBUCKET) cur[t] = rowptr[t * 256];
}

// pass 1: partition edges into 196 row-buckets, grouped contiguous writes.
__global__ __launch_bounds__(256) void k_part1(
    const int* __restrict__ er, const u32* __restrict__ pkcv,
    int* __restrict__ cur, uint2* __restrict__ parted)
{
    __shared__ int hist[NBUCKET], base[NBUCKET], cnt[NBUCKET];
    const int t = threadIdx.x;
    if (t < NBUCKET) hist[t] = 0;
    __syncthreads();

    const int e0 = blockIdx.x * PART_E;
    int rows[16]; u32 pks[16];
#pragma unroll
    for (int i = 0; i < 16; ++i) {
        const int e = e0 + t + 256 * i;
        if (e < N_EDGES) {
            rows[i] = er[e];
            pks[i] = pkcv[e];
            atomicAdd(&hist[rows[i] >> 8], 1);
        } else rows[i] = -1;
    }
    __syncthreads();
    if (t < NBUCKET) { base[t] = atomicAdd(&cur[t], hist[t]); cnt[t] = 0; }
    __syncthreads();

#pragma unroll
    for (int i = 0; i < 16; ++i) {
        if (rows[i] >= 0) {
            const int b = rows[i] >> 8;
            const int off = atomicAdd(&cnt[b], 1);
            parted[base[b] + off] = make_uint2(pks[i], (u32)rows[i]);
        }
    }
}

// pass 2: one block per bucket; scatter confined to the bucket's CSR window.
__global__ __launch_bounds__(256) void k_sort2(
    const int* __restrict__ rowptr, const uint2* __restrict__ parted,
    u32* __restrict__ ecv32)
{
    __shared__ int cur[256];
    const int b = blockIdx.x;
    const int t = threadIdx.x;
    const int r0 = b * 256;
    const int rt = r0 + t;
    cur[t] = rowptr[rt < N_NODES ? rt : N_NODES];
    __syncthreads();

    const int lo = rowptr[r0];
    const int r1 = r0 + 256;
    const int hi = rowptr[r1 < N_NODES ? r1 : N_NODES];

    for (int e = lo + t; e < hi; e += 256) {
        const uint2 pe = parted[e];
        const int low = (int)(pe.y & 255u);
        const int slot = atomicAdd(&cur[low], 1);
        ecv32[slot] = pe.x;
    }
}

// ---------------------------------------------------------------------------
// prepw: WT[n][k] = bf16(W[k][n]) for all 4 weight matrices.
// ---------------------------------------------------------------------------
__global__ __launch_bounds__(128) void k_prepw(
    const float* __restrict__ Wp1, const float* __restrict__ Ws1,
    const float* __restrict__ Wp2, const float* __restrict__ Ws2,
    u16* __restrict__ WT1p, u16* __restrict__ WT1s,
    u16* __restrict__ WT2p, u16* __restrict__ WT2s)
{
    const int b = blockIdx.x, k = threadIdx.x;
    const float* src; u16* dst; int N, n;
    if (b < 128)      { src = Wp1; N = 128; n = b;       dst = WT1p + n * 128; }
    else if (b < 256) { src = Ws1; N = 128; n = b - 128; dst = WT1s + n * 128; }
    else if (b < 320) { src = Wp2; N = 64;  n = b - 256; dst = WT2p + n * 128; }
    else              { src = Ws2; N = 64;  n = b - 320; dst = WT2s + n * 128; }
    dst[k] = f2b(src[k * N + n]);
}

// ---------------------------------------------------------------------------
// GEMM1 (MFMA): Y1pb (bf16) = X @ Wp1 ; ACC1 (f32) = X @ Ws1 + (bs1+bp1)
// ---------------------------------------------------------------------------
__global__ __launch_bounds__(256) void k_gemm1(
    const float* __restrict__ X,
    const u16* __restrict__ WT1p, const u16* __restrict__ WT1s,
    const float* __restrict__ bp, const float* __restrict__ bs,
    u16* __restrict__ Y1pb, float* __restrict__ ACC1)
{
    __shared__ u16 Xs[80 * 128];
    const int t = threadIdx.x;

    const float4* Xv = reinterpret_cast<const float4*>(X) + (size_t)blockIdx.x * 2560;
#pragma unroll
    for (int i = 0; i < 10; ++i) {
        const int f4 = t + 256 * i;
        const float4 v = Xv[f4];
        const int row = f4 >> 5, col4 = f4 & 31;
        const u32 lo = (u32)f2b(v.x) | ((u32)f2b(v.y) << 16);
        const u32 hi = (u32)f2b(v.z) | ((u32)f2b(v.w) << 16);
        const int e = row * 128 + ((col4 * 4) ^ ((row & 7) << 3));
        *reinterpret_cast<uint2*>(&Xs[e]) = make_uint2(lo, hi);
    }
    __syncthreads();

    const int lane = t & 63;
    const int w = t >> 6;
    const int mat = w >> 1;
    const int cbase = (w & 1) * 64;
    const u16* __restrict__ WT = mat ? WT1s : WT1p;
    const int lr = lane & 15;
    const int lk = (lane >> 4) * 8;

    f32x4 acc[5][4];
#pragma unroll
    for (int m = 0; m < 5; ++m)
#pragma unroll
        for (int n = 0; n < 4; ++n) acc[m][n] = (f32x4){0.f, 0.f, 0.f, 0.f};

#pragma unroll
    for (int kk = 0; kk < 4; ++kk) {
        short8 b[4];
#pragma unroll
        for (int n = 0; n < 4; ++n) {
            const int col = cbase + n * 16 + lr;
            b[n] = *reinterpret_cast<const short8*>(WT + col * 128 + kk * 32 + lk);
        }
#pragma unroll
        for (int m = 0; m < 5; ++m) {
            const int row = m * 16 + lr;
            const int e = row * 128 + ((kk * 32 + lk) ^ ((row & 7) << 3));
            const short8 a = *reinterpret_cast<const short8*>(&Xs[e]);
#pragma unroll
            for (int n = 0; n < 4; ++n)
                acc[m][n] = __builtin_amdgcn_mfma_f32_16x16x32_bf16(a, b[n], acc[m][n], 0, 0, 0);
        }
    }

    const int row0 = blockIdx.x * 80;
    const int rq = (lane >> 4) * 4;
    if (mat == 0) {
#pragma unroll
        for (int m = 0; m < 5; ++m)
#pragma unroll
            for (int n = 0; n < 4; ++n) {
                const int col = cbase + n * 16 + lr;
#pragma unroll
                for (int q = 0; q < 4; ++q)
                    Y1pb[(size_t)(row0 + m * 16 + rq + q) * 128 + col] = f2b(acc[m][n][q]);
            }
    } else {
        float bias[4];
#pragma unroll
        for (int n = 0; n < 4; ++n) {
            const int col = cbase + n * 16 + lr;
            bias[n] = bs[col] + bp[col];
        }
#pragma unroll
        for (int m = 0; m < 5; ++m)
#pragma unroll
            for (int n = 0; n < 4; ++n) {
                const int col = cbase + n * 16 + lr;
#pragma unroll
                for (int q = 0; q < 4; ++q)
                    ACC1[(size_t)(row0 + m * 16 + rq + q) * 128 + col] = acc[m][n][q] + bias[n];
            }
    }
}

// ---------------------------------------------------------------------------
// agg1: H1b[i] = relu( ACC1[i] + sum val_j * Y1pb[col_j] )    (bf16 out)
// ---------------------------------------------------------------------------
__global__ __launch_bounds__(256) void k_agg1(
    const int* __restrict__ rowptr, const u32* __restrict__ ecv32,
    const u16* __restrict__ Y1pb, const float* __restrict__ ACC1,
    u16* __restrict__ H1b)
{
    const unsigned tid = blockIdx.x * 256u + threadIdx.x;
    const unsigned i = tid >> 6;
    if (i >= N_NODES) return;
    const unsigned lane = tid & 63u;

    const int e0 = rowptr[i];
    const int e1 = rowptr[i + 1];

    const u32* __restrict__ Yv = reinterpret_cast<const u32*>(Y1pb);

    float ax0 = 0.f, ay0 = 0.f, ax1 = 0.f, ay1 = 0.f;
    float ax2 = 0.f, ay2 = 0.f, ax3 = 0.f, ay3 = 0.f;
    int j = e0;
    for (; j + 3 < e1; j += 4) {
        const u32 p0 = ecv32[j], p1 = ecv32[j + 1], p2 = ecv32[j + 2], p3 = ecv32[j + 3];
        const u32 w0 = Yv[(p0 & 0xffffu) * 64 + lane];
        const u32 w1 = Yv[(p1 & 0xffffu) * 64 + lane];
        const u32 w2 = Yv[(p2 & 0xffffu) * 64 + lane];
        const u32 w3 = Yv[(p3 & 0xffffu) * 64 + lane];
        const float v0 = b2f((u16)(p0 >> 16)), v1 = b2f((u16)(p1 >> 16));
        const float v2 = b2f((u16)(p2 >> 16)), v3 = b2f((u16)(p3 >> 16));
        ax0 = fmaf(v0, b2f((u16)(w0 & 0xffffu)), ax0); ay0 = fmaf(v0, b2f((u16)(w0 >> 16)), ay0);
        ax1 = fmaf(v1, b2f((u16)(w1 & 0xffffu)), ax1); ay1 = fmaf(v1, b2f((u16)(w1 >> 16)), ay1);
        ax2 = fmaf(v2, b2f((u16)(w2 & 0xffffu)), ax2); ay2 = fmaf(v2, b2f((u16)(w2 >> 16)), ay2);
        ax3 = fmaf(v3, b2f((u16)(w3 & 0xffffu)), ax3); ay3 = fmaf(v3, b2f((u16)(w3 >> 16)), ay3);
    }
    for (; j < e1; ++j) {
        const u32 p = ecv32[j];
        const u32 w = Yv[(p & 0xffffu) * 64 + lane];
        const float v = b2f((u16)(p >> 16));
        ax0 = fmaf(v, b2f((u16)(w & 0xffffu)), ax0);
        ay0 = fmaf(v, b2f((u16)(w >> 16)), ay0);
    }
    const float ax = (ax0 + ax1) + (ax2 + ax3);
    const float ay = (ay0 + ay1) + (ay2 + ay3);

    const float2 s = reinterpret_cast<const float2*>(ACC1)[i * 64 + lane];
    const float h0 = fmaxf(s.x + ax, 0.f);
    const float h1 = fmaxf(s.y + ay, 0.f);
    reinterpret_cast<u32*>(H1b)[i * 64 + lane] = (u32)f2b(h0) | ((u32)f2b(h1) << 16);
}

// ---------------------------------------------------------------------------
// GEMM2 (MFMA): Y2pb (bf16) = H1 @ Wp2 ; ACC2 (f32) = H1 @ Ws2 + (bs2+bp2)
// ---------------------------------------------------------------------------
__global__ __launch_bounds__(256) void k_gemm2(
    const u16* __restrict__ H1b,
    const u16* __restrict__ WT2p, const u16* __restrict__ WT2s,
    const float* __restrict__ bp, const float* __restrict__ bs,
    u16* __restrict__ Y2pb, float* __restrict__ ACC2)
{
    __shared__ u16 Hs[80 * 128];
    const int t = threadIdx.x;

    const uint4* Hv = reinterpret_cast<const uint4*>(H1b) + (size_t)blockIdx.x * 1280;
#pragma unroll
    for (int i = 0; i < 5; ++i) {
        const int ch = t + 256 * i;
        const uint4 v = Hv[ch];
        const int row = ch >> 4, c16 = ch & 15;
        const int e = row * 128 + ((c16 * 8) ^ ((row & 7) << 3));
        *reinterpret_cast<uint4*>(&Hs[e]) = v;
    }
    __syncthreads();

    const int lane = t & 63;
    const int w = t >> 6;
    const int mat = w >> 1;
    const int cbase = (w & 1) * 32;
    const u16* __restrict__ WT = mat ? WT2s : WT2p;
    const int lr = lane & 15;
    const int lk = (lane >> 4) * 8;

    f32x4 acc[5][2];
#pragma unroll
    for (int m = 0; m < 5; ++m)
#pragma unroll
        for (int n = 0; n < 2; ++n) acc[m][n] = (f32x4){0.f, 0.f, 0.f, 0.f};

#pragma unroll
    for (int kk = 0; kk < 4; ++kk) {
        short8 b[2];
#pragma unroll
        for (int n = 0; n < 2; ++n) {
            const int col = cbase + n * 16 + lr;
            b[n] = *reinterpret_cast<const short8*>(WT + col * 128 + kk * 32 + lk);
        }
#pragma unroll
        for (int m = 0; m < 5; ++m) {
            const int row = m * 16 + lr;
            const int e = row * 128 + ((kk * 32 + lk) ^ ((row & 7) << 3));
            const short8 a = *reinterpret_cast<const short8*>(&Hs[e]);
#pragma unroll
            for (int n = 0; n < 2; ++n)
                acc[m][n] = __builtin_amdgcn_mfma_f32_16x16x32_bf16(a, b[n], acc[m][n], 0, 0, 0);
        }
    }

    const int row0 = blockIdx.x * 80;
    const int rq = (lane >> 4) * 4;
    if (mat == 0) {
#pragma unroll
        for (int m = 0; m < 5; ++m)
#pragma unroll
            for (int n = 0; n < 2; ++n) {
                const int col = cbase + n * 16 + lr;
#pragma unroll
                for (int q = 0; q < 4; ++q)
                    Y2pb[(size_t)(row0 + m * 16 + rq + q) * 64 + col] = f2b(acc[m][n][q]);
            }
    } else {
        float bias[2];
#pragma unroll
        for (int n = 0; n < 2; ++n) {
            const int col = cbase + n * 16 + lr;
            bias[n] = bs[col] + bp[col];
        }
#pragma unroll
        for (int m = 0; m < 5; ++m)
#pragma unroll
            for (int n = 0; n < 2; ++n) {
                const int col = cbase + n * 16 + lr;
#pragma unroll
                for (int q = 0; q < 4; ++q)
                    ACC2[(size_t)(row0 + m * 16 + rq + q) * 64 + col] = acc[m][n][q] + bias[n];
            }
    }
}

// ---------------------------------------------------------------------------
// agg2: H2b[i] = relu( ACC2[i] + sum val_j * Y2pb[col_j] )   (bf16 out)
// ---------------------------------------------------------------------------
__global__ __launch_bounds__(256) void k_agg2(
    const int* __restrict__ rowptr, const u32* __restrict__ ecv32,
    const u16* __restrict__ Y2pb, const float* __restrict__ ACC2,
    u16* __restrict__ H2b)
{
    const unsigned tid = blockIdx.x * 256u + threadIdx.x;
    const unsigned lane = tid & 63u;
    const unsigned i = (tid >> 6) * 2 + (lane >> 5);
    if (i >= N_NODES) return;
    const unsigned hl = lane & 31u;

    const int e0 = rowptr[i];
    const int e1 = rowptr[i + 1];

    const u32* __restrict__ Yv = reinterpret_cast<const u32*>(Y2pb);

    float ax0 = 0.f, ay0 = 0.f, ax1 = 0.f, ay1 = 0.f;
    float ax2 = 0.f, ay2 = 0.f, ax3 = 0.f, ay3 = 0.f;
    int j = e0;
    for (; j + 3 < e1; j += 4) {
        const u32 p0 = ecv32[j], p1 = ecv32[j + 1], p2 = ecv32[j + 2], p3 = ecv32[j + 3];
        const u32 w0 = Yv[(p0 & 0xffffu) * 32 + hl];
        const u32 w1 = Yv[(p1 & 0xffffu) * 32 + hl];
        const u32 w2 = Yv[(p2 & 0xffffu) * 32 + hl];
        const u32 w3 = Yv[(p3 & 0xffffu) * 32 + hl];
        const float v0 = b2f((u16)(p0 >> 16)), v1 = b2f((u16)(p1 >> 16));
        const float v2 = b2f((u16)(p2 >> 16)), v3 = b2f((u16)(p3 >> 16));
        ax0 = fmaf(v0, b2f((u16)(w0 & 0xffffu)), ax0); ay0 = fmaf(v0, b2f((u16)(w0 >> 16)), ay0);
        ax1 = fmaf(v1, b2f((u16)(w1 & 0xffffu)), ax1); ay1 = fmaf(v1, b2f((u16)(w1 >> 16)), ay1);
        ax2 = fmaf(v2, b2f((u16)(w2 & 0xffffu)), ax2); ay2 = fmaf(v2, b2f((u16)(w2 >> 16)), ay2);
        ax3 = fmaf(v3, b2f((u16)(w3 & 0xffffu)), ax3); ay3 = fmaf(v3, b2f((u16)(w3 >> 16)), ay3);
    }
    for (; j < e1; ++j) {
        const u32 p = ecv32[j];
        const u32 w = Yv[(p & 0xffffu) * 32 + hl];
        const float v = b2f((u16)(p >> 16));
        ax0 = fmaf(v, b2f((u16)(w & 0xffffu)), ax0);
        ay0 = fmaf(v, b2f((u16)(w >> 16)), ay0);
    }
    const float ax = (ax0 + ax1) + (ax2 + ax3);
    const float ay = (ay0 + ay1) + (ay2 + ay3);

    const float2 s = reinterpret_cast<const float2*>(ACC2)[i * 32 + hl];
    const float h0 = fmaxf(s.x + ax, 0.f);
    const float h1 = fmaxf(s.y + ay, 0.f);
    reinterpret_cast<u32*>(H2b)[i * 32 + hl] = (u32)f2b(h0) | ((u32)f2b(h1) << 16);
}

// ---------------------------------------------------------------------------
// edgedot: out[e] = sigmoid( dot(H2[row], H2[col]) )
// ---------------------------------------------------------------------------
__global__ __launch_bounds__(256) void k_edgedot(
    const int* __restrict__ er, const int* __restrict__ ec,
    const u16* __restrict__ H2b, float* __restrict__ out)
{
    const int e = blockIdx.x * 256 + threadIdx.x;
    if (e >= N_EDGES) return;

    const int r = er[e];
    const int c = ec[e];

    const uint4* __restrict__ A = reinterpret_cast<const uint4*>(H2b + (size_t)r * 64);
    const uint4* __restrict__ B = reinterpret_cast<const uint4*>(H2b + (size_t)c * 64);

    float s0 = 0.f, s1 = 0.f, s2 = 0.f, s3 = 0.f;
#pragma unroll
    for (int k = 0; k < 8; ++k) {
        const uint4 a = A[k];
        const uint4 b = B[k];
        s0 = fmaf(b2f((u16)(a.x & 0xffffu)), b2f((u16)(b.x & 0xffffu)), s0);
        s1 = fmaf(b2f((u16)(a.x >> 16)),     b2f((u16)(b.x >> 16)),     s1);
        s2 = fmaf(b2f((u16)(a.y & 0xffffu)), b2f((u16)(b.y & 0xffffu)), s2);
        s3 = fmaf(b2f((u16)(a.y >> 16)),     b2f((u16)(b.y >> 16)),     s3);
        s0 = fmaf(b2f((u16)(a.z & 0xffffu)), b2f((u16)(b.z & 0xffffu)), s0);
        s1 = fmaf(b2f((u16)(a.z >> 16)),     b2f((u16)(b.z >> 16)),     s1);
        s2 = fmaf(b2f((u16)(a.w & 0xffffu)), b2f((u16)(b.w & 0xffffu)), s2);
        s3 = fmaf(b2f((u16)(a.w >> 16)),     b2f((u16)(b.w >> 16)),     s3);
    }
    const float p = (s0 + s1) + (s2 + s3);
    out[e] = 1.f / (1.f + expf(-p));
}

// ---------------------------------------------------------------------------
extern "C" void kernel_launch(void* const* d_in, const int* in_sizes, int n_in,
                              void* d_out, int out_size, void* d_ws, size_t ws_size,
                              hipStream_t stream)
{
    const float* X   = (const float*)d_in[0];
    const int*   er  = (const int*)d_in[1];
    const int*   ec  = (const int*)d_in[2];
    const float* ev  = (const float*)d_in[3];
    const float* Wp1 = (const float*)d_in[4];
    const float* bp1 = (const float*)d_in[5];
    const float* Ws1 = (const float*)d_in[6];
    const float* bs1 = (const float*)d_in[7];
    const float* Wp2 = (const float*)d_in[8];
    const float* bp2 = (const float*)d_in[9];
    const float* Ws2 = (const float*)d_in[10];
    const float* bs2 = (const float*)d_in[11];
    float* out = (float*)d_out;

    // workspace layout (float units from base):
    //   phase 0 (CSR build): parted uint2[800k] occupies ws[0,1.6M) floats (dead
    //     before gemm1 writes ACC1/Y2pb there).
    //   phase 1: ACC1 f32 [0, 6.4M) | Y1pb bf16 [6.4M, 9.6M) | H1b bf16 [9.6M, 12.8M)
    //   phase 2 (reuses [0,6.4M)): Y2pb bf16 [0,1.6M) | ACC2 f32 [1.6M,4.8M) | H2b bf16 [4.8M,6.4M)
    //   CSR at [12.8M,...): rp_base[50008] | bsum[64] | cur[256] | ecv32 u32[800k]
    //     | pkcv u32[800k] | WT bufs.  cnt[50000] aliases ecv32 (dead before sort2).
    float* ws    = (float*)d_ws;
    float* ACC1  = ws;
    u16*   Y1pb  = (u16*)(ws + (size_t)N_NODES * 128);
    u16*   H1b   = (u16*)(ws + (size_t)N_NODES * 128 + (size_t)N_NODES * 64);
    u16*   Y2pb  = (u16*)ws;
    float* ACC2  = ws + (size_t)N_NODES * 32;
    u16*   H2b   = (u16*)(ws + (size_t)N_NODES * 32 + (size_t)N_NODES * 64);
    uint2* parted = (uint2*)ws;           // CSR-phase alias of ACC1 region

    int*  rp_base = (int*)(ws + (size_t)N_NODES * 256);
    int*  rowptr  = rp_base + 3;          // rowptr+1 is 16B-aligned
    int*  bsum    = rp_base + 50008;      // 16B-aligned
    int*  cur     = bsum + 64;
    u32*  ecv32   = (u32*)(cur + 256);    // 16B-aligned
    int*  cnt     = (int*)ecv32;          // alias (dead before sort2)
    u32*  pkcv    = ecv32 + N_EDGES;
    u16*  WT1p    = (u16*)(pkcv + N_EDGES);
    u16*  WT1s    = WT1p + 128 * 128;
    u16*  WT2p    = WT1s + 128 * 128;
    u16*  WT2s    = WT2p + 64 * 128;

    const dim3 blk(256);
    const int node_waves  = (N_NODES * 64 + 255) / 256;        // 12500
    const int node2_waves = ((N_NODES / 2) * 64 + 255) / 256;  // 6250
    const int edge_thr    = (N_EDGES + 255) / 256;             // 3125
    const int scan_blocks = 49;
    const int part_blocks = (N_EDGES + PART_E - 1) / PART_E;   // 196
    const int gemm_blocks = N_NODES / 80;                      // 625 exact

    // weight prep + CSR build
    k_prepw   <<<384, 128, 0, stream>>>(Wp1, Ws1, Wp2, Ws2, WT1p, WT1s, WT2p, WT2s);
    k_zero    <<<scan_blocks, blk, 0, stream>>>(cnt);
    k_histpack<<<edge_thr,    blk, 0, stream>>>(er, ec, ev, cnt, pkcv);
    k_scan1   <<<scan_blocks, blk, 0, stream>>>(cnt, rowptr, bsum);
    k_scan3   <<<scan_blocks, blk, 0, stream>>>(rowptr, bsum);
    k_initcur <<<1,           blk, 0, stream>>>(rowptr, cur);
    k_part1   <<<part_blocks, blk, 0, stream>>>(er, pkcv, cur, parted);
    k_sort2   <<<NBUCKET,     blk, 0, stream>>>(rowptr, parted, ecv32);

    // layer 1
    k_gemm1<<<gemm_blocks, blk, 0, stream>>>(X, WT1p, WT1s, bp1, bs1, Y1pb, ACC1);
    k_agg1 <<<node_waves,  blk, 0, stream>>>(rowptr, ecv32, Y1pb, ACC1, H1b);

    // layer 2
    k_gemm2<<<gemm_blocks, blk, 0, stream>>>(H1b, WT2p, WT2s, bp2, bs2, Y2pb, ACC2);
    k_agg2 <<<node2_waves, blk, 0, stream>>>(rowptr, ecv32, Y2pb, ACC2, H2b);

    // edge scores
    k_edgedot<<<edge_thr, blk, 0, stream>>>(er, ec, H2b, out);
}

// Round 10
// 187.408 us; speedup vs baseline: 5.6418x; 1.0555x over previous
//
#include <hip/hip_runtime.h>
#include <hip/hip_bf16.h>
#include <math.h>

#define N_NODES 50000
#define N_EDGES 800000
#define NBUCKET 196              // ceil(50000/256)
#define PART_E  4096             // edges per part1 block
#define GEMM_BLOCKS 625          // N_NODES / 80

typedef unsigned short u16;
typedef unsigned int   u32;
typedef short short8 __attribute__((ext_vector_type(8)));
typedef float f32x4  __attribute__((ext_vector_type(4)));

static __device__ __forceinline__ float b2f(u16 u) {
    union { u32 i; float f; } x; x.i = ((u32)u) << 16; return x.f;
}
static __device__ __forceinline__ u16 f2b(float f) {
    union { float f; u32 i; } x; x.f = f;
    u32 r = x.i + 0x7fffu + ((x.i >> 16) & 1u);   // round-to-nearest-even
    return (u16)(r >> 16);
}

// ---------------------------------------------------------------------------
// prep: blocks [0,49) zero cnt; blocks [49,241) transpose weights to bf16.
// ---------------------------------------------------------------------------
__global__ __launch_bounds__(256) void k_prep(
    const float* __restrict__ Wp1, const float* __restrict__ Ws1,
    const float* __restrict__ Wp2, const float* __restrict__ Ws2,
    u16* __restrict__ WT1p, u16* __restrict__ WT1s,
    u16* __restrict__ WT2p, u16* __restrict__ WT2s,
    int* __restrict__ cnt)
{
    const int b = blockIdx.x, t = threadIdx.x;
    if (b < 49) {
        const int i = b * 256 + t;
        if (i < 12500) reinterpret_cast<int4*>(cnt)[i] = make_int4(0, 0, 0, 0);
        return;
    }
    const int idx = (b - 49) * 2 + (t >> 7);   // [0,384)
    const int k = t & 127;
    const float* src; u16* dst; int N, n;
    if (idx < 128)      { src = Wp1; N = 128; n = idx;       dst = WT1p + n * 128; }
    else if (idx < 256) { src = Ws1; N = 128; n = idx - 128; dst = WT1s + n * 128; }
    else if (idx < 320) { src = Wp2; N = 64;  n = idx - 256; dst = WT2p + n * 128; }
    else                { src = Ws2; N = 64;  n = idx - 320; dst = WT2s + n * 128; }
    dst[k] = f2b(src[k * N + n]);
}

// ---------------------------------------------------------------------------
// histpack: per-row counts + pack (col,bf16(val)) to 4B.
// ---------------------------------------------------------------------------
__global__ __launch_bounds__(256) void k_histpack(
    const int* __restrict__ er, const int* __restrict__ ec,
    const float* __restrict__ ev,
    int* __restrict__ cnt, u32* __restrict__ pkcv)
{
    const int e = blockIdx.x * 256 + threadIdx.x;
    if (e >= N_EDGES) return;
    atomicAdd(&cnt[er[e]], 1);
    pkcv[e] = (u32)ec[e] | ((u32)f2b(ev[e]) << 16);
}

__global__ __launch_bounds__(256) void k_scan1(
    const int* __restrict__ cnt, int* __restrict__ rowptr, int* __restrict__ bsum)
{
    __shared__ int wsum[4];
    const int t = threadIdx.x;
    const int g4 = blockIdx.x * 256 + t;
    int4 v = make_int4(0, 0, 0, 0);
    if (g4 < 12500) v = reinterpret_cast<const int4*>(cnt)[g4];
    const int s0 = v.x, s1 = s0 + v.y, s2 = s1 + v.z, s3 = s2 + v.w;

    const int lane = t & 63, wv = t >> 6;
    int incl = s3;
#pragma unroll
    for (int off = 1; off < 64; off <<= 1) {
        int u = __shfl_up(incl, off, 64);
        if (lane >= off) incl += u;
    }
    if (lane == 63) wsum[wv] = incl;
    __syncthreads();
    int woff = 0;
    if (wv > 0) woff += wsum[0];
    if (wv > 1) woff += wsum[1];
    if (wv > 2) woff += wsum[2];
    const int excl = woff + incl - s3;

    if (g4 < 12500) {
        int4 o;
        o.x = excl + s0; o.y = excl + s1; o.z = excl + s2; o.w = excl + s3;
        reinterpret_cast<int4*>(rowptr + 1)[g4] = o;
    }
    if (t == 255) bsum[blockIdx.x] = woff + incl;
}

// scan3: add block offsets; also emit bucket cursors cur[k] = rowptr[k*256].
__global__ __launch_bounds__(256) void k_scan3(
    int* __restrict__ rowptr, const int* __restrict__ bsum, int* __restrict__ cur)
{
    __shared__ int s_add;
    const int b = blockIdx.x;
    const int t = threadIdx.x;
    if (t < 64) {
        int v = (t < b) ? bsum[t] : 0;
#pragma unroll
        for (int off = 32; off; off >>= 1) v += __shfl_xor(v, off, 64);
        if (t == 0) s_add = v;
    }
    __syncthreads();
    const int add = s_add;
    const int g4 = b * 256 + t;
    if (g4 < 12500) {
        int4* o4 = reinterpret_cast<int4*>(rowptr + 1);
        int4 v = o4[g4];
        v.x += add; v.y += add; v.z += add; v.w += add;
        if (b) o4[g4] = v;                      // b==0: add==0, skip write
        const int i0 = 4 * g4 + 1;
        const int vv[4] = {v.x, v.y, v.z, v.w};
#pragma unroll
        for (int j = 0; j < 4; ++j) {
            const int idx = i0 + j;
            if (idx < N_NODES && (idx & 255) == 0) cur[idx >> 8] = vv[j];
        }
    }
    if (b == 0 && t == 0) { rowptr[0] = 0; cur[0] = 0; }
}

// ---------------------------------------------------------------------------
// FAT kernel: blocks [0,625) = GEMM1 (MFMA), blocks [625,821) = part1.
// GEMM1: Y1pb (bf16) = X @ Wp1 ; ACC1b (bf16) = X @ Ws1 + (bs1+bp1)
// part1: partition edges into 196 row-buckets (grouped contiguous writes).
// Independent inputs -> co-resident execution hides the partition pass.
// ---------------------------------------------------------------------------
__global__ __launch_bounds__(256) void k_gemm1_part1(
    const float* __restrict__ X,
    const u16* __restrict__ WT1p, const u16* __restrict__ WT1s,
    const float* __restrict__ bp, const float* __restrict__ bs,
    u16* __restrict__ Y1pb, u16* __restrict__ ACC1b,
    const int* __restrict__ er, const u32* __restrict__ pkcv,
    int* __restrict__ cur, uint2* __restrict__ parted)
{
    __shared__ u16 Xs[80 * 128];
    __shared__ int hist[NBUCKET], base[NBUCKET], cntl[NBUCKET];
    const int t = threadIdx.x;

    if (blockIdx.x >= GEMM_BLOCKS) {
        // ---- part1 ----
        if (t < NBUCKET) hist[t] = 0;
        __syncthreads();

        const int e0 = (blockIdx.x - GEMM_BLOCKS) * PART_E;
        int rows[16]; u32 pks[16];
#pragma unroll
        for (int i = 0; i < 16; ++i) {
            const int e = e0 + t + 256 * i;
            if (e < N_EDGES) {
                rows[i] = er[e];
                pks[i] = pkcv[e];
                atomicAdd(&hist[rows[i] >> 8], 1);
            } else rows[i] = -1;
        }
        __syncthreads();
        if (t < NBUCKET) { base[t] = atomicAdd(&cur[t], hist[t]); cntl[t] = 0; }
        __syncthreads();

#pragma unroll
        for (int i = 0; i < 16; ++i) {
            if (rows[i] >= 0) {
                const int b = rows[i] >> 8;
                const int off = atomicAdd(&cntl[b], 1);
                parted[base[b] + off] = make_uint2(pks[i], (u32)rows[i]);
            }
        }
        return;
    }

    // ---- GEMM1 ----
    const float4* Xv = reinterpret_cast<const float4*>(X) + (size_t)blockIdx.x * 2560;
#pragma unroll
    for (int i = 0; i < 10; ++i) {
        const int f4 = t + 256 * i;
        const float4 v = Xv[f4];
        const int row = f4 >> 5, col4 = f4 & 31;
        const u32 lo = (u32)f2b(v.x) | ((u32)f2b(v.y) << 16);
        const u32 hi = (u32)f2b(v.z) | ((u32)f2b(v.w) << 16);
        const int e = row * 128 + ((col4 * 4) ^ ((row & 7) << 3));
        *reinterpret_cast<uint2*>(&Xs[e]) = make_uint2(lo, hi);
    }
    __syncthreads();

    const int lane = t & 63;
    const int w = t >> 6;
    const int mat = w >> 1;
    const int cbase = (w & 1) * 64;
    const u16* __restrict__ WT = mat ? WT1s : WT1p;
    const int lr = lane & 15;
    const int lk = (lane >> 4) * 8;

    f32x4 acc[5][4];
#pragma unroll
    for (int m = 0; m < 5; ++m)
#pragma unroll
        for (int n = 0; n < 4; ++n) acc[m][n] = (f32x4){0.f, 0.f, 0.f, 0.f};

#pragma unroll
    for (int kk = 0; kk < 4; ++kk) {
        short8 b[4];
#pragma unroll
        for (int n = 0; n < 4; ++n) {
            const int col = cbase + n * 16 + lr;
            b[n] = *reinterpret_cast<const short8*>(WT + col * 128 + kk * 32 + lk);
        }
#pragma unroll
        for (int m = 0; m < 5; ++m) {
            const int row = m * 16 + lr;
            const int e = row * 128 + ((kk * 32 + lk) ^ ((row & 7) << 3));
            const short8 a = *reinterpret_cast<const short8*>(&Xs[e]);
#pragma unroll
            for (int n = 0; n < 4; ++n)
                acc[m][n] = __builtin_amdgcn_mfma_f32_16x16x32_bf16(a, b[n], acc[m][n], 0, 0, 0);
        }
    }

    const int row0 = blockIdx.x * 80;
    const int rq = (lane >> 4) * 4;
    if (mat == 0) {
#pragma unroll
        for (int m = 0; m < 5; ++m)
#pragma unroll
            for (int n = 0; n < 4; ++n) {
                const int col = cbase + n * 16 + lr;
#pragma unroll
                for (int q = 0; q < 4; ++q)
                    Y1pb[(size_t)(row0 + m * 16 + rq + q) * 128 + col] = f2b(acc[m][n][q]);
            }
    } else {
        float bias[4];
#pragma unroll
        for (int n = 0; n < 4; ++n) {
            const int col = cbase + n * 16 + lr;
            bias[n] = bs[col] + bp[col];
        }
#pragma unroll
        for (int m = 0; m < 5; ++m)
#pragma unroll
            for (int n = 0; n < 4; ++n) {
                const int col = cbase + n * 16 + lr;
#pragma unroll
                for (int q = 0; q < 4; ++q)
                    ACC1b[(size_t)(row0 + m * 16 + rq + q) * 128 + col] = f2b(acc[m][n][q] + bias[n]);
            }
    }
}

// pass 2: one block per bucket; scatter confined to the bucket's CSR window.
__global__ __launch_bounds__(256) void k_sort2(
    const int* __restrict__ rowptr, const uint2* __restrict__ parted,
    u32* __restrict__ ecv32)
{
    __shared__ int cur[256];
    const int b = blockIdx.x;
    const int t = threadIdx.x;
    const int r0 = b * 256;
    const int rt = r0 + t;
    cur[t] = rowptr[rt < N_NODES ? rt : N_NODES];
    __syncthreads();

    const int lo = rowptr[r0];
    const int r1 = r0 + 256;
    const int hi = rowptr[r1 < N_NODES ? r1 : N_NODES];

    for (int e = lo + t; e < hi; e += 256) {
        const uint2 pe = parted[e];
        const int low = (int)(pe.y & 255u);
        const int slot = atomicAdd(&cur[low], 1);
        ecv32[slot] = pe.x;
    }
}

// ---------------------------------------------------------------------------
// agg1: H1b[i] = relu( ACC1b[i] + sum val_j * Y1pb[col_j] )    (bf16 out)
// ---------------------------------------------------------------------------
__global__ __launch_bounds__(256) void k_agg1(
    const int* __restrict__ rowptr, const u32* __restrict__ ecv32,
    const u16* __restrict__ Y1pb, const u16* __restrict__ ACC1b,
    u16* __restrict__ H1b)
{
    const unsigned tid = blockIdx.x * 256u + threadIdx.x;
    const unsigned i = tid >> 6;
    if (i >= N_NODES) return;
    const unsigned lane = tid & 63u;

    const int e0 = rowptr[i];
    const int e1 = rowptr[i + 1];

    const u32* __restrict__ Yv = reinterpret_cast<const u32*>(Y1pb);

    float ax0 = 0.f, ay0 = 0.f, ax1 = 0.f, ay1 = 0.f;
    float ax2 = 0.f, ay2 = 0.f, ax3 = 0.f, ay3 = 0.f;
    int j = e0;
    for (; j + 3 < e1; j += 4) {
        const u32 p0 = ecv32[j], p1 = ecv32[j + 1], p2 = ecv32[j + 2], p3 = ecv32[j + 3];
        const u32 w0 = Yv[(p0 & 0xffffu) * 64 + lane];
        const u32 w1 = Yv[(p1 & 0xffffu) * 64 + lane];
        const u32 w2 = Yv[(p2 & 0xffffu) * 64 + lane];
        const u32 w3 = Yv[(p3 & 0xffffu) * 64 + lane];
        const float v0 = b2f((u16)(p0 >> 16)), v1 = b2f((u16)(p1 >> 16));
        const float v2 = b2f((u16)(p2 >> 16)), v3 = b2f((u16)(p3 >> 16));
        ax0 = fmaf(v0, b2f((u16)(w0 & 0xffffu)), ax0); ay0 = fmaf(v0, b2f((u16)(w0 >> 16)), ay0);
        ax1 = fmaf(v1, b2f((u16)(w1 & 0xffffu)), ax1); ay1 = fmaf(v1, b2f((u16)(w1 >> 16)), ay1);
        ax2 = fmaf(v2, b2f((u16)(w2 & 0xffffu)), ax2); ay2 = fmaf(v2, b2f((u16)(w2 >> 16)), ay2);
        ax3 = fmaf(v3, b2f((u16)(w3 & 0xffffu)), ax3); ay3 = fmaf(v3, b2f((u16)(w3 >> 16)), ay3);
    }
    for (; j < e1; ++j) {
        const u32 p = ecv32[j];
        const u32 w = Yv[(p & 0xffffu) * 64 + lane];
        const float v = b2f((u16)(p >> 16));
        ax0 = fmaf(v, b2f((u16)(w & 0xffffu)), ax0);
        ay0 = fmaf(v, b2f((u16)(w >> 16)), ay0);
    }
    const float ax = (ax0 + ax1) + (ax2 + ax3);
    const float ay = (ay0 + ay1) + (ay2 + ay3);

    const u32 s = reinterpret_cast<const u32*>(ACC1b)[i * 64 + lane];
    const float h0 = fmaxf(b2f((u16)(s & 0xffffu)) + ax, 0.f);
    const float h1 = fmaxf(b2f((u16)(s >> 16)) + ay, 0.f);
    reinterpret_cast<u32*>(H1b)[i * 64 + lane] = (u32)f2b(h0) | ((u32)f2b(h1) << 16);
}

// ---------------------------------------------------------------------------
// GEMM2 (MFMA): Y2pb (bf16) = H1 @ Wp2 ; ACC2b (bf16) = H1 @ Ws2 + (bs2+bp2)
// ---------------------------------------------------------------------------
__global__ __launch_bounds__(256) void k_gemm2(
    const u16* __restrict__ H1b,
    const u16* __restrict__ WT2p, const u16* __restrict__ WT2s,
    const float* __restrict__ bp, const float* __restrict__ bs,
    u16* __restrict__ Y2pb, u16* __restrict__ ACC2b)
{
    __shared__ u16 Hs[80 * 128];
    const int t = threadIdx.x;

    const uint4* Hv = reinterpret_cast<const uint4*>(H1b) + (size_t)blockIdx.x * 1280;
#pragma unroll
    for (int i = 0; i < 5; ++i) {
        const int ch = t + 256 * i;
        const uint4 v = Hv[ch];
        const int row = ch >> 4, c16 = ch & 15;
        const int e = row * 128 + ((c16 * 8) ^ ((row & 7) << 3));
        *reinterpret_cast<uint4*>(&Hs[e]) = v;
    }
    __syncthreads();

    const int lane = t & 63;
    const int w = t >> 6;
    const int mat = w >> 1;
    const int cbase = (w & 1) * 32;
    const u16* __restrict__ WT = mat ? WT2s : WT2p;
    const int lr = lane & 15;
    const int lk = (lane >> 4) * 8;

    f32x4 acc[5][2];
#pragma unroll
    for (int m = 0; m < 5; ++m)
#pragma unroll
        for (int n = 0; n < 2; ++n) acc[m][n] = (f32x4){0.f, 0.f, 0.f, 0.f};

#pragma unroll
    for (int kk = 0; kk < 4; ++kk) {
        short8 b[2];
#pragma unroll
        for (int n = 0; n < 2; ++n) {
            const int col = cbase + n * 16 + lr;
            b[n] = *reinterpret_cast<const short8*>(WT + col * 128 + kk * 32 + lk);
        }
#pragma unroll
        for (int m = 0; m < 5; ++m) {
            const int row = m * 16 + lr;
            const int e = row * 128 + ((kk * 32 + lk) ^ ((row & 7) << 3));
            const short8 a = *reinterpret_cast<const short8*>(&Hs[e]);
#pragma unroll
            for (int n = 0; n < 2; ++n)
                acc[m][n] = __builtin_amdgcn_mfma_f32_16x16x32_bf16(a, b[n], acc[m][n], 0, 0, 0);
        }
    }

    const int row0 = blockIdx.x * 80;
    const int rq = (lane >> 4) * 4;
    if (mat == 0) {
#pragma unroll
        for (int m = 0; m < 5; ++m)
#pragma unroll
            for (int n = 0; n < 2; ++n) {
                const int col = cbase + n * 16 + lr;
#pragma unroll
                for (int q = 0; q < 4; ++q)
                    Y2pb[(size_t)(row0 + m * 16 + rq + q) * 64 + col] = f2b(acc[m][n][q]);
            }
    } else {
        float bias[2];
#pragma unroll
        for (int n = 0; n < 2; ++n) {
            const int col = cbase + n * 16 + lr;
            bias[n] = bs[col] + bp[col];
        }
#pragma unroll
        for (int m = 0; m < 5; ++m)
#pragma unroll
            for (int n = 0; n < 2; ++n) {
                const int col = cbase + n * 16 + lr;
#pragma unroll
                for (int q = 0; q < 4; ++q)
                    ACC2b[(size_t)(row0 + m * 16 + rq + q) * 64 + col] = f2b(acc[m][n][q] + bias[n]);
            }
    }
}

// ---------------------------------------------------------------------------
// agg2: H2b[i] = relu( ACC2b[i] + sum val_j * Y2pb[col_j] )   (bf16 out)
// ---------------------------------------------------------------------------
__global__ __launch_bounds__(256) void k_agg2(
    const int* __restrict__ rowptr, const u32* __restrict__ ecv32,
    const u16* __restrict__ Y2pb, const u16* __restrict__ ACC2b,
    u16* __restrict__ H2b)
{
    const unsigned tid = blockIdx.x * 256u + threadIdx.x;
    const unsigned lane = tid & 63u;
    const unsigned i = (tid >> 6) * 2 + (lane >> 5);
    if (i >= N_NODES) return;
    const unsigned hl = lane & 31u;

    const int e0 = rowptr[i];
    const int e1 = rowptr[i + 1];

    const u32* __restrict__ Yv = reinterpret_cast<const u32*>(Y2pb);

    float ax0 = 0.f, ay0 = 0.f, ax1 = 0.f, ay1 = 0.f;
    float ax2 = 0.f, ay2 = 0.f, ax3 = 0.f, ay3 = 0.f;
    int j = e0;
    for (; j + 3 < e1; j += 4) {
        const u32 p0 = ecv32[j], p1 = ecv32[j + 1], p2 = ecv32[j + 2], p3 = ecv32[j + 3];
        const u32 w0 = Yv[(p0 & 0xffffu) * 32 + hl];
        const u32 w1 = Yv[(p1 & 0xffffu) * 32 + hl];
        const u32 w2 = Yv[(p2 & 0xffffu) * 32 + hl];
        const u32 w3 = Yv[(p3 & 0xffffu) * 32 + hl];
        const float v0 = b2f((u16)(p0 >> 16)), v1 = b2f((u16)(p1 >> 16));
        const float v2 = b2f((u16)(p2 >> 16)), v3 = b2f((u16)(p3 >> 16));
        ax0 = fmaf(v0, b2f((u16)(w0 & 0xffffu)), ax0); ay0 = fmaf(v0, b2f((u16)(w0 >> 16)), ay0);
        ax1 = fmaf(v1, b2f((u16)(w1 & 0xffffu)), ax1); ay1 = fmaf(v1, b2f((u16)(w1 >> 16)), ay1);
        ax2 = fmaf(v2, b2f((u16)(w2 & 0xffffu)), ax2); ay2 = fmaf(v2, b2f((u16)(w2 >> 16)), ay2);
        ax3 = fmaf(v3, b2f((u16)(w3 & 0xffffu)), ax3); ay3 = fmaf(v3, b2f((u16)(w3 >> 16)), ay3);
    }
    for (; j < e1; ++j) {
        const u32 p = ecv32[j];
        const u32 w = Yv[(p & 0xffffu) * 32 + hl];
        const float v = b2f((u16)(p >> 16));
        ax0 = fmaf(v, b2f((u16)(w & 0xffffu)), ax0);
        ay0 = fmaf(v, b2f((u16)(w >> 16)), ay0);
    }
    const float ax = (ax0 + ax1) + (ax2 + ax3);
    const float ay = (ay0 + ay1) + (ay2 + ay3);

    const u32 s = reinterpret_cast<const u32*>(ACC2b)[i * 32 + hl];
    const float h0 = fmaxf(b2f((u16)(s & 0xffffu)) + ax, 0.f);
    const float h1 = fmaxf(b2f((u16)(s >> 16)) + ay, 0.f);
    reinterpret_cast<u32*>(H2b)[i * 32 + hl] = (u32)f2b(h0) | ((u32)f2b(h1) << 16);
}

// ---------------------------------------------------------------------------
// edgedot: out[e] = sigmoid( dot(H2[row], H2[col]) )
// ---------------------------------------------------------------------------
__global__ __launch_bounds__(256) void k_edgedot(
    const int* __restrict__ er, const int* __restrict__ ec,
    const u16* __restrict__ H2b, float* __restrict__ out)
{
    const int e = blockIdx.x * 256 + threadIdx.x;
    if (e >= N_EDGES) return;

    const int r = er[e];
    const int c = ec[e];

    const uint4* __restrict__ A = reinterpret_cast<const uint4*>(H2b + (size_t)r * 64);
    const uint4* __restrict__ B = reinterpret_cast<const uint4*>(H2b + (size_t)c * 64);

    float s0 = 0.f, s1 = 0.f, s2 = 0.f, s3 = 0.f;
#pragma unroll
    for (int k = 0; k < 8; ++k) {
        const uint4 a = A[k];
        const uint4 b = B[k];
        s0 = fmaf(b2f((u16)(a.x & 0xffffu)), b2f((u16)(b.x & 0xffffu)), s0);
        s1 = fmaf(b2f((u16)(a.x >> 16)),     b2f((u16)(b.x >> 16)),     s1);
        s2 = fmaf(b2f((u16)(a.y & 0xffffu)), b2f((u16)(b.y & 0xffffu)), s2);
        s3 = fmaf(b2f((u16)(a.y >> 16)),     b2f((u16)(b.y >> 16)),     s3);
        s0 = fmaf(b2f((u16)(a.z & 0xffffu)), b2f((u16)(b.z & 0xffffu)), s0);
        s1 = fmaf(b2f((u16)(a.z >> 16)),     b2f((u16)(b.z >> 16)),     s1);
        s2 = fmaf(b2f((u16)(a.w & 0xffffu)), b2f((u16)(b.w & 0xffffu)), s2);
        s3 = fmaf(b2f((u16)(a.w >> 16)),     b2f((u16)(b.w >> 16)),     s3);
    }
    const float p = (s0 + s1) + (s2 + s3);
    out[e] = 1.f / (1.f + expf(-p));
}

// ---------------------------------------------------------------------------
extern "C" void kernel_launch(void* const* d_in, const int* in_sizes, int n_in,
                              void* d_out, int out_size, void* d_ws, size_t ws_size,
                              hipStream_t stream)
{
    const float* X   = (const float*)d_in[0];
    const int*   er  = (const int*)d_in[1];
    const int*   ec  = (const int*)d_in[2];
    const float* ev  = (const float*)d_in[3];
    const float* Wp1 = (const float*)d_in[4];
    const float* bp1 = (const float*)d_in[5];
    const float* Ws1 = (const float*)d_in[6];
    const float* bs1 = (const float*)d_in[7];
    const float* Wp2 = (const float*)d_in[8];
    const float* bp2 = (const float*)d_in[9];
    const float* Ws2 = (const float*)d_in[10];
    const float* bs2 = (const float*)d_in[11];
    float* out = (float*)d_out;

    // workspace layout (float units from base):
    //   phase 1: ACC1b bf16 [0, 3.2M) | Y1pb bf16 [3.2M, 6.4M) | H1b bf16 [6.4M, 9.6M)
    //   phase 2 (reuses [0,4.8M)): Y2pb [0,1.6M) | ACC2b [1.6M,3.2M) | H2b [3.2M,4.8M)
    //   CSR at [9.6M,...): rp_base[50008] | bsum[64] | cur[256] | ecv32 u32[800k]
    //     | pkcv u32[800k] | WT bufs | parted uint2[800k] (dedicated — fat kernel
    //     writes it concurrently with ACC1b/Y1pb).
    //   cnt[50000] aliases ecv32 (dead before sort2).
    float* ws     = (float*)d_ws;
    u16*   ACC1b  = (u16*)ws;
    u16*   Y1pb   = (u16*)(ws + (size_t)3200000);
    u16*   H1b    = (u16*)(ws + (size_t)6400000);
    u16*   Y2pb   = (u16*)ws;
    u16*   ACC2b  = (u16*)(ws + (size_t)1600000);
    u16*   H2b    = (u16*)(ws + (size_t)3200000);

    int*  rp_base = (int*)(ws + (size_t)9600000);
    int*  rowptr  = rp_base + 3;          // rowptr+1 is 16B-aligned
    int*  bsum    = rp_base + 50008;      // 16B-aligned
    int*  cur     = bsum + 64;
    u32*  ecv32   = (u32*)(cur + 256);    // 16B-aligned
    int*  cnt     = (int*)ecv32;          // alias (dead before sort2)
    u32*  pkcv    = ecv32 + N_EDGES;
    u16*  WT1p    = (u16*)(pkcv + N_EDGES);
    u16*  WT1s    = WT1p + 128 * 128;
    u16*  WT2p    = WT1s + 128 * 128;
    u16*  WT2s    = WT2p + 64 * 128;
    uint2* parted = (uint2*)(WT2s + 64 * 128);   // 16B-aligned (even u16 count)

    const dim3 blk(256);
    const int node_waves  = (N_NODES * 64 + 255) / 256;        // 12500
    const int node2_waves = ((N_NODES / 2) * 64 + 255) / 256;  // 6250
    const int edge_thr    = (N_EDGES + 255) / 256;             // 3125
    const int scan_blocks = 49;
    const int part_blocks = (N_EDGES + PART_E - 1) / PART_E;   // 196
    const int fat_blocks  = GEMM_BLOCKS + part_blocks;         // 821

    // prep (zero + weight transpose) + CSR build
    k_prep    <<<241,         blk, 0, stream>>>(Wp1, Ws1, Wp2, Ws2,
                                                WT1p, WT1s, WT2p, WT2s, cnt);
    k_histpack<<<edge_thr,    blk, 0, stream>>>(er, ec, ev, cnt, pkcv);
    k_scan1   <<<scan_blocks, blk, 0, stream>>>(cnt, rowptr, bsum);
    k_scan3   <<<scan_blocks, blk, 0, stream>>>(rowptr, bsum, cur);

    // layer-1 GEMM co-resident with edge partition
    k_gemm1_part1<<<fat_blocks, blk, 0, stream>>>(X, WT1p, WT1s, bp1, bs1,
                                                  Y1pb, ACC1b, er, pkcv, cur, parted);
    k_sort2   <<<NBUCKET,     blk, 0, stream>>>(rowptr, parted, ecv32);

    // layer 1 aggregation
    k_agg1 <<<node_waves,  blk, 0, stream>>>(rowptr, ecv32, Y1pb, ACC1b, H1b);

    // layer 2
    k_gemm2<<<GEMM_BLOCKS, blk, 0, stream>>>(H1b, WT2p, WT2s, bp2, bs2, Y2pb, ACC2b);
    k_agg2 <<<node2_waves, blk, 0, stream>>>(rowptr, ecv32, Y2pb, ACC2b, H2b);

    // edge scores
    k_edgedot<<<edge_thr, blk, 0, stream>>>(er, ec, H2b, out);
}

// Round 11
// 176.353 us; speedup vs baseline: 5.9954x; 1.0627x over previous
//
#include <hip/hip_runtime.h>
#include <hip/hip_bf16.h>
#include <math.h>

#define N_NODES 50000
#define N_EDGES 800000
#define NBUCKET 196              // ceil(50000/256)
#define PART_E  4096             // edges per part1 block
#define GEMM_BLOCKS 625          // N_NODES / 80

typedef unsigned short u16;
typedef unsigned int   u32;
typedef short short8 __attribute__((ext_vector_type(8)));
typedef float f32x4  __attribute__((ext_vector_type(4)));

static __device__ __forceinline__ float b2f(u16 u) {
    union { u32 i; float f; } x; x.i = ((u32)u) << 16; return x.f;
}
static __device__ __forceinline__ u16 f2b(float f) {
    union { float f; u32 i; } x; x.f = f;
    u32 r = x.i + 0x7fffu + ((x.i >> 16) & 1u);   // round-to-nearest-even
    return (u16)(r >> 16);
}

// ---------------------------------------------------------------------------
// prep: blocks [0,49) zero cnt; blocks [49,241) transpose weights to bf16.
// ---------------------------------------------------------------------------
__global__ __launch_bounds__(256) void k_prep(
    const float* __restrict__ Wp1, const float* __restrict__ Ws1,
    const float* __restrict__ Wp2, const float* __restrict__ Ws2,
    u16* __restrict__ WT1p, u16* __restrict__ WT1s,
    u16* __restrict__ WT2p, u16* __restrict__ WT2s,
    int* __restrict__ cnt)
{
    const int b = blockIdx.x, t = threadIdx.x;
    if (b < 49) {
        const int i = b * 256 + t;
        if (i < 12500) reinterpret_cast<int4*>(cnt)[i] = make_int4(0, 0, 0, 0);
        return;
    }
    const int idx = (b - 49) * 2 + (t >> 7);   // [0,384)
    const int k = t & 127;
    const float* src; u16* dst; int N, n;
    if (idx < 128)      { src = Wp1; N = 128; n = idx;       dst = WT1p + n * 128; }
    else if (idx < 256) { src = Ws1; N = 128; n = idx - 128; dst = WT1s + n * 128; }
    else if (idx < 320) { src = Wp2; N = 64;  n = idx - 256; dst = WT2p + n * 128; }
    else                { src = Ws2; N = 64;  n = idx - 320; dst = WT2s + n * 128; }
    dst[k] = f2b(src[k * N + n]);
}

// ---------------------------------------------------------------------------
// hist: per-row counts only (packing moved into part1).
// ---------------------------------------------------------------------------
__global__ __launch_bounds__(256) void k_hist(
    const int* __restrict__ er, int* __restrict__ cnt)
{
    const int e = blockIdx.x * 256 + threadIdx.x;
    if (e < N_EDGES) atomicAdd(&cnt[er[e]], 1);
}

__global__ __launch_bounds__(256) void k_scan1(
    const int* __restrict__ cnt, int* __restrict__ rowptr, int* __restrict__ bsum)
{
    __shared__ int wsum[4];
    const int t = threadIdx.x;
    const int g4 = blockIdx.x * 256 + t;
    int4 v = make_int4(0, 0, 0, 0);
    if (g4 < 12500) v = reinterpret_cast<const int4*>(cnt)[g4];
    const int s0 = v.x, s1 = s0 + v.y, s2 = s1 + v.z, s3 = s2 + v.w;

    const int lane = t & 63, wv = t >> 6;
    int incl = s3;
#pragma unroll
    for (int off = 1; off < 64; off <<= 1) {
        int u = __shfl_up(incl, off, 64);
        if (lane >= off) incl += u;
    }
    if (lane == 63) wsum[wv] = incl;
    __syncthreads();
    int woff = 0;
    if (wv > 0) woff += wsum[0];
    if (wv > 1) woff += wsum[1];
    if (wv > 2) woff += wsum[2];
    const int excl = woff + incl - s3;

    if (g4 < 12500) {
        int4 o;
        o.x = excl + s0; o.y = excl + s1; o.z = excl + s2; o.w = excl + s3;
        reinterpret_cast<int4*>(rowptr + 1)[g4] = o;
    }
    if (t == 255) bsum[blockIdx.x] = woff + incl;
}

// scan3: add block offsets; also emit bucket cursors cur[k] = rowptr[k*256].
__global__ __launch_bounds__(256) void k_scan3(
    int* __restrict__ rowptr, const int* __restrict__ bsum, int* __restrict__ cur)
{
    __shared__ int s_add;
    const int b = blockIdx.x;
    const int t = threadIdx.x;
    if (t < 64) {
        int v = (t < b) ? bsum[t] : 0;
#pragma unroll
        for (int off = 32; off; off >>= 1) v += __shfl_xor(v, off, 64);
        if (t == 0) s_add = v;
    }
    __syncthreads();
    const int add = s_add;
    const int g4 = b * 256 + t;
    if (g4 < 12500) {
        int4* o4 = reinterpret_cast<int4*>(rowptr + 1);
        int4 v = o4[g4];
        v.x += add; v.y += add; v.z += add; v.w += add;
        if (b) o4[g4] = v;                      // b==0: add==0, skip write
        const int i0 = 4 * g4 + 1;
        const int vv[4] = {v.x, v.y, v.z, v.w};
#pragma unroll
        for (int j = 0; j < 4; ++j) {
            const int idx = i0 + j;
            if (idx < N_NODES && (idx & 255) == 0) cur[idx >> 8] = vv[j];
        }
    }
    if (b == 0 && t == 0) { rowptr[0] = 0; cur[0] = 0; }
}

// ---------------------------------------------------------------------------
// FAT kernel: blocks [0,625) = GEMM1 (MFMA), blocks [625,821) = part1.
// GEMM1: Y1pb (bf16) = X @ Wp1 ; ACC1b (bf16) = X @ Ws1 + (bs1+bp1)
// part1: pack (col, bf16(val)) on the fly and partition edges into 196
//        row-buckets (grouped contiguous writes).
// ---------------------------------------------------------------------------
__global__ __launch_bounds__(256) void k_gemm1_part1(
    const float* __restrict__ X,
    const u16* __restrict__ WT1p, const u16* __restrict__ WT1s,
    const float* __restrict__ bp, const float* __restrict__ bs,
    u16* __restrict__ Y1pb, u16* __restrict__ ACC1b,
    const int* __restrict__ er, const int* __restrict__ ec,
    const float* __restrict__ ev,
    int* __restrict__ cur, uint2* __restrict__ parted)
{
    __shared__ u16 Xs[80 * 128];
    __shared__ int hist[NBUCKET], base[NBUCKET], cntl[NBUCKET];
    const int t = threadIdx.x;

    if (blockIdx.x >= GEMM_BLOCKS) {
        // ---- part1 (+pack) ----
        if (t < NBUCKET) hist[t] = 0;
        __syncthreads();

        const int e0 = (blockIdx.x - GEMM_BLOCKS) * PART_E;
        int rows[16]; u32 pks[16];
#pragma unroll
        for (int i = 0; i < 16; ++i) {
            const int e = e0 + t + 256 * i;
            if (e < N_EDGES) {
                rows[i] = er[e];
                pks[i] = (u32)ec[e] | ((u32)f2b(ev[e]) << 16);
                atomicAdd(&hist[rows[i] >> 8], 1);
            } else rows[i] = -1;
        }
        __syncthreads();
        if (t < NBUCKET) { base[t] = atomicAdd(&cur[t], hist[t]); cntl[t] = 0; }
        __syncthreads();

#pragma unroll
        for (int i = 0; i < 16; ++i) {
            if (rows[i] >= 0) {
                const int b = rows[i] >> 8;
                const int off = atomicAdd(&cntl[b], 1);
                parted[base[b] + off] = make_uint2(pks[i], (u32)rows[i]);
            }
        }
        return;
    }

    // ---- GEMM1 ----
    const float4* Xv = reinterpret_cast<const float4*>(X) + (size_t)blockIdx.x * 2560;
#pragma unroll
    for (int i = 0; i < 10; ++i) {
        const int f4 = t + 256 * i;
        const float4 v = Xv[f4];
        const int row = f4 >> 5, col4 = f4 & 31;
        const u32 lo = (u32)f2b(v.x) | ((u32)f2b(v.y) << 16);
        const u32 hi = (u32)f2b(v.z) | ((u32)f2b(v.w) << 16);
        const int e = row * 128 + ((col4 * 4) ^ ((row & 7) << 3));
        *reinterpret_cast<uint2*>(&Xs[e]) = make_uint2(lo, hi);
    }
    __syncthreads();

    const int lane = t & 63;
    const int w = t >> 6;
    const int mat = w >> 1;
    const int cbase = (w & 1) * 64;
    const u16* __restrict__ WT = mat ? WT1s : WT1p;
    const int lr = lane & 15;
    const int lk = (lane >> 4) * 8;

    f32x4 acc[5][4];
#pragma unroll
    for (int m = 0; m < 5; ++m)
#pragma unroll
        for (int n = 0; n < 4; ++n) acc[m][n] = (f32x4){0.f, 0.f, 0.f, 0.f};

#pragma unroll
    for (int kk = 0; kk < 4; ++kk) {
        short8 b[4];
#pragma unroll
        for (int n = 0; n < 4; ++n) {
            const int col = cbase + n * 16 + lr;
            b[n] = *reinterpret_cast<const short8*>(WT + col * 128 + kk * 32 + lk);
        }
#pragma unroll
        for (int m = 0; m < 5; ++m) {
            const int row = m * 16 + lr;
            const int e = row * 128 + ((kk * 32 + lk) ^ ((row & 7) << 3));
            const short8 a = *reinterpret_cast<const short8*>(&Xs[e]);
#pragma unroll
            for (int n = 0; n < 4; ++n)
                acc[m][n] = __builtin_amdgcn_mfma_f32_16x16x32_bf16(a, b[n], acc[m][n], 0, 0, 0);
        }
    }

    const int row0 = blockIdx.x * 80;
    const int rq = (lane >> 4) * 4;
    if (mat == 0) {
#pragma unroll
        for (int m = 0; m < 5; ++m)
#pragma unroll
            for (int n = 0; n < 4; ++n) {
                const int col = cbase + n * 16 + lr;
#pragma unroll
                for (int q = 0; q < 4; ++q)
                    Y1pb[(size_t)(row0 + m * 16 + rq + q) * 128 + col] = f2b(acc[m][n][q]);
            }
    } else {
        float bias[4];
#pragma unroll
        for (int n = 0; n < 4; ++n) {
            const int col = cbase + n * 16 + lr;
            bias[n] = bs[col] + bp[col];
        }
#pragma unroll
        for (int m = 0; m < 5; ++m)
#pragma unroll
            for (int n = 0; n < 4; ++n) {
                const int col = cbase + n * 16 + lr;
#pragma unroll
                for (int q = 0; q < 4; ++q)
                    ACC1b[(size_t)(row0 + m * 16 + rq + q) * 128 + col] = f2b(acc[m][n][q] + bias[n]);
            }
    }
}

// pass 2: one block per bucket; scatter confined to the bucket's CSR window.
__global__ __launch_bounds__(256) void k_sort2(
    const int* __restrict__ rowptr, const uint2* __restrict__ parted,
    u32* __restrict__ ecv32)
{
    __shared__ int cur[256];
    const int b = blockIdx.x;
    const int t = threadIdx.x;
    const int r0 = b * 256;
    const int rt = r0 + t;
    cur[t] = rowptr[rt < N_NODES ? rt : N_NODES];
    __syncthreads();

    const int lo = rowptr[r0];
    const int r1 = r0 + 256;
    const int hi = rowptr[r1 < N_NODES ? r1 : N_NODES];

    for (int e = lo + t; e < hi; e += 256) {
        const uint2 pe = parted[e];
        const int low = (int)(pe.y & 255u);
        const int slot = atomicAdd(&cur[low], 1);
        ecv32[slot] = pe.x;
    }
}

// ---------------------------------------------------------------------------
// agg1: H1b[i] = relu( ACC1b[i] + sum val_j * Y1pb[col_j] )    (bf16 out)
// one wave per node; 8 in-flight row-gathers (MLP=8).
// ---------------------------------------------------------------------------
__global__ __launch_bounds__(256) void k_agg1(
    const int* __restrict__ rowptr, const u32* __restrict__ ecv32,
    const u16* __restrict__ Y1pb, const u16* __restrict__ ACC1b,
    u16* __restrict__ H1b)
{
    const unsigned tid = blockIdx.x * 256u + threadIdx.x;
    const unsigned i = tid >> 6;
    if (i >= N_NODES) return;
    const unsigned lane = tid & 63u;

    const int e0 = rowptr[i];
    const int e1 = rowptr[i + 1];

    // self-term early (overlaps first gather batch)
    const u32 s = reinterpret_cast<const u32*>(ACC1b)[i * 64 + lane];

    const u32* __restrict__ Yv = reinterpret_cast<const u32*>(Y1pb);

    float ax0 = 0.f, ay0 = 0.f, ax1 = 0.f, ay1 = 0.f;
    float ax2 = 0.f, ay2 = 0.f, ax3 = 0.f, ay3 = 0.f;
    int j = e0;
    for (; j + 7 < e1; j += 8) {
        u32 p[8], w[8];
#pragma unroll
        for (int q = 0; q < 8; ++q) p[q] = ecv32[j + q];
#pragma unroll
        for (int q = 0; q < 8; ++q) w[q] = Yv[(p[q] & 0xffffu) * 64 + lane];
#pragma unroll
        for (int q = 0; q < 8; ++q) {
            const float v = b2f((u16)(p[q] >> 16));
            if ((q & 3) == 0) { ax0 = fmaf(v, b2f((u16)(w[q] & 0xffffu)), ax0); ay0 = fmaf(v, b2f((u16)(w[q] >> 16)), ay0); }
            if ((q & 3) == 1) { ax1 = fmaf(v, b2f((u16)(w[q] & 0xffffu)), ax1); ay1 = fmaf(v, b2f((u16)(w[q] >> 16)), ay1); }
            if ((q & 3) == 2) { ax2 = fmaf(v, b2f((u16)(w[q] & 0xffffu)), ax2); ay2 = fmaf(v, b2f((u16)(w[q] >> 16)), ay2); }
            if ((q & 3) == 3) { ax3 = fmaf(v, b2f((u16)(w[q] & 0xffffu)), ax3); ay3 = fmaf(v, b2f((u16)(w[q] >> 16)), ay3); }
        }
    }
    for (; j + 3 < e1; j += 4) {
        const u32 p0 = ecv32[j], p1 = ecv32[j + 1], p2 = ecv32[j + 2], p3 = ecv32[j + 3];
        const u32 w0 = Yv[(p0 & 0xffffu) * 64 + lane];
        const u32 w1 = Yv[(p1 & 0xffffu) * 64 + lane];
        const u32 w2 = Yv[(p2 & 0xffffu) * 64 + lane];
        const u32 w3 = Yv[(p3 & 0xffffu) * 64 + lane];
        const float v0 = b2f((u16)(p0 >> 16)), v1 = b2f((u16)(p1 >> 16));
        const float v2 = b2f((u16)(p2 >> 16)), v3 = b2f((u16)(p3 >> 16));
        ax0 = fmaf(v0, b2f((u16)(w0 & 0xffffu)), ax0); ay0 = fmaf(v0, b2f((u16)(w0 >> 16)), ay0);
        ax1 = fmaf(v1, b2f((u16)(w1 & 0xffffu)), ax1); ay1 = fmaf(v1, b2f((u16)(w1 >> 16)), ay1);
        ax2 = fmaf(v2, b2f((u16)(w2 & 0xffffu)), ax2); ay2 = fmaf(v2, b2f((u16)(w2 >> 16)), ay2);
        ax3 = fmaf(v3, b2f((u16)(w3 & 0xffffu)), ax3); ay3 = fmaf(v3, b2f((u16)(w3 >> 16)), ay3);
    }
    for (; j < e1; ++j) {
        const u32 p = ecv32[j];
        const u32 w = Yv[(p & 0xffffu) * 64 + lane];
        const float v = b2f((u16)(p >> 16));
        ax0 = fmaf(v, b2f((u16)(w & 0xffffu)), ax0);
        ay0 = fmaf(v, b2f((u16)(w >> 16)), ay0);
    }
    const float ax = (ax0 + ax1) + (ax2 + ax3);
    const float ay = (ay0 + ay1) + (ay2 + ay3);

    const float h0 = fmaxf(b2f((u16)(s & 0xffffu)) + ax, 0.f);
    const float h1 = fmaxf(b2f((u16)(s >> 16)) + ay, 0.f);
    reinterpret_cast<u32*>(H1b)[i * 64 + lane] = (u32)f2b(h0) | ((u32)f2b(h1) << 16);
}

// ---------------------------------------------------------------------------
// GEMM2 (MFMA): Y2pb (bf16) = H1 @ Wp2 ; ACC2b (bf16) = H1 @ Ws2 + (bs2+bp2)
// ---------------------------------------------------------------------------
__global__ __launch_bounds__(256) void k_gemm2(
    const u16* __restrict__ H1b,
    const u16* __restrict__ WT2p, const u16* __restrict__ WT2s,
    const float* __restrict__ bp, const float* __restrict__ bs,
    u16* __restrict__ Y2pb, u16* __restrict__ ACC2b)
{
    __shared__ u16 Hs[80 * 128];
    const int t = threadIdx.x;

    const uint4* Hv = reinterpret_cast<const uint4*>(H1b) + (size_t)blockIdx.x * 1280;
#pragma unroll
    for (int i = 0; i < 5; ++i) {
        const int ch = t + 256 * i;
        const uint4 v = Hv[ch];
        const int row = ch >> 4, c16 = ch & 15;
        const int e = row * 128 + ((c16 * 8) ^ ((row & 7) << 3));
        *reinterpret_cast<uint4*>(&Hs[e]) = v;
    }
    __syncthreads();

    const int lane = t & 63;
    const int w = t >> 6;
    const int mat = w >> 1;
    const int cbase = (w & 1) * 32;
    const u16* __restrict__ WT = mat ? WT2s : WT2p;
    const int lr = lane & 15;
    const int lk = (lane >> 4) * 8;

    f32x4 acc[5][2];
#pragma unroll
    for (int m = 0; m < 5; ++m)
#pragma unroll
        for (int n = 0; n < 2; ++n) acc[m][n] = (f32x4){0.f, 0.f, 0.f, 0.f};

#pragma unroll
    for (int kk = 0; kk < 4; ++kk) {
        short8 b[2];
#pragma unroll
        for (int n = 0; n < 2; ++n) {
            const int col = cbase + n * 16 + lr;
            b[n] = *reinterpret_cast<const short8*>(WT + col * 128 + kk * 32 + lk);
        }
#pragma unroll
        for (int m = 0; m < 5; ++m) {
            const int row = m * 16 + lr;
            const int e = row * 128 + ((kk * 32 + lk) ^ ((row & 7) << 3));
            const short8 a = *reinterpret_cast<const short8*>(&Hs[e]);
#pragma unroll
            for (int n = 0; n < 2; ++n)
                acc[m][n] = __builtin_amdgcn_mfma_f32_16x16x32_bf16(a, b[n], acc[m][n], 0, 0, 0);
        }
    }

    const int row0 = blockIdx.x * 80;
    const int rq = (lane >> 4) * 4;
    if (mat == 0) {
#pragma unroll
        for (int m = 0; m < 5; ++m)
#pragma unroll
            for (int n = 0; n < 2; ++n) {
                const int col = cbase + n * 16 + lr;
#pragma unroll
                for (int q = 0; q < 4; ++q)
                    Y2pb[(size_t)(row0 + m * 16 + rq + q) * 64 + col] = f2b(acc[m][n][q]);
            }
    } else {
        float bias[2];
#pragma unroll
        for (int n = 0; n < 2; ++n) {
            const int col = cbase + n * 16 + lr;
            bias[n] = bs[col] + bp[col];
        }
#pragma unroll
        for (int m = 0; m < 5; ++m)
#pragma unroll
            for (int n = 0; n < 2; ++n) {
                const int col = cbase + n * 16 + lr;
#pragma unroll
                for (int q = 0; q < 4; ++q)
                    ACC2b[(size_t)(row0 + m * 16 + rq + q) * 64 + col] = f2b(acc[m][n][q] + bias[n]);
            }
    }
}

// ---------------------------------------------------------------------------
// agg2: H2b[i] = relu( ACC2b[i] + sum val_j * Y2pb[col_j] )   (bf16 out)
// 2 nodes per wave, 32 lanes/node; MLP=8.
// ---------------------------------------------------------------------------
__global__ __launch_bounds__(256) void k_agg2(
    const int* __restrict__ rowptr, const u32* __restrict__ ecv32,
    const u16* __restrict__ Y2pb, const u16* __restrict__ ACC2b,
    u16* __restrict__ H2b)
{
    const unsigned tid = blockIdx.x * 256u + threadIdx.x;
    const unsigned lane = tid & 63u;
    const unsigned i = (tid >> 6) * 2 + (lane >> 5);
    if (i >= N_NODES) return;
    const unsigned hl = lane & 31u;

    const int e0 = rowptr[i];
    const int e1 = rowptr[i + 1];

    const u32 s = reinterpret_cast<const u32*>(ACC2b)[i * 32 + hl];

    const u32* __restrict__ Yv = reinterpret_cast<const u32*>(Y2pb);

    float ax0 = 0.f, ay0 = 0.f, ax1 = 0.f, ay1 = 0.f;
    float ax2 = 0.f, ay2 = 0.f, ax3 = 0.f, ay3 = 0.f;
    int j = e0;
    for (; j + 7 < e1; j += 8) {
        u32 p[8], w[8];
#pragma unroll
        for (int q = 0; q < 8; ++q) p[q] = ecv32[j + q];
#pragma unroll
        for (int q = 0; q < 8; ++q) w[q] = Yv[(p[q] & 0xffffu) * 32 + hl];
#pragma unroll
        for (int q = 0; q < 8; ++q) {
            const float v = b2f((u16)(p[q] >> 16));
            if ((q & 3) == 0) { ax0 = fmaf(v, b2f((u16)(w[q] & 0xffffu)), ax0); ay0 = fmaf(v, b2f((u16)(w[q] >> 16)), ay0); }
            if ((q & 3) == 1) { ax1 = fmaf(v, b2f((u16)(w[q] & 0xffffu)), ax1); ay1 = fmaf(v, b2f((u16)(w[q] >> 16)), ay1); }
            if ((q & 3) == 2) { ax2 = fmaf(v, b2f((u16)(w[q] & 0xffffu)), ax2); ay2 = fmaf(v, b2f((u16)(w[q] >> 16)), ay2); }
            if ((q & 3) == 3) { ax3 = fmaf(v, b2f((u16)(w[q] & 0xffffu)), ax3); ay3 = fmaf(v, b2f((u16)(w[q] >> 16)), ay3); }
        }
    }
    for (; j + 3 < e1; j += 4) {
        const u32 p0 = ecv32[j], p1 = ecv32[j + 1], p2 = ecv32[j + 2], p3 = ecv32[j + 3];
        const u32 w0 = Yv[(p0 & 0xffffu) * 32 + hl];
        const u32 w1 = Yv[(p1 & 0xffffu) * 32 + hl];
        const u32 w2 = Yv[(p2 & 0xffffu) * 32 + hl];
        const u32 w3 = Yv[(p3 & 0xffffu) * 32 + hl];
        const float v0 = b2f((u16)(p0 >> 16)), v1 = b2f((u16)(p1 >> 16));
        const float v2 = b2f((u16)(p2 >> 16)), v3 = b2f((u16)(p3 >> 16));
        ax0 = fmaf(v0, b2f((u16)(w0 & 0xffffu)), ax0); ay0 = fmaf(v0, b2f((u16)(w0 >> 16)), ay0);
        ax1 = fmaf(v1, b2f((u16)(w1 & 0xffffu)), ax1); ay1 = fmaf(v1, b2f((u16)(w1 >> 16)), ay1);
        ax2 = fmaf(v2, b2f((u16)(w2 & 0xffffu)), ax2); ay2 = fmaf(v2, b2f((u16)(w2 >> 16)), ay2);
        ax3 = fmaf(v3, b2f((u16)(w3 & 0xffffu)), ax3); ay3 = fmaf(v3, b2f((u16)(w3 >> 16)), ay3);
    }
    for (; j < e1; ++j) {
        const u32 p = ecv32[j];
        const u32 w = Yv[(p & 0xffffu) * 32 + hl];
        const float v = b2f((u16)(p >> 16));
        ax0 = fmaf(v, b2f((u16)(w & 0xffffu)), ax0);
        ay0 = fmaf(v, b2f((u16)(w >> 16)), ay0);
    }
    const float ax = (ax0 + ax1) + (ax2 + ax3);
    const float ay = (ay0 + ay1) + (ay2 + ay3);

    const float h0 = fmaxf(b2f((u16)(s & 0xffffu)) + ax, 0.f);
    const float h1 = fmaxf(b2f((u16)(s >> 16)) + ay, 0.f);
    reinterpret_cast<u32*>(H2b)[i * 32 + hl] = (u32)f2b(h0) | ((u32)f2b(h1) << 16);
}

// ---------------------------------------------------------------------------
// edgedot: out[e] = sigmoid( dot(H2[row], H2[col]) )
// ---------------------------------------------------------------------------
__global__ __launch_bounds__(256) void k_edgedot(
    const int* __restrict__ er, const int* __restrict__ ec,
    const u16* __restrict__ H2b, float* __restrict__ out)
{
    const int e = blockIdx.x * 256 + threadIdx.x;
    if (e >= N_EDGES) return;

    const int r = er[e];
    const int c = ec[e];

    const uint4* __restrict__ A = reinterpret_cast<const uint4*>(H2b + (size_t)r * 64);
    const uint4* __restrict__ B = reinterpret_cast<const uint4*>(H2b + (size_t)c * 64);

    float s0 = 0.f, s1 = 0.f, s2 = 0.f, s3 = 0.f;
#pragma unroll
    for (int k = 0; k < 8; ++k) {
        const uint4 a = A[k];
        const uint4 b = B[k];
        s0 = fmaf(b2f((u16)(a.x & 0xffffu)), b2f((u16)(b.x & 0xffffu)), s0);
        s1 = fmaf(b2f((u16)(a.x >> 16)),     b2f((u16)(b.x >> 16)),     s1);
        s2 = fmaf(b2f((u16)(a.y & 0xffffu)), b2f((u16)(b.y & 0xffffu)), s2);
        s3 = fmaf(b2f((u16)(a.y >> 16)),     b2f((u16)(b.y >> 16)),     s3);
        s0 = fmaf(b2f((u16)(a.z & 0xffffu)), b2f((u16)(b.z & 0xffffu)), s0);
        s1 = fmaf(b2f((u16)(a.z >> 16)),     b2f((u16)(b.z >> 16)),     s1);
        s2 = fmaf(b2f((u16)(a.w & 0xffffu)), b2f((u16)(b.w & 0xffffu)), s2);
        s3 = fmaf(b2f((u16)(a.w >> 16)),     b2f((u16)(b.w >> 16)),     s3);
    }
    const float p = (s0 + s1) + (s2 + s3);
    out[e] = 1.f / (1.f + expf(-p));
}

// ---------------------------------------------------------------------------
extern "C" void kernel_launch(void* const* d_in, const int* in_sizes, int n_in,
                              void* d_out, int out_size, void* d_ws, size_t ws_size,
                              hipStream_t stream)
{
    const float* X   = (const float*)d_in[0];
    const int*   er  = (const int*)d_in[1];
    const int*   ec  = (const int*)d_in[2];
    const float* ev  = (const float*)d_in[3];
    const float* Wp1 = (const float*)d_in[4];
    const float* bp1 = (const float*)d_in[5];
    const float* Ws1 = (const float*)d_in[6];
    const float* bs1 = (const float*)d_in[7];
    const float* Wp2 = (const float*)d_in[8];
    const float* bp2 = (const float*)d_in[9];
    const float* Ws2 = (const float*)d_in[10];
    const float* bs2 = (const float*)d_in[11];
    float* out = (float*)d_out;

    // workspace layout (float units from base):
    //   phase 1: ACC1b bf16 [0, 3.2M) | Y1pb bf16 [3.2M, 6.4M) | H1b bf16 [6.4M, 9.6M)
    //   phase 2 (reuses [0,4.8M)): Y2pb [0,1.6M) | ACC2b [1.6M,3.2M) | H2b [3.2M,4.8M)
    //   CSR at [9.6M,...): rp_base[50008] | bsum[64] | cur[256] | ecv32 u32[800k]
    //     | WT bufs | parted uint2[800k] (dedicated).
    //   cnt[50000] aliases ecv32 (dead before sort2).
    float* ws     = (float*)d_ws;
    u16*   ACC1b  = (u16*)ws;
    u16*   Y1pb   = (u16*)(ws + (size_t)3200000);
    u16*   H1b    = (u16*)(ws + (size_t)6400000);
    u16*   Y2pb   = (u16*)ws;
    u16*   ACC2b  = (u16*)(ws + (size_t)1600000);
    u16*   H2b    = (u16*)(ws + (size_t)3200000);

    int*  rp_base = (int*)(ws + (size_t)9600000);
    int*  rowptr  = rp_base + 3;          // rowptr+1 is 16B-aligned
    int*  bsum    = rp_base + 50008;      // 16B-aligned
    int*  cur     = bsum + 64;
    u32*  ecv32   = (u32*)(cur + 256);    // 16B-aligned
    int*  cnt     = (int*)ecv32;          // alias (dead before sort2)
    u16*  WT1p    = (u16*)(ecv32 + N_EDGES);
    u16*  WT1s    = WT1p + 128 * 128;
    u16*  WT2p    = WT1s + 128 * 128;
    u16*  WT2s    = WT2p + 64 * 128;
    uint2* parted = (uint2*)(WT2s + 64 * 128);   // 16B-aligned (even u16 count)

    const dim3 blk(256);
    const int node_waves  = (N_NODES * 64 + 255) / 256;        // 12500
    const int node2_waves = ((N_NODES / 2) * 64 + 255) / 256;  // 6250
    const int edge_thr    = (N_EDGES + 255) / 256;             // 3125
    const int scan_blocks = 49;
    const int part_blocks = (N_EDGES + PART_E - 1) / PART_E;   // 196
    const int fat_blocks  = GEMM_BLOCKS + part_blocks;         // 821

    // prep (zero + weight transpose) + CSR build
    k_prep    <<<241,         blk, 0, stream>>>(Wp1, Ws1, Wp2, Ws2,
                                                WT1p, WT1s, WT2p, WT2s, cnt);
    k_hist    <<<edge_thr,    blk, 0, stream>>>(er, cnt);
    k_scan1   <<<scan_blocks, blk, 0, stream>>>(cnt, rowptr, bsum);
    k_scan3   <<<scan_blocks, blk, 0, stream>>>(rowptr, bsum, cur);

    // layer-1 GEMM co-resident with edge partition (+pack)
    k_gemm1_part1<<<fat_blocks, blk, 0, stream>>>(X, WT1p, WT1s, bp1, bs1,
                                                  Y1pb, ACC1b, er, ec, ev, cur, parted);
    k_sort2   <<<NBUCKET,     blk, 0, stream>>>(rowptr, parted, ecv32);

    // layer 1 aggregation
    k_agg1 <<<node_waves,  blk, 0, stream>>>(rowptr, ecv32, Y1pb, ACC1b, H1b);

    // layer 2
    k_gemm2<<<GEMM_BLOCKS, blk, 0, stream>>>(H1b, WT2p, WT2s, bp2, bs2, Y2pb, ACC2b);
    k_agg2 <<<node2_waves, blk, 0, stream>>>(rowptr, ecv32, Y2pb, ACC2b, H2b);

    // edge scores
    k_edgedot<<<edge_thr, blk, 0, stream>>>(er, ec, H2b, out);
}